// Round 1
// 441.069 us; speedup vs baseline: 1.0299x; 1.0299x over previous
//
#include <hip/hip_runtime.h>
#include <math.h>

// ---------- types ----------
typedef __bf16 bf16x8 __attribute__((ext_vector_type(8)));
typedef float  f32x4  __attribute__((ext_vector_type(4)));

#define QCHUNK 128
#define NCHUNK 16
#define SLD 136              // LDS row stride (bf16 elems) for 128-wide arrays

__device__ __forceinline__ float bf2f(unsigned short u) {
    union { unsigned int i; float f; } v; v.i = ((unsigned int)u) << 16; return v.f;
}
__device__ __forceinline__ unsigned short f2bf(float f) {
    union { float f; unsigned int i; } v; v.f = f;
    unsigned int x = v.i;
    unsigned int r = (x + 0x7FFFu + ((x >> 16) & 1u)) >> 16;
    return (unsigned short)r;
}
__device__ __forceinline__ uint4 pack8(float4 a, float4 b) {
    uint4 r;
    r.x = (unsigned)f2bf(a.x) | ((unsigned)f2bf(a.y) << 16);
    r.y = (unsigned)f2bf(a.z) | ((unsigned)f2bf(a.w) << 16);
    r.z = (unsigned)f2bf(b.x) | ((unsigned)f2bf(b.y) << 16);
    r.w = (unsigned)f2bf(b.z) | ((unsigned)f2bf(b.w) << 16);
    return r;
}
__device__ __forceinline__ void load_lds16(const void* g, void* l) {
    __builtin_amdgcn_global_load_lds((const __attribute__((address_space(1))) void*)g,
                                     (__attribute__((address_space(3))) void*)l,
                                     16, 0, 0);
}

// ---------- convert: x -> x_bf, w_in -> w_in_bf (padded 3584 rows, zero-filled) ----------
__global__ __launch_bounds__(256)
void convert_kernel(const float* __restrict__ x, const float* __restrict__ w_in,
                    unsigned short* __restrict__ x_bf, unsigned short* __restrict__ w_in_bf) {
    int idx = blockIdx.x * 256 + threadIdx.x;      // 8 elems each
    const int NX  = 8192 * 768 / 8;                // 786432
    const int NW1 = 3584 * 768 / 8;                // 344064 (padded to 14x256 tiles)
    const int NW1r = 3352 * 768 / 8;               // 321792 (real)
    if (idx < NX) {
        const float* s = x + (size_t)idx * 8;
        *(uint4*)(x_bf + (size_t)idx * 8) = pack8(*(const float4*)s, *(const float4*)(s + 4));
    } else if (idx < NX + NW1) {
        int j = idx - NX;
        uint4 v = make_uint4(0u, 0u, 0u, 0u);
        if (j < NW1r) {
            const float* s = w_in + (size_t)j * 8;
            v = pack8(*(const float4*)s, *(const float4*)(s + 4));
        }
        *(uint4*)(w_in_bf + (size_t)j * 8) = v;
    }
}

// ---------- convert w_out -> bf16 ----------
__global__ __launch_bounds__(256)
void convert_wout_kernel(const float* __restrict__ w_out, unsigned short* __restrict__ w_out_bf) {
    int idx = blockIdx.x * 256 + threadIdx.x;      // 147456 total
    const float* s = w_out + (size_t)idx * 8;
    *(uint4*)(w_out_bf + (size_t)idx * 8) = pack8(*(const float4*)s, *(const float4*)(s + 4));
}

// ---------- 256x256 phase-split GEMM (T2+T3+T4+T5): Out[m,n] = sum_k A[m,k]*Bw[n,k], bf16 out ----------
// 512 threads = 8 waves (2 wr x 4 wc); per-wave output 128x64; BK=64 in two k-half phases.
// LDS: A[2 dbuf][2 kh][256][32] bf16 @0 (64KB), B same @65536 (64KB) = 128 KiB.
// Swizzle: 16B k-slot kb stored at kb^(r&3); applied on BOTH global-source and ds_read side.
// Schedule per phase: vmcnt(4); s_barrier; 12x ds_read_b128; issue 4x global_load_lds(next
// tile k-half); setprio(1); 32 MFMA; setprio(0).  vmcnt never drains to 0 in the main loop.
__global__ __launch_bounds__(512)
void gemm_8phase(const unsigned short* __restrict__ A,
                 const unsigned short* __restrict__ Bw,
                 unsigned short* __restrict__ Out,
                 int N_real, int K) {
    extern __shared__ __align__(16) char smem[];

    const int tid = threadIdx.x;
    const int bid = blockIdx.x;
    // XCD-chunked swizzle: 448 blocks = 8 XCDs x 56; m-fastest within chunk (B-panel L2 reuse)
    const int swz = (bid & 7) * 56 + (bid >> 3);
    const int m0 = (swz & 31) * 256;
    const int n0 = (swz >> 5) * 256;

    const int wave = tid >> 6, lane = tid & 63;
    const int wr = wave >> 2, wc = wave & 3;
    const int lr = lane & 15, q = lane >> 4;

    // ds_read lane offsets (bytes): row*64 + swizzled-slot*16
    const int sw   = ((q ^ (lr & 3)) << 4);
    const int aoff = (wr * 128 + lr) * 64 + sw;
    const int boff = 65536 + (wc * 64 + lr) * 64 + sw;

    // staging: thread tid covers LDS linear slot (r=tid>>2, kb=tid&3) of an 8KB j-chunk;
    // global source pre-swizzled so linear LDS + swizzled read = identity.
    const int srow = tid >> 2;                 // 0..127
    const int skb  = (tid & 3) ^ (srow & 3);   // swizzled k-slot
    const unsigned short* ga0 = A  + (size_t)(m0 + srow) * K       + skb * 8;
    const unsigned short* ga1 = A  + (size_t)(m0 + 128 + srow) * K + skb * 8;
    const unsigned short* gb0 = Bw + (size_t)(n0 + srow) * K       + skb * 8;
    const unsigned short* gb1 = Bw + (size_t)(n0 + 128 + srow) * K + skb * 8;
    char* sA0 = smem +              (size_t)tid * 16;   // rows 0-127
    char* sA1 = smem +       8192 + (size_t)tid * 16;   // rows 128-255
    char* sB0 = smem + 65536 +      (size_t)tid * 16;
    char* sB1 = smem + 65536 + 8192 + (size_t)tid * 16;

    const int NT = K >> 6;
    f32x4 acc[8][4] = {};

    // prologue: tile0 k-half0 then k-half1 into dbuf0 (8 loads, grouped by k-half)
    load_lds16(ga0 + 0,  sA0 + 0);
    load_lds16(ga1 + 0,  sA1 + 0);
    load_lds16(gb0 + 0,  sB0 + 0);
    load_lds16(gb1 + 0,  sB1 + 0);
    load_lds16(ga0 + 32, sA0 + 16384);
    load_lds16(ga1 + 32, sA1 + 16384);
    load_lds16(gb0 + 32, sB0 + 16384);
    load_lds16(gb1 + 32, sB1 + 16384);

    for (int t = 0; t < NT; ++t) {
        const int d = t & 1;
        const char* pbase = smem + d * 32768;
        const int sdst = (d ^ 1) * 32768;
        const int kt = (t + 1) << 6;           // next tile's k base (elements)
        const bool more = (t + 1 < NT);
        #pragma unroll
        for (int kh = 0; kh < 2; ++kh) {
            // gate: oldest 4 outstanding = this phase's k-half (issued 2 phases ago)
            if (more || kh == 0) asm volatile("s_waitcnt vmcnt(4)" ::: "memory");
            else                 asm volatile("s_waitcnt vmcnt(0)" ::: "memory");
            __builtin_amdgcn_s_barrier();

            const char* pa = pbase + kh * 16384 + aoff;
            const char* pb = pbase + kh * 16384 + boff;
            bf16x8 af[8], bfr[4];
            #pragma unroll
            for (int m = 0; m < 8; ++m) af[m]  = *(const bf16x8*)(pa + m * 1024);
            #pragma unroll
            for (int n = 0; n < 4; ++n) bfr[n] = *(const bf16x8*)(pb + n * 1024);

            if (more) {                         // stage next tile's same k-half -> other dbuf
                const int kg = kt + kh * 32;
                const int ld = sdst + kh * 16384;
                load_lds16(ga0 + kg, sA0 + ld);
                load_lds16(ga1 + kg, sA1 + ld);
                load_lds16(gb0 + kg, sB0 + ld);
                load_lds16(gb1 + kg, sB1 + ld);
            }

            __builtin_amdgcn_s_setprio(1);
            #pragma unroll
            for (int m = 0; m < 8; ++m)
                #pragma unroll
                for (int n = 0; n < 4; ++n)
                    acc[m][n] = __builtin_amdgcn_mfma_f32_16x16x32_bf16(af[m], bfr[n], acc[m][n], 0, 0, 0);
            __builtin_amdgcn_s_setprio(0);
        }
    }

    // epilogue: C/D layout col=lane&15, row=(lane>>4)*4+reg
    #pragma unroll
    for (int m = 0; m < 8; ++m) {
        #pragma unroll
        for (int r = 0; r < 4; ++r) {
            int row = m0 + wr * 128 + m * 16 + q * 4 + r;
            #pragma unroll
            for (int n = 0; n < 4; ++n) {
                int col = n0 + wc * 64 + n * 16 + lr;
                if (col < N_real)
                    Out[(size_t)row * N_real + col] = f2bf(acc[m][n][r]);
            }
        }
    }
}

// ---------- GEMM (m97-style): Out[m,n] = sum_k A[m,k]*Bw[n,k] (+resid). bf16 in, global_load_lds staging ----------
template <bool OUT_F32, bool RESID>
__global__ __launch_bounds__(256)
void gemm_lds(const unsigned short* __restrict__ A, const unsigned short* __restrict__ Bw,
              void* __restrict__ Outp, const float* __restrict__ Resid,
              int NT, int N_real, int K, int lda) {
    __shared__ __align__(16) __bf16 As[128 * 32];
    __shared__ __align__(16) __bf16 Bs[128 * 32];

    const int tid = threadIdx.x;
    const int blk = blockIdx.x;
    const int xcd = blk & 7, j = blk >> 3;
    const int m0 = (xcd * 8 + (j & 7)) * 128;
    const int n0 = (j >> 3) * 128;

    const int wave = tid >> 6, lane = tid & 63;
    const int wm = (wave & 1) * 64, wn = (wave >> 1) * 64;
    const int lr = lane & 15, q = lane >> 4;

    const int srow = tid >> 2;
    const int scol = (tid & 3) << 3;
    const unsigned short* ag  = A + (size_t)(m0 + srow) * lda + scol;
    const unsigned short* ag2 = A + (size_t)(m0 + 64 + srow) * lda + scol;
    const unsigned short* bg  = Bw + (size_t)(n0 + srow) * K + scol;
    const unsigned short* bg2 = Bw + (size_t)(n0 + 64 + srow) * K + scol;
    __bf16* asd  = As + tid * 8;
    __bf16* asd2 = As + 2048 + tid * 8;
    __bf16* bsd  = Bs + tid * 8;
    __bf16* bsd2 = Bs + 2048 + tid * 8;

    f32x4 acc[4][4] = {};

    for (int k0 = 0; k0 < K; k0 += 32) {
        load_lds16(ag + k0, asd);
        load_lds16(ag2 + k0, asd2);
        load_lds16(bg + k0, bsd);
        load_lds16(bg2 + k0, bsd2);
        __syncthreads();

        bf16x8 af[4], bfr[4];
        #pragma unroll
        for (int t = 0; t < 4; ++t) {
            af[t]  = *(const bf16x8*)(As + (wm + t * 16 + lr) * 32 + q * 8);
            bfr[t] = *(const bf16x8*)(Bs + (wn + t * 16 + lr) * 32 + q * 8);
        }
        #pragma unroll
        for (int ti = 0; ti < 4; ++ti)
            #pragma unroll
            for (int tj = 0; tj < 4; ++tj)
                acc[ti][tj] = __builtin_amdgcn_mfma_f32_16x16x32_bf16(af[ti], bfr[tj], acc[ti][tj], 0, 0, 0);
        __syncthreads();
    }

    #pragma unroll
    for (int ti = 0; ti < 4; ++ti) {
        #pragma unroll
        for (int r = 0; r < 4; ++r) {
            int m = m0 + wm + ti * 16 + q * 4 + r;
            #pragma unroll
            for (int tj = 0; tj < 4; ++tj) {
                int n = n0 + wn + tj * 16 + lr;
                if (n < N_real) {
                    float v = acc[ti][tj][r];
                    if (RESID) v += Resid[(size_t)m * N_real + n];
                    if (OUT_F32) ((float*)Outp)[(size_t)m * N_real + n] = v;
                    else ((unsigned short*)Outp)[(size_t)m * N_real + n] = f2bf(v);
                }
            }
        }
    }
}

// ---------- fused conv(4)+silu+layout: zx xBC cols -> xT (transposed), bT (transposed), Brow/Crow (row-major), all bf16 ----------
// grid: b(4) x t-tile(32) x ch-tile(28), 256 threads. Tile 64 t x 64 ch.
__global__ __launch_bounds__(256)
void conv_fused_kernel(const unsigned short* __restrict__ zx,
                       const float* __restrict__ cw, const float* __restrict__ cb,
                       unsigned short* __restrict__ xT, unsigned short* __restrict__ bT,
                       unsigned short* __restrict__ Brow, unsigned short* __restrict__ Crow) {
    __shared__ unsigned short outt[64][66];
    __shared__ float cwl[64][4];
    __shared__ float cbl[64];

    int blk = blockIdx.x;
    int cht = blk % 28;
    int tt  = (blk / 28) % 32;
    int b   = blk / (28 * 32);
    int ch0 = cht * 64, t0 = tt * 64;
    int tid = threadIdx.x;
    int tx = tid & 63, ty = tid >> 6;

    if (tid < 64) cbl[tid] = cb[ch0 + tid];
    cwl[tid >> 2][tid & 3] = cw[(ch0 + (tid >> 2)) * 4 + (tid & 3)];
    __syncthreads();

    const unsigned short* zp = zx + (size_t)(b * 2048) * 3352 + 1536 + ch0 + tx;
    float w0 = cwl[tx][0], w1 = cwl[tx][1], w2 = cwl[tx][2], w3 = cwl[tx][3];
    float bias = cbl[tx];
    int tg = t0 + ty * 16;                 // first output t for this thread
    float r0 = (tg >= 3) ? bf2f(zp[(size_t)(tg - 3) * 3352]) : 0.f;
    float r1 = (tg >= 2) ? bf2f(zp[(size_t)(tg - 2) * 3352]) : 0.f;
    float r2 = (tg >= 1) ? bf2f(zp[(size_t)(tg - 1) * 3352]) : 0.f;
    #pragma unroll
    for (int k = 0; k < 16; ++k) {
        float cur = bf2f(zp[(size_t)(tg + k) * 3352]);
        float a = bias + r0 * w0 + r1 * w1 + r2 * w2 + cur * w3;
        a = a / (1.f + expf(-a));          // silu
        outt[ty * 16 + k][tx] = f2bf(a);
        r0 = r1; r1 = r2; r2 = cur;
    }
    __syncthreads();

    if (ch0 < 1536) {
        // x region: transposed write xT[ch][t]
        unsigned short* dst = xT + ((size_t)(b * 1536 + ch0)) * 2048 + t0;
        #pragma unroll
        for (int k = 0; k < 16; ++k) {
            int chl = ty * 16 + k;
            dst[(size_t)chl * 2048 + tx] = outt[tx][chl];
        }
    } else if (ch0 < 1664) {
        // B region: transposed bT[n][t] + row-major Brow[t][n]
        int n0 = ch0 - 1536;
        unsigned short* dstT = bT + ((size_t)(b * 128 + n0)) * 2048 + t0;
        #pragma unroll
        for (int k = 0; k < 16; ++k) {
            int chl = ty * 16 + k;
            dstT[(size_t)chl * 2048 + tx] = outt[tx][chl];
        }
        unsigned short* dstR = Brow + ((size_t)(b * 2048 + t0)) * 128 + n0;
        int tl = tid >> 3, c8 = (tid & 7) << 3;
        #pragma unroll
        for (int it = 0; it < 2; ++it) {
            int t = tl + it * 32;
            unsigned short tmp[8];
            #pragma unroll
            for (int jj = 0; jj < 8; ++jj) tmp[jj] = outt[t][c8 + jj];
            *(uint4*)(dstR + (size_t)t * 128 + c8) = *(uint4*)tmp;
        }
    } else {
        // C region: row-major Crow[t][n]
        int n0 = ch0 - 1664;
        unsigned short* dstR = Crow + ((size_t)(b * 2048 + t0)) * 128 + n0;
        int tl = tid >> 3, c8 = (tid & 7) << 3;
        #pragma unroll
        for (int it = 0; it < 2; ++it) {
            int t = tl + it * 32;
            unsigned short tmp[8];
            #pragma unroll
            for (int jj = 0; jj < 8; ++jj) tmp[jj] = outt[t][c8 + jj];
            *(uint4*)(dstR + (size_t)t * 128 + c8) = *(uint4*)tmp;
        }
    }
}

// ---------- dt in full f32 -> interleaved (dt, dt*A) float2 ----------
__global__ __launch_bounds__(64)
void dt_kernel(const float* __restrict__ x, const float* __restrict__ w_in,
               const float* __restrict__ dt_bias, const float* __restrict__ A_log,
               float2* __restrict__ dtdA) {
    int row = blockIdx.x;
    int lane = threadIdx.x;
    float xv[12];
    #pragma unroll
    for (int i = 0; i < 12; ++i) xv[i] = x[(size_t)row * 768 + i * 64 + lane];
    for (int h = 0; h < 24; ++h) {
        const float* w = w_in + (size_t)(3328 + h) * 768;
        float acc = 0.f;
        #pragma unroll
        for (int i = 0; i < 12; ++i) acc += xv[i] * w[i * 64 + lane];
        #pragma unroll
        for (int m = 1; m < 64; m <<= 1) acc += __shfl_xor(acc, m);
        if (lane == 0) {
            float v = acc + dt_bias[h];
            float dt = (v > 20.f) ? v : log1pf(expf(v));
            float A = -expf(A_log[h]);
            dtdA[(size_t)row * 24 + h] = make_float2(dt, dt * A);   // (dt, log dA)
        }
    }
}

// ---------- SSD local kernel: per (b,h,chunk): G -> M -> Y, s_out ----------
__global__ __launch_bounds__(256)
void ssd_local_kernel(const unsigned short* __restrict__ Brow,
                      const unsigned short* __restrict__ Crow,
                      const float2* __restrict__ dtdA,
                      const unsigned short* __restrict__ xT,
                      const unsigned short* __restrict__ bT,
                      const float* __restrict__ Dh,
                      float* __restrict__ yb,
                      unsigned short* __restrict__ sst,
                      float* __restrict__ Pbuf) {
    extern __shared__ __align__(16) char smem[];
    __bf16* Bs  = (__bf16*)smem;                 // 128 x SLD; later Xt(0:17408)+Xtw(17408:34816)
    __bf16* Cs  = (__bf16*)(smem + 34816);       // 128 x SLD; later Ms
    float*  Lc  = (float*)(smem + 69632);        // 128
    float*  dtl = (float*)(smem + 70144);        // 128

    const int tid = threadIdx.x;
    const int c   = blockIdx.x & 15;
    const int bh  = blockIdx.x >> 4;
    const int b   = bh / 24, h = bh % 24;
    const int t0g = b * 2048 + c * QCHUNK;
    const int wave = tid >> 6, lane = tid & 63;
    const int lr = lane & 15, q = lane >> 4;

    for (int cc = tid; cc < 2048; cc += 256) {
        int r = cc >> 4, c8 = (cc & 15) << 3;
        *(uint4*)(Bs + r * SLD + c8) = *(const uint4*)(Brow + ((size_t)(t0g + r)) * 128 + c8);
        *(uint4*)(Cs + r * SLD + c8) = *(const uint4*)(Crow + ((size_t)(t0g + r)) * 128 + c8);
    }
    if (tid < 128) {
        float2 dd = dtdA[((size_t)t0g + tid) * 24 + h];
        dtl[tid] = dd.x;
        Lc[tid]  = dd.y;     // log dA
    }
    __syncthreads();
    for (int off = 1; off < 128; off <<= 1) {
        float v = 0.f;
        if (tid < 128 && tid >= off) v = Lc[tid - off];
        __syncthreads();
        if (tid < 128) Lc[tid] += v;
        __syncthreads();
    }

    // P1: G = Cs . Bs^T
    const int wm = (wave & 1) * 64, wn = (wave >> 1) * 64;
    f32x4 g[4][4] = {};
    #pragma unroll
    for (int k0 = 0; k0 < 128; k0 += 32) {
        bf16x8 af[4], bfr[4];
        #pragma unroll
        for (int t = 0; t < 4; ++t) {
            af[t]  = *(const bf16x8*)(Cs + (wm + t * 16 + lr) * SLD + k0 + q * 8);
            bfr[t] = *(const bf16x8*)(Bs + (wn + t * 16 + lr) * SLD + k0 + q * 8);
        }
        #pragma unroll
        for (int ti = 0; ti < 4; ++ti)
            #pragma unroll
            for (int tj = 0; tj < 4; ++tj)
                g[ti][tj] = __builtin_amdgcn_mfma_f32_16x16x32_bf16(af[ti], bfr[tj], g[ti][tj], 0, 0, 0);
    }
    __syncthreads();

    // P5: masked scale -> Ms[t][tau]
    __bf16* Ms = Cs;
    {
        float lt_[4], dt_[4];
        #pragma unroll
        for (int tj = 0; tj < 4; ++tj) {
            int tau = wn + tj * 16 + lr;
            lt_[tj] = Lc[tau];
            dt_[tj] = dtl[tau];
        }
        #pragma unroll
        for (int ti = 0; ti < 4; ++ti) {
            #pragma unroll
            for (int r = 0; r < 4; ++r) {
                int t = wm + ti * 16 + q * 4 + r;
                float Lt = Lc[t];
                #pragma unroll
                for (int tj = 0; tj < 4; ++tj) {
                    int tau = wn + tj * 16 + lr;
                    float mv = (tau <= t) ? g[ti][tj][r] * expf(Lt - lt_[tj]) * dt_[tj] : 0.f;
                    unsigned short u = f2bf(mv);
                    Ms[t * SLD + tau] = *(__bf16*)&u;
                }
            }
        }
    }

    // P3: stage Xt[p][t] and Xtw[p][t]
    __bf16* Xt  = Bs;
    __bf16* Xtw = (__bf16*)(smem + 17408);
    {
        float LQ = Lc[127];
        const unsigned short* xTb = xT + ((size_t)(b * 1536 + h * 64)) * 2048 + c * QCHUNK;
        for (int cc = tid; cc < 1024; cc += 256) {
            int p = cc >> 4, c8 = (cc & 15) << 3;
            uint4 v = *(const uint4*)(xTb + (size_t)p * 2048 + c8);
            *(uint4*)(Xt + p * SLD + c8) = v;
            unsigned short uu[8] = {(unsigned short)(v.x & 0xFFFF), (unsigned short)(v.x >> 16),
                                    (unsigned short)(v.y & 0xFFFF), (unsigned short)(v.y >> 16),
                                    (unsigned short)(v.z & 0xFFFF), (unsigned short)(v.z >> 16),
                                    (unsigned short)(v.w & 0xFFFF), (unsigned short)(v.w >> 16)};
            float w0[8];
            #pragma unroll
            for (int jj = 0; jj < 8; ++jj) {
                int tau = c8 + jj;
                w0[jj] = bf2f(uu[jj]) * expf(LQ - Lc[tau]) * dtl[tau];
            }
            *(uint4*)(Xtw + p * SLD + c8) = pack8(make_float4(w0[0], w0[1], w0[2], w0[3]),
                                                  make_float4(w0[4], w0[5], w0[6], w0[7]));
        }
    }
    __syncthreads();

    // P4: s_out[n][p] = bT . Xtw^T
    {
        f32x4 so[2][4] = {};
        const unsigned short* bTb = bT + ((size_t)(b * 128)) * 2048 + c * QCHUNK;
        #pragma unroll
        for (int k0 = 0; k0 < 128; k0 += 32) {
            bf16x8 af[2], bfr[4];
            #pragma unroll
            for (int ti = 0; ti < 2; ++ti) {
                int n = wave * 32 + ti * 16 + lr;
                af[ti] = *(const bf16x8*)(bTb + (size_t)n * 2048 + k0 + q * 8);
            }
            #pragma unroll
            for (int tj = 0; tj < 4; ++tj)
                bfr[tj] = *(const bf16x8*)(Xtw + (tj * 16 + lr) * SLD + k0 + q * 8);
            #pragma unroll
            for (int ti = 0; ti < 2; ++ti)
                #pragma unroll
                for (int tj = 0; tj < 4; ++tj)
                    so[ti][tj] = __builtin_amdgcn_mfma_f32_16x16x32_bf16(af[ti], bfr[tj], so[ti][tj], 0, 0, 0);
        }
        unsigned short* sb = sst + ((size_t)(bh * NCHUNK + c)) * 8192;
        #pragma unroll
        for (int ti = 0; ti < 2; ++ti) {
            #pragma unroll
            for (int r = 0; r < 4; ++r) {
                int n = wave * 32 + ti * 16 + q * 4 + r;
                #pragma unroll
                for (int tj = 0; tj < 4; ++tj) {
                    int p = tj * 16 + lr;
                    sb[n * 64 + p] = f2bf(so[ti][tj][r]);
                }
            }
        }
        if (tid == 0) Pbuf[bh * NCHUNK + c] = expf(Lc[127]);
    }

    // P6: Y[t][p] = Ms . Xt^T  (+ D skip)
    {
        f32x4 ya[2][4] = {};
        #pragma unroll
        for (int k0 = 0; k0 < 128; k0 += 32) {
            bf16x8 af[2], bfr[4];
            #pragma unroll
            for (int ti = 0; ti < 2; ++ti)
                af[ti] = *(const bf16x8*)(Ms + (wave * 32 + ti * 16 + lr) * SLD + k0 + q * 8);
            #pragma unroll
            for (int tj = 0; tj < 4; ++tj)
                bfr[tj] = *(const bf16x8*)(Xt + (tj * 16 + lr) * SLD + k0 + q * 8);
            #pragma unroll
            for (int ti = 0; ti < 2; ++ti)
                #pragma unroll
                for (int tj = 0; tj < 4; ++tj)
                    ya[ti][tj] = __builtin_amdgcn_mfma_f32_16x16x32_bf16(af[ti], bfr[tj], ya[ti][tj], 0, 0, 0);
        }
        float Dv = Dh[h];
        float* ybb = yb + (size_t)t0g * 1536 + h * 64;
        #pragma unroll
        for (int ti = 0; ti < 2; ++ti) {
            #pragma unroll
            for (int r = 0; r < 4; ++r) {
                int t = wave * 32 + ti * 16 + q * 4 + r;
                #pragma unroll
                for (int tj = 0; tj < 4; ++tj) {
                    int p = tj * 16 + lr;
                    __bf16 xb = Xt[p * SLD + t];
                    float xv = bf2f(*(unsigned short*)&xb);
                    ybb[(size_t)t * 1536 + p] = ya[ti][tj][r] + Dv * xv;
                }
            }
        }
    }
}

// ---------- combine ----------
__global__ __launch_bounds__(256)
void combine_kernel(const unsigned short* __restrict__ sst,
                    unsigned short* __restrict__ sstT,
                    const float* __restrict__ Pbuf) {
    int flat = blockIdx.x * 256 + threadIdx.x;
    int bh = flat >> 13;
    int pn = flat & 8191;
    int n = pn >> 6, p = pn & 63;
    const unsigned short* sb = sst + (size_t)bh * NCHUNK * 8192;
    unsigned short* tb = sstT + (size_t)bh * NCHUNK * 8192 + p * 128 + n;
    const float* Pb = Pbuf + bh * NCHUNK;
    float s = 0.f;
    #pragma unroll
    for (int c = 0; c < NCHUNK; ++c) {
        float tmp = bf2f(sb[(size_t)c * 8192 + pn]);
        tb[(size_t)c * 8192] = f2bf(s);
        s = Pb[c] * s + tmp;
    }
}

// ---------- SSD inter kernel ----------
__global__ __launch_bounds__(256)
void ssd_inter_kernel(const unsigned short* __restrict__ Crow,
                      const float2* __restrict__ dtdA,
                      const unsigned short* __restrict__ sstT,
                      float* __restrict__ yb) {
    __shared__ __align__(16) __bf16 Cs[128 * SLD];
    __shared__ __align__(16) __bf16 St[64 * SLD];
    __shared__ float Lc[128];

    const int tid = threadIdx.x;
    const int blk = blockIdx.x;
    const int bh = blk / 15;
    const int c  = blk % 15 + 1;
    const int b = bh / 24, h = bh % 24;
    const int t0g = b * 2048 + c * QCHUNK;
    const int wave = tid >> 6, lane = tid & 63;
    const int lr = lane & 15, q = lane >> 4;

    for (int cc = tid; cc < 2048; cc += 256) {
        int r = cc >> 4, c8 = (cc & 15) << 3;
        *(uint4*)(Cs + r * SLD + c8) = *(const uint4*)(Crow + ((size_t)(t0g + r)) * 128 + c8);
    }
    const unsigned short* stb = sstT + ((size_t)(bh * NCHUNK + c)) * 8192;
    for (int cc = tid; cc < 1024; cc += 256) {
        int p = cc >> 4, c8 = (cc & 15) << 3;
        *(uint4*)(St + p * SLD + c8) = *(const uint4*)(stb + p * 128 + c8);
    }
    if (tid < 128) Lc[tid] = dtdA[((size_t)t0g + tid) * 24 + h].y;
    __syncthreads();
    for (int off = 1; off < 128; off <<= 1) {
        float v = 0.f;
        if (tid < 128 && tid >= off) v = Lc[tid - off];
        __syncthreads();
        if (tid < 128) Lc[tid] += v;
        __syncthreads();
    }

    f32x4 ya[2][4] = {};
    #pragma unroll
    for (int k0 = 0; k0 < 128; k0 += 32) {
        bf16x8 af[2], bfr[4];
        #pragma unroll
        for (int ti = 0; ti < 2; ++ti)
            af[ti] = *(const bf16x8*)(Cs + (wave * 32 + ti * 16 + lr) * SLD + k0 + q * 8);
        #pragma unroll
        for (int tj = 0; tj < 4; ++tj)
            bfr[tj] = *(const bf16x8*)(St + (tj * 16 + lr) * SLD + k0 + q * 8);
        #pragma unroll
        for (int ti = 0; ti < 2; ++ti)
            #pragma unroll
            for (int tj = 0; tj < 4; ++tj)
                ya[ti][tj] = __builtin_amdgcn_mfma_f32_16x16x32_bf16(af[ti], bfr[tj], ya[ti][tj], 0, 0, 0);
    }
    float* ybb = yb + (size_t)t0g * 1536 + h * 64;
    #pragma unroll
    for (int ti = 0; ti < 2; ++ti) {
        #pragma unroll
        for (int r = 0; r < 4; ++r) {
            int t = wave * 32 + ti * 16 + q * 4 + r;
            float sc = expf(Lc[t]);
            #pragma unroll
            for (int tj = 0; tj < 4; ++tj) {
                int p = tj * 16 + lr;
                float* yp = ybb + (size_t)t * 1536 + p;
                *yp = *yp + sc * ya[ti][tj][r];
            }
        }
    }
}

// ---------- gated RMSNorm: writes bf16 into zx cols [1536,3072) ----------
__global__ __launch_bounds__(256)
void norm_kernel(const float* __restrict__ yb,
                 unsigned short* __restrict__ zx,
                 const float* __restrict__ nw) {
    int row = blockIdx.x;
    const float* yr = yb + (size_t)row * 1536;
    unsigned short* zr = zx + (size_t)row * 3352;
    int tid = threadIdx.x;
    float u[6];
    float ss = 0.f;
    #pragma unroll
    for (int i = 0; i < 6; ++i) {
        int c = tid + i * 256;
        float z = bf2f(zr[c]);
        float uu = yr[c] * (z / (1.f + expf(-z)));
        u[i] = uu;
        ss += uu * uu;
    }
    #pragma unroll
    for (int m = 1; m < 64; m <<= 1) ss += __shfl_xor(ss, m);
    __shared__ float red[4];
    if ((tid & 63) == 0) red[tid >> 6] = ss;
    __syncthreads();
    float tot = red[0] + red[1] + red[2] + red[3];
    float inv = rsqrtf(tot * (1.f / 1536.f) + 1e-5f);
    #pragma unroll
    for (int i = 0; i < 6; ++i) {
        int c = tid + i * 256;
        zr[1536 + c] = f2bf(u[i] * inv * nw[c]);
    }
}

// ---------- launch ----------
extern "C" void kernel_launch(void* const* d_in, const int* in_sizes, int n_in,
                              void* d_out, int out_size, void* d_ws, size_t ws_size,
                              hipStream_t stream) {
    const float* x       = (const float*)d_in[0];
    const float* w_in    = (const float*)d_in[1];
    const float* conv_w  = (const float*)d_in[2];
    const float* conv_b  = (const float*)d_in[3];
    const float* dt_bias = (const float*)d_in[4];
    const float* A_log   = (const float*)d_in[5];
    const float* Dp      = (const float*)d_in[6];
    const float* nw      = (const float*)d_in[7];
    const float* w_out   = (const float*)d_in[8];
    float* out = (float*)d_out;

    char* ws = (char*)d_ws;
    const size_t off_zx   = 0;                        // 8192*3352 bf16 = 54,919,168
    const size_t off_A    = off_zx + 54919168;        // region A (58,720,256 reserved)
    const size_t off_xT   = off_A;                    // 25,165,824 (sstT + w_out_bf alias later)
    const size_t off_bT   = off_A + 25165824;         // 2,097,152
    const size_t off_Brow = off_A + 27262976;         // 2,097,152
    const size_t off_Crow = off_A + 29360128;         // 2,097,152
    const size_t off_dtdA = off_A + 58720256;         // 1,572,864
    const size_t off_y    = off_dtdA + 1572864;       // 50,331,648 (x_bf aliases head)
    const size_t off_sst  = off_y + 50331648;         // 25,165,824 (w_in_bf aliases head)
    const size_t off_P    = off_sst + 25165824;       // 6,144

    unsigned short* zx   = (unsigned short*)(ws + off_zx);
    unsigned short* xT   = (unsigned short*)(ws + off_xT);
    unsigned short* bT   = (unsigned short*)(ws + off_bT);
    unsigned short* Brow = (unsigned short*)(ws + off_Brow);
    unsigned short* Crow = (unsigned short*)(ws + off_Crow);
    float2* dtdA = (float2*)(ws + off_dtdA);
    float* yb    = (float*)(ws + off_y);
    unsigned short* sst  = (unsigned short*)(ws + off_sst);
    unsigned short* sstT = xT;                        // xT dead after ssd_local
    float* Pbuf = (float*)(ws + off_P);

    // transient aliases (dead regions at time of use)
    unsigned short* x_bf     = (unsigned short*)(ws + off_y);    // gemm1 only (before yb written)
    unsigned short* w_in_bf  = (unsigned short*)(ws + off_sst);  // gemm1 only (before sst written)
    unsigned short* w_out_bf = (unsigned short*)(ws + off_xT);   // written after sstT dead (step 7.5)

    static bool attr_set = false;
    if (!attr_set) {
        hipFuncSetAttribute((const void*)ssd_local_kernel,
                            hipFuncAttributeMaxDynamicSharedMemorySize, 70656);
        hipFuncSetAttribute((const void*)gemm_8phase,
                            hipFuncAttributeMaxDynamicSharedMemorySize, 131072);
        attr_set = true;
    }

    // 0. convert x, w_in (padded to 3584 rows) -> bf16
    convert_kernel<<<4416, 256, 0, stream>>>(x, w_in, x_bf, w_in_bf);
    // 1. in_proj (M=8192, N=3352 padded 3584, K=768) — 256x256 phase-split pipeline
    gemm_8phase<<<448, 512, 131072, stream>>>(x_bf, w_in_bf, zx, 3352, 768);
    // 2. fused conv + silu + layout (replaces conv_silu + transpose; cv eliminated)
    conv_fused_kernel<<<3584, 256, 0, stream>>>(zx, conv_w, conv_b, xT, bT, Brow, Crow);
    // 3. dt / log-dA (full f32)
    dt_kernel<<<8192, 64, 0, stream>>>(x, w_in, dt_bias, A_log, dtdA);
    // 4. SSD local
    ssd_local_kernel<<<1536, 256, 70656, stream>>>(Brow, Crow, dtdA, xT, bT, Dp, yb, sst, Pbuf);
    // 5. combine
    combine_kernel<<<3072, 256, 0, stream>>>(sst, sstT, Pbuf);
    // 6. SSD inter
    ssd_inter_kernel<<<1440, 256, 0, stream>>>(Crow, dtdA, sstT, yb);
    // 6.5 convert w_out -> bf16 (xT/sstT region dead now)
    convert_wout_kernel<<<576, 256, 0, stream>>>(w_out, w_out_bf);
    // 7. gated RMSNorm -> bf16 into zx cols [1536,3072)
    norm_kernel<<<8192, 256, 0, stream>>>(yb, zx, nw);
    // 8. out_proj + residual
    gemm_lds<true, true><<<64 * 6, 256, 0, stream>>>(zx + 1536, w_out_bf, out, x, 6, 768, 1536, 3352);
}

// Round 2
// 411.602 us; speedup vs baseline: 1.1036x; 1.0716x over previous
//
#include <hip/hip_runtime.h>
#include <math.h>

// ---------- types ----------
typedef __bf16 bf16x8 __attribute__((ext_vector_type(8)));
typedef float  f32x4  __attribute__((ext_vector_type(4)));

#define QCHUNK 128
#define NCHUNK 16
#define SLD 136              // LDS row stride (bf16 elems) for 128-wide arrays

__device__ __forceinline__ float bf2f(unsigned short u) {
    union { unsigned int i; float f; } v; v.i = ((unsigned int)u) << 16; return v.f;
}
__device__ __forceinline__ unsigned short f2bf(float f) {
    union { float f; unsigned int i; } v; v.f = f;
    unsigned int x = v.i;
    unsigned int r = (x + 0x7FFFu + ((x >> 16) & 1u)) >> 16;
    return (unsigned short)r;
}
__device__ __forceinline__ uint4 pack8(float4 a, float4 b) {
    uint4 r;
    r.x = (unsigned)f2bf(a.x) | ((unsigned)f2bf(a.y) << 16);
    r.y = (unsigned)f2bf(a.z) | ((unsigned)f2bf(a.w) << 16);
    r.z = (unsigned)f2bf(b.x) | ((unsigned)f2bf(b.y) << 16);
    r.w = (unsigned)f2bf(b.z) | ((unsigned)f2bf(b.w) << 16);
    return r;
}
__device__ __forceinline__ void load_lds16(const void* g, void* l) {
    __builtin_amdgcn_global_load_lds((const __attribute__((address_space(1))) void*)g,
                                     (__attribute__((address_space(3))) void*)l,
                                     16, 0, 0);
}

// ---------- convert: x -> x_bf, w_in -> w_in_bf (padded 3584 rows, zero-filled) ----------
__global__ __launch_bounds__(256)
void convert_kernel(const float* __restrict__ x, const float* __restrict__ w_in,
                    unsigned short* __restrict__ x_bf, unsigned short* __restrict__ w_in_bf) {
    int idx = blockIdx.x * 256 + threadIdx.x;      // 8 elems each
    const int NX  = 8192 * 768 / 8;                // 786432
    const int NW1 = 3584 * 768 / 8;                // 344064 (padded to 14x256 tiles)
    const int NW1r = 3352 * 768 / 8;               // 321792 (real)
    if (idx < NX) {
        const float* s = x + (size_t)idx * 8;
        *(uint4*)(x_bf + (size_t)idx * 8) = pack8(*(const float4*)s, *(const float4*)(s + 4));
    } else if (idx < NX + NW1) {
        int j = idx - NX;
        uint4 v = make_uint4(0u, 0u, 0u, 0u);
        if (j < NW1r) {
            const float* s = w_in + (size_t)j * 8;
            v = pack8(*(const float4*)s, *(const float4*)(s + 4));
        }
        *(uint4*)(w_in_bf + (size_t)j * 8) = v;
    }
}

// ---------- convert w_out -> bf16 ----------
__global__ __launch_bounds__(256)
void convert_wout_kernel(const float* __restrict__ w_out, unsigned short* __restrict__ w_out_bf) {
    int idx = blockIdx.x * 256 + threadIdx.x;      // 147456 total
    const float* s = w_out + (size_t)idx * 8;
    *(uint4*)(w_out_bf + (size_t)idx * 8) = pack8(*(const float4*)s, *(const float4*)(s + 4));
}

// ---------- 256x256 phase-split GEMM (T2+T3+T4+T5): Out[m,n] = sum_k A[m,k]*Bw[n,k], bf16 out ----------
// 512 threads = 8 waves (2 wr x 4 wc); per-wave output 128x64; BK=64 in two k-half phases.
// LDS: A[2 dbuf][2 kh][256][32] bf16 @0 (64KB), B same @65536 (64KB) = 128 KiB.
// Swizzle: 16B k-slot kb stored at kb^(r&3); applied on BOTH global-source and ds_read side.
// Schedule per phase: vmcnt(4); s_barrier; 12x ds_read_b128; issue 4x global_load_lds(next
// tile k-half); setprio(1); 32 MFMA; setprio(0).  vmcnt never drains to 0 in the main loop.
__global__ __launch_bounds__(512)
void gemm_8phase(const unsigned short* __restrict__ A,
                 const unsigned short* __restrict__ Bw,
                 unsigned short* __restrict__ Out,
                 int N_real, int K) {
    extern __shared__ __align__(16) char smem[];

    const int tid = threadIdx.x;
    const int bid = blockIdx.x;
    // XCD-chunked swizzle: 448 blocks = 8 XCDs x 56; m-fastest within chunk (B-panel L2 reuse)
    const int swz = (bid & 7) * 56 + (bid >> 3);
    const int m0 = (swz & 31) * 256;
    const int n0 = (swz >> 5) * 256;

    const int wave = tid >> 6, lane = tid & 63;
    const int wr = wave >> 2, wc = wave & 3;
    const int lr = lane & 15, q = lane >> 4;

    // ds_read lane offsets (bytes): row*64 + swizzled-slot*16
    const int sw   = ((q ^ (lr & 3)) << 4);
    const int aoff = (wr * 128 + lr) * 64 + sw;
    const int boff = 65536 + (wc * 64 + lr) * 64 + sw;

    // staging: thread tid covers LDS linear slot (r=tid>>2, kb=tid&3) of an 8KB j-chunk;
    // global source pre-swizzled so linear LDS + swizzled read = identity.
    const int srow = tid >> 2;                 // 0..127
    const int skb  = (tid & 3) ^ (srow & 3);   // swizzled k-slot
    const unsigned short* ga0 = A  + (size_t)(m0 + srow) * K       + skb * 8;
    const unsigned short* ga1 = A  + (size_t)(m0 + 128 + srow) * K + skb * 8;
    const unsigned short* gb0 = Bw + (size_t)(n0 + srow) * K       + skb * 8;
    const unsigned short* gb1 = Bw + (size_t)(n0 + 128 + srow) * K + skb * 8;
    char* sA0 = smem +              (size_t)tid * 16;   // rows 0-127
    char* sA1 = smem +       8192 + (size_t)tid * 16;   // rows 128-255
    char* sB0 = smem + 65536 +      (size_t)tid * 16;
    char* sB1 = smem + 65536 + 8192 + (size_t)tid * 16;

    const int NT = K >> 6;
    f32x4 acc[8][4] = {};

    // prologue: tile0 k-half0 then k-half1 into dbuf0 (8 loads, grouped by k-half)
    load_lds16(ga0 + 0,  sA0 + 0);
    load_lds16(ga1 + 0,  sA1 + 0);
    load_lds16(gb0 + 0,  sB0 + 0);
    load_lds16(gb1 + 0,  sB1 + 0);
    load_lds16(ga0 + 32, sA0 + 16384);
    load_lds16(ga1 + 32, sA1 + 16384);
    load_lds16(gb0 + 32, sB0 + 16384);
    load_lds16(gb1 + 32, sB1 + 16384);

    for (int t = 0; t < NT; ++t) {
        const int d = t & 1;
        const char* pbase = smem + d * 32768;
        const int sdst = (d ^ 1) * 32768;
        const int kt = (t + 1) << 6;           // next tile's k base (elements)
        const bool more = (t + 1 < NT);
        #pragma unroll
        for (int kh = 0; kh < 2; ++kh) {
            // gate: oldest 4 outstanding = this phase's k-half (issued 2 phases ago)
            if (more || kh == 0) asm volatile("s_waitcnt vmcnt(4)" ::: "memory");
            else                 asm volatile("s_waitcnt vmcnt(0)" ::: "memory");
            __builtin_amdgcn_s_barrier();

            const char* pa = pbase + kh * 16384 + aoff;
            const char* pb = pbase + kh * 16384 + boff;
            bf16x8 af[8], bfr[4];
            #pragma unroll
            for (int m = 0; m < 8; ++m) af[m]  = *(const bf16x8*)(pa + m * 1024);
            #pragma unroll
            for (int n = 0; n < 4; ++n) bfr[n] = *(const bf16x8*)(pb + n * 1024);

            if (more) {                         // stage next tile's same k-half -> other dbuf
                const int kg = kt + kh * 32;
                const int ld = sdst + kh * 16384;
                load_lds16(ga0 + kg, sA0 + ld);
                load_lds16(ga1 + kg, sA1 + ld);
                load_lds16(gb0 + kg, sB0 + ld);
                load_lds16(gb1 + kg, sB1 + ld);
            }

            __builtin_amdgcn_s_setprio(1);
            #pragma unroll
            for (int m = 0; m < 8; ++m)
                #pragma unroll
                for (int n = 0; n < 4; ++n)
                    acc[m][n] = __builtin_amdgcn_mfma_f32_16x16x32_bf16(af[m], bfr[n], acc[m][n], 0, 0, 0);
            __builtin_amdgcn_s_setprio(0);
        }
    }

    // epilogue: C/D layout col=lane&15, row=(lane>>4)*4+reg
    #pragma unroll
    for (int m = 0; m < 8; ++m) {
        #pragma unroll
        for (int r = 0; r < 4; ++r) {
            int row = m0 + wr * 128 + m * 16 + q * 4 + r;
            #pragma unroll
            for (int n = 0; n < 4; ++n) {
                int col = n0 + wc * 64 + n * 16 + lr;
                if (col < N_real)
                    Out[(size_t)row * N_real + col] = f2bf(acc[m][n][r]);
            }
        }
    }
}

// ---------- out_proj GEMM: Out[m,n] = sum_k A[m,k]*Bw[n,k] + Resid, f32 out ----------
// M=8192, N=768, K=1536. BM=BN=128, 512 threads = 8 waves (2 wr x 4 wc), per-wave 64x32.
// LDS: [2 dbuf][2 kh][A 128x32 | B 128x32] bf16 = 64 KiB -> 2 blocks/CU; 384 blocks all
// co-resident (12 waves/CU). Counted-vmcnt pipeline: gate vmcnt(2), never 0 mid-loop.
__global__ __launch_bounds__(512)
void gemm_out(const unsigned short* __restrict__ A,
              const unsigned short* __restrict__ Bw,
              float* __restrict__ Out, const float* __restrict__ Resid,
              int lda) {
    extern __shared__ __align__(16) char smem[];
    const int K = 1536, Nn = 768;

    const int tid = threadIdx.x;
    const int bid = blockIdx.x;
    // XCD-chunked: 384 = 8 x 48; within chunk n-fastest (A-panel reuse across 6 n-tiles)
    const int xcd = bid & 7, local = bid >> 3;
    const int mt = xcd * 8 + local / 6;        // 0..63
    const int nt = local % 6;                  // 0..5
    const int m0 = mt * 128, n0 = nt * 128;

    const int wave = tid >> 6, lane = tid & 63;
    const int wr = wave >> 2, wc = wave & 3;
    const int lr = lane & 15, q = lane >> 4;

    // ds_read offsets (bytes): row*64 + swizzled 16B slot (uniform over 8 bank-groups)
    const int sw   = ((q ^ (lr & 3)) << 4);
    const int aoff = (wr * 64 + lr) * 64 + sw;
    const int boff = 8192 + (wc * 32 + lr) * 64 + sw;

    // staging: linear LDS dest, pre-swizzled global source
    const int srow = tid >> 2;                 // 0..127
    const int skb  = (tid & 3) ^ (srow & 3);
    const unsigned short* ga = A  + (size_t)(m0 + srow) * lda + skb * 8;
    const unsigned short* gb = Bw + (size_t)(n0 + srow) * K   + skb * 8;
    char* sAd = smem +        (size_t)tid * 16;
    char* sBd = smem + 8192 + (size_t)tid * 16;

    f32x4 acc[4][2] = {};

    // prologue: tile0 kh0 (A,B) then kh1 (A,B)   [region = d*32768 + kh*16384]
    load_lds16(ga + 0,  sAd + 0);
    load_lds16(gb + 0,  sBd + 0);
    load_lds16(ga + 32, sAd + 16384);
    load_lds16(gb + 32, sBd + 16384);

    const int NT = K >> 6;   // 24
    for (int t = 0; t < NT; ++t) {
        const int d = t & 1;
        const char* pbase = smem + d * 32768;
        const int sdst = (d ^ 1) * 32768;
        const int kt = (t + 1) << 6;
        const bool more = (t + 1 < NT);
        #pragma unroll
        for (int kh = 0; kh < 2; ++kh) {
            if (more || kh == 0) asm volatile("s_waitcnt vmcnt(2)" ::: "memory");
            else                 asm volatile("s_waitcnt vmcnt(0)" ::: "memory");
            __builtin_amdgcn_s_barrier();

            const char* pa = pbase + kh * 16384 + aoff;
            const char* pb = pbase + kh * 16384 + boff;
            bf16x8 af[4], bfr[2];
            #pragma unroll
            for (int m = 0; m < 4; ++m) af[m]  = *(const bf16x8*)(pa + m * 1024);
            #pragma unroll
            for (int n = 0; n < 2; ++n) bfr[n] = *(const bf16x8*)(pb + n * 1024);

            if (more) {                         // stage tile t+1, same kh -> other dbuf
                const int kg = kt + kh * 32;
                const int ld = sdst + kh * 16384;
                load_lds16(ga + kg, sAd + ld);
                load_lds16(gb + kg, sBd + ld);
            }

            __builtin_amdgcn_s_setprio(1);
            #pragma unroll
            for (int m = 0; m < 4; ++m)
                #pragma unroll
                for (int n = 0; n < 2; ++n)
                    acc[m][n] = __builtin_amdgcn_mfma_f32_16x16x32_bf16(af[m], bfr[n], acc[m][n], 0, 0, 0);
            __builtin_amdgcn_s_setprio(0);
        }
    }

    // epilogue: f32 out + residual (N=768 = 6x128 exactly, no masking)
    #pragma unroll
    for (int m = 0; m < 4; ++m) {
        #pragma unroll
        for (int r = 0; r < 4; ++r) {
            int row = m0 + wr * 64 + m * 16 + q * 4 + r;
            #pragma unroll
            for (int n = 0; n < 2; ++n) {
                int col = n0 + wc * 32 + n * 16 + lr;
                Out[(size_t)row * Nn + col] = acc[m][n][r] + Resid[(size_t)row * Nn + col];
            }
        }
    }
}

// ---------- fused conv(4)+silu+layout: zx xBC cols -> xT (transposed), bT (transposed), Brow/Crow (row-major), all bf16 ----------
// grid: b(4) x t-tile(32) x ch-tile(28), 256 threads. Tile 64 t x 64 ch.
__global__ __launch_bounds__(256)
void conv_fused_kernel(const unsigned short* __restrict__ zx,
                       const float* __restrict__ cw, const float* __restrict__ cb,
                       unsigned short* __restrict__ xT, unsigned short* __restrict__ bT,
                       unsigned short* __restrict__ Brow, unsigned short* __restrict__ Crow) {
    __shared__ unsigned short outt[64][66];
    __shared__ float cwl[64][4];
    __shared__ float cbl[64];

    int blk = blockIdx.x;
    int cht = blk % 28;
    int tt  = (blk / 28) % 32;
    int b   = blk / (28 * 32);
    int ch0 = cht * 64, t0 = tt * 64;
    int tid = threadIdx.x;
    int tx = tid & 63, ty = tid >> 6;

    if (tid < 64) cbl[tid] = cb[ch0 + tid];
    cwl[tid >> 2][tid & 3] = cw[(ch0 + (tid >> 2)) * 4 + (tid & 3)];
    __syncthreads();

    const unsigned short* zp = zx + (size_t)(b * 2048) * 3352 + 1536 + ch0 + tx;
    float w0 = cwl[tx][0], w1 = cwl[tx][1], w2 = cwl[tx][2], w3 = cwl[tx][3];
    float bias = cbl[tx];
    int tg = t0 + ty * 16;                 // first output t for this thread
    float r0 = (tg >= 3) ? bf2f(zp[(size_t)(tg - 3) * 3352]) : 0.f;
    float r1 = (tg >= 2) ? bf2f(zp[(size_t)(tg - 2) * 3352]) : 0.f;
    float r2 = (tg >= 1) ? bf2f(zp[(size_t)(tg - 1) * 3352]) : 0.f;
    #pragma unroll
    for (int k = 0; k < 16; ++k) {
        float cur = bf2f(zp[(size_t)(tg + k) * 3352]);
        float a = bias + r0 * w0 + r1 * w1 + r2 * w2 + cur * w3;
        a = a / (1.f + expf(-a));          // silu
        outt[ty * 16 + k][tx] = f2bf(a);
        r0 = r1; r1 = r2; r2 = cur;
    }
    __syncthreads();

    if (ch0 < 1536) {
        // x region: transposed write xT[ch][t]
        unsigned short* dst = xT + ((size_t)(b * 1536 + ch0)) * 2048 + t0;
        #pragma unroll
        for (int k = 0; k < 16; ++k) {
            int chl = ty * 16 + k;
            dst[(size_t)chl * 2048 + tx] = outt[tx][chl];
        }
    } else if (ch0 < 1664) {
        // B region: transposed bT[n][t] + row-major Brow[t][n]
        int n0 = ch0 - 1536;
        unsigned short* dstT = bT + ((size_t)(b * 128 + n0)) * 2048 + t0;
        #pragma unroll
        for (int k = 0; k < 16; ++k) {
            int chl = ty * 16 + k;
            dstT[(size_t)chl * 2048 + tx] = outt[tx][chl];
        }
        unsigned short* dstR = Brow + ((size_t)(b * 2048 + t0)) * 128 + n0;
        int tl = tid >> 3, c8 = (tid & 7) << 3;
        #pragma unroll
        for (int it = 0; it < 2; ++it) {
            int t = tl + it * 32;
            unsigned short tmp[8];
            #pragma unroll
            for (int jj = 0; jj < 8; ++jj) tmp[jj] = outt[t][c8 + jj];
            *(uint4*)(dstR + (size_t)t * 128 + c8) = *(uint4*)tmp;
        }
    } else {
        // C region: row-major Crow[t][n]
        int n0 = ch0 - 1664;
        unsigned short* dstR = Crow + ((size_t)(b * 2048 + t0)) * 128 + n0;
        int tl = tid >> 3, c8 = (tid & 7) << 3;
        #pragma unroll
        for (int it = 0; it < 2; ++it) {
            int t = tl + it * 32;
            unsigned short tmp[8];
            #pragma unroll
            for (int jj = 0; jj < 8; ++jj) tmp[jj] = outt[t][c8 + jj];
            *(uint4*)(dstR + (size_t)t * 128 + c8) = *(uint4*)tmp;
        }
    }
}

// ---------- dt in full f32 -> interleaved (dt, dt*A) float2 ----------
__global__ __launch_bounds__(64)
void dt_kernel(const float* __restrict__ x, const float* __restrict__ w_in,
               const float* __restrict__ dt_bias, const float* __restrict__ A_log,
               float2* __restrict__ dtdA) {
    int row = blockIdx.x;
    int lane = threadIdx.x;
    float xv[12];
    #pragma unroll
    for (int i = 0; i < 12; ++i) xv[i] = x[(size_t)row * 768 + i * 64 + lane];
    for (int h = 0; h < 24; ++h) {
        const float* w = w_in + (size_t)(3328 + h) * 768;
        float acc = 0.f;
        #pragma unroll
        for (int i = 0; i < 12; ++i) acc += xv[i] * w[i * 64 + lane];
        #pragma unroll
        for (int m = 1; m < 64; m <<= 1) acc += __shfl_xor(acc, m);
        if (lane == 0) {
            float v = acc + dt_bias[h];
            float dt = (v > 20.f) ? v : log1pf(expf(v));
            float A = -expf(A_log[h]);
            dtdA[(size_t)row * 24 + h] = make_float2(dt, dt * A);   // (dt, log dA)
        }
    }
}

// ---------- SSD local kernel: per (b,h,chunk): G -> M -> Y, s_out ----------
__global__ __launch_bounds__(256)
void ssd_local_kernel(const unsigned short* __restrict__ Brow,
                      const unsigned short* __restrict__ Crow,
                      const float2* __restrict__ dtdA,
                      const unsigned short* __restrict__ xT,
                      const unsigned short* __restrict__ bT,
                      const float* __restrict__ Dh,
                      float* __restrict__ yb,
                      unsigned short* __restrict__ sst,
                      float* __restrict__ Pbuf) {
    extern __shared__ __align__(16) char smem[];
    __bf16* Bs  = (__bf16*)smem;                 // 128 x SLD; later Xt(0:17408)+Xtw(17408:34816)
    __bf16* Cs  = (__bf16*)(smem + 34816);       // 128 x SLD; later Ms
    float*  Lc  = (float*)(smem + 69632);        // 128
    float*  dtl = (float*)(smem + 70144);        // 128

    const int tid = threadIdx.x;
    const int c   = blockIdx.x & 15;
    const int bh  = blockIdx.x >> 4;
    const int b   = bh / 24, h = bh % 24;
    const int t0g = b * 2048 + c * QCHUNK;
    const int wave = tid >> 6, lane = tid & 63;
    const int lr = lane & 15, q = lane >> 4;

    for (int cc = tid; cc < 2048; cc += 256) {
        int r = cc >> 4, c8 = (cc & 15) << 3;
        *(uint4*)(Bs + r * SLD + c8) = *(const uint4*)(Brow + ((size_t)(t0g + r)) * 128 + c8);
        *(uint4*)(Cs + r * SLD + c8) = *(const uint4*)(Crow + ((size_t)(t0g + r)) * 128 + c8);
    }
    if (tid < 128) {
        float2 dd = dtdA[((size_t)t0g + tid) * 24 + h];
        dtl[tid] = dd.x;
        Lc[tid]  = dd.y;     // log dA
    }
    __syncthreads();
    for (int off = 1; off < 128; off <<= 1) {
        float v = 0.f;
        if (tid < 128 && tid >= off) v = Lc[tid - off];
        __syncthreads();
        if (tid < 128) Lc[tid] += v;
        __syncthreads();
    }

    // P1: G = Cs . Bs^T
    const int wm = (wave & 1) * 64, wn = (wave >> 1) * 64;
    f32x4 g[4][4] = {};
    #pragma unroll
    for (int k0 = 0; k0 < 128; k0 += 32) {
        bf16x8 af[4], bfr[4];
        #pragma unroll
        for (int t = 0; t < 4; ++t) {
            af[t]  = *(const bf16x8*)(Cs + (wm + t * 16 + lr) * SLD + k0 + q * 8);
            bfr[t] = *(const bf16x8*)(Bs + (wn + t * 16 + lr) * SLD + k0 + q * 8);
        }
        #pragma unroll
        for (int ti = 0; ti < 4; ++ti)
            #pragma unroll
            for (int tj = 0; tj < 4; ++tj)
                g[ti][tj] = __builtin_amdgcn_mfma_f32_16x16x32_bf16(af[ti], bfr[tj], g[ti][tj], 0, 0, 0);
    }
    __syncthreads();

    // P5: masked scale -> Ms[t][tau]
    __bf16* Ms = Cs;
    {
        float lt_[4], dt_[4];
        #pragma unroll
        for (int tj = 0; tj < 4; ++tj) {
            int tau = wn + tj * 16 + lr;
            lt_[tj] = Lc[tau];
            dt_[tj] = dtl[tau];
        }
        #pragma unroll
        for (int ti = 0; ti < 4; ++ti) {
            #pragma unroll
            for (int r = 0; r < 4; ++r) {
                int t = wm + ti * 16 + q * 4 + r;
                float Lt = Lc[t];
                #pragma unroll
                for (int tj = 0; tj < 4; ++tj) {
                    int tau = wn + tj * 16 + lr;
                    float mv = (tau <= t) ? g[ti][tj][r] * expf(Lt - lt_[tj]) * dt_[tj] : 0.f;
                    unsigned short u = f2bf(mv);
                    Ms[t * SLD + tau] = *(__bf16*)&u;
                }
            }
        }
    }

    // P3: stage Xt[p][t] and Xtw[p][t]
    __bf16* Xt  = Bs;
    __bf16* Xtw = (__bf16*)(smem + 17408);
    {
        float LQ = Lc[127];
        const unsigned short* xTb = xT + ((size_t)(b * 1536 + h * 64)) * 2048 + c * QCHUNK;
        for (int cc = tid; cc < 1024; cc += 256) {
            int p = cc >> 4, c8 = (cc & 15) << 3;
            uint4 v = *(const uint4*)(xTb + (size_t)p * 2048 + c8);
            *(uint4*)(Xt + p * SLD + c8) = v;
            unsigned short uu[8] = {(unsigned short)(v.x & 0xFFFF), (unsigned short)(v.x >> 16),
                                    (unsigned short)(v.y & 0xFFFF), (unsigned short)(v.y >> 16),
                                    (unsigned short)(v.z & 0xFFFF), (unsigned short)(v.z >> 16),
                                    (unsigned short)(v.w & 0xFFFF), (unsigned short)(v.w >> 16)};
            float w0[8];
            #pragma unroll
            for (int jj = 0; jj < 8; ++jj) {
                int tau = c8 + jj;
                w0[jj] = bf2f(uu[jj]) * expf(LQ - Lc[tau]) * dtl[tau];
            }
            *(uint4*)(Xtw + p * SLD + c8) = pack8(make_float4(w0[0], w0[1], w0[2], w0[3]),
                                                  make_float4(w0[4], w0[5], w0[6], w0[7]));
        }
    }
    __syncthreads();

    // P4: s_out[n][p] = bT . Xtw^T
    {
        f32x4 so[2][4] = {};
        const unsigned short* bTb = bT + ((size_t)(b * 128)) * 2048 + c * QCHUNK;
        #pragma unroll
        for (int k0 = 0; k0 < 128; k0 += 32) {
            bf16x8 af[2], bfr[4];
            #pragma unroll
            for (int ti = 0; ti < 2; ++ti) {
                int n = wave * 32 + ti * 16 + lr;
                af[ti] = *(const bf16x8*)(bTb + (size_t)n * 2048 + k0 + q * 8);
            }
            #pragma unroll
            for (int tj = 0; tj < 4; ++tj)
                bfr[tj] = *(const bf16x8*)(Xtw + (tj * 16 + lr) * SLD + k0 + q * 8);
            #pragma unroll
            for (int ti = 0; ti < 2; ++ti)
                #pragma unroll
                for (int tj = 0; tj < 4; ++tj)
                    so[ti][tj] = __builtin_amdgcn_mfma_f32_16x16x32_bf16(af[ti], bfr[tj], so[ti][tj], 0, 0, 0);
        }
        unsigned short* sb = sst + ((size_t)(bh * NCHUNK + c)) * 8192;
        #pragma unroll
        for (int ti = 0; ti < 2; ++ti) {
            #pragma unroll
            for (int r = 0; r < 4; ++r) {
                int n = wave * 32 + ti * 16 + q * 4 + r;
                #pragma unroll
                for (int tj = 0; tj < 4; ++tj) {
                    int p = tj * 16 + lr;
                    sb[n * 64 + p] = f2bf(so[ti][tj][r]);
                }
            }
        }
        if (tid == 0) Pbuf[bh * NCHUNK + c] = expf(Lc[127]);
    }

    // P6: Y[t][p] = Ms . Xt^T  (+ D skip)
    {
        f32x4 ya[2][4] = {};
        #pragma unroll
        for (int k0 = 0; k0 < 128; k0 += 32) {
            bf16x8 af[2], bfr[4];
            #pragma unroll
            for (int ti = 0; ti < 2; ++ti)
                af[ti] = *(const bf16x8*)(Ms + (wave * 32 + ti * 16 + lr) * SLD + k0 + q * 8);
            #pragma unroll
            for (int tj = 0; tj < 4; ++tj)
                bfr[tj] = *(const bf16x8*)(Xt + (tj * 16 + lr) * SLD + k0 + q * 8);
            #pragma unroll
            for (int ti = 0; ti < 2; ++ti)
                #pragma unroll
                for (int tj = 0; tj < 4; ++tj)
                    ya[ti][tj] = __builtin_amdgcn_mfma_f32_16x16x32_bf16(af[ti], bfr[tj], ya[ti][tj], 0, 0, 0);
        }
        float Dv = Dh[h];
        float* ybb = yb + (size_t)t0g * 1536 + h * 64;
        #pragma unroll
        for (int ti = 0; ti < 2; ++ti) {
            #pragma unroll
            for (int r = 0; r < 4; ++r) {
                int t = wave * 32 + ti * 16 + q * 4 + r;
                #pragma unroll
                for (int tj = 0; tj < 4; ++tj) {
                    int p = tj * 16 + lr;
                    __bf16 xb = Xt[p * SLD + t];
                    float xv = bf2f(*(unsigned short*)&xb);
                    ybb[(size_t)t * 1536 + p] = ya[ti][tj][r] + Dv * xv;
                }
            }
        }
    }
}

// ---------- combine ----------
__global__ __launch_bounds__(256)
void combine_kernel(const unsigned short* __restrict__ sst,
                    unsigned short* __restrict__ sstT,
                    const float* __restrict__ Pbuf) {
    int flat = blockIdx.x * 256 + threadIdx.x;
    int bh = flat >> 13;
    int pn = flat & 8191;
    int n = pn >> 6, p = pn & 63;
    const unsigned short* sb = sst + (size_t)bh * NCHUNK * 8192;
    unsigned short* tb = sstT + (size_t)bh * NCHUNK * 8192 + p * 128 + n;
    const float* Pb = Pbuf + bh * NCHUNK;
    float s = 0.f;
    #pragma unroll
    for (int c = 0; c < NCHUNK; ++c) {
        float tmp = bf2f(sb[(size_t)c * 8192 + pn]);
        tb[(size_t)c * 8192] = f2bf(s);
        s = Pb[c] * s + tmp;
    }
}

// ---------- SSD inter kernel ----------
__global__ __launch_bounds__(256)
void ssd_inter_kernel(const unsigned short* __restrict__ Crow,
                      const float2* __restrict__ dtdA,
                      const unsigned short* __restrict__ sstT,
                      float* __restrict__ yb) {
    __shared__ __align__(16) __bf16 Cs[128 * SLD];
    __shared__ __align__(16) __bf16 St[64 * SLD];
    __shared__ float Lc[128];

    const int tid = threadIdx.x;
    const int blk = blockIdx.x;
    const int bh = blk / 15;
    const int c  = blk % 15 + 1;
    const int b = bh / 24, h = bh % 24;
    const int t0g = b * 2048 + c * QCHUNK;
    const int wave = tid >> 6, lane = tid & 63;
    const int lr = lane & 15, q = lane >> 4;

    for (int cc = tid; cc < 2048; cc += 256) {
        int r = cc >> 4, c8 = (cc & 15) << 3;
        *(uint4*)(Cs + r * SLD + c8) = *(const uint4*)(Crow + ((size_t)(t0g + r)) * 128 + c8);
    }
    const unsigned short* stb = sstT + ((size_t)(bh * NCHUNK + c)) * 8192;
    for (int cc = tid; cc < 1024; cc += 256) {
        int p = cc >> 4, c8 = (cc & 15) << 3;
        *(uint4*)(St + p * SLD + c8) = *(const uint4*)(stb + p * 128 + c8);
    }
    if (tid < 128) Lc[tid] = dtdA[((size_t)t0g + tid) * 24 + h].y;
    __syncthreads();
    for (int off = 1; off < 128; off <<= 1) {
        float v = 0.f;
        if (tid < 128 && tid >= off) v = Lc[tid - off];
        __syncthreads();
        if (tid < 128) Lc[tid] += v;
        __syncthreads();
    }

    f32x4 ya[2][4] = {};
    #pragma unroll
    for (int k0 = 0; k0 < 128; k0 += 32) {
        bf16x8 af[2], bfr[4];
        #pragma unroll
        for (int ti = 0; ti < 2; ++ti)
            af[ti] = *(const bf16x8*)(Cs + (wave * 32 + ti * 16 + lr) * SLD + k0 + q * 8);
        #pragma unroll
        for (int tj = 0; tj < 4; ++tj)
            bfr[tj] = *(const bf16x8*)(St + (tj * 16 + lr) * SLD + k0 + q * 8);
        #pragma unroll
        for (int ti = 0; ti < 2; ++ti)
            #pragma unroll
            for (int tj = 0; tj < 4; ++tj)
                ya[ti][tj] = __builtin_amdgcn_mfma_f32_16x16x32_bf16(af[ti], bfr[tj], ya[ti][tj], 0, 0, 0);
    }
    float* ybb = yb + (size_t)t0g * 1536 + h * 64;
    #pragma unroll
    for (int ti = 0; ti < 2; ++ti) {
        #pragma unroll
        for (int r = 0; r < 4; ++r) {
            int t = wave * 32 + ti * 16 + q * 4 + r;
            float sc = expf(Lc[t]);
            #pragma unroll
            for (int tj = 0; tj < 4; ++tj) {
                int p = tj * 16 + lr;
                float* yp = ybb + (size_t)t * 1536 + p;
                *yp = *yp + sc * ya[ti][tj][r];
            }
        }
    }
}

// ---------- gated RMSNorm: writes bf16 into zx cols [1536,3072) ----------
__global__ __launch_bounds__(256)
void norm_kernel(const float* __restrict__ yb,
                 unsigned short* __restrict__ zx,
                 const float* __restrict__ nw) {
    int row = blockIdx.x;
    const float* yr = yb + (size_t)row * 1536;
    unsigned short* zr = zx + (size_t)row * 3352;
    int tid = threadIdx.x;
    float u[6];
    float ss = 0.f;
    #pragma unroll
    for (int i = 0; i < 6; ++i) {
        int c = tid + i * 256;
        float z = bf2f(zr[c]);
        float uu = yr[c] * (z / (1.f + expf(-z)));
        u[i] = uu;
        ss += uu * uu;
    }
    #pragma unroll
    for (int m = 1; m < 64; m <<= 1) ss += __shfl_xor(ss, m);
    __shared__ float red[4];
    if ((tid & 63) == 0) red[tid >> 6] = ss;
    __syncthreads();
    float tot = red[0] + red[1] + red[2] + red[3];
    float inv = rsqrtf(tot * (1.f / 1536.f) + 1e-5f);
    #pragma unroll
    for (int i = 0; i < 6; ++i) {
        int c = tid + i * 256;
        zr[1536 + c] = f2bf(u[i] * inv * nw[c]);
    }
}

// ---------- launch ----------
extern "C" void kernel_launch(void* const* d_in, const int* in_sizes, int n_in,
                              void* d_out, int out_size, void* d_ws, size_t ws_size,
                              hipStream_t stream) {
    const float* x       = (const float*)d_in[0];
    const float* w_in    = (const float*)d_in[1];
    const float* conv_w  = (const float*)d_in[2];
    const float* conv_b  = (const float*)d_in[3];
    const float* dt_bias = (const float*)d_in[4];
    const float* A_log   = (const float*)d_in[5];
    const float* Dp      = (const float*)d_in[6];
    const float* nw      = (const float*)d_in[7];
    const float* w_out   = (const float*)d_in[8];
    float* out = (float*)d_out;

    char* ws = (char*)d_ws;
    const size_t off_zx   = 0;                        // 8192*3352 bf16 = 54,919,168
    const size_t off_A    = off_zx + 54919168;        // region A (58,720,256 reserved)
    const size_t off_xT   = off_A;                    // 25,165,824 (sstT + w_out_bf alias later)
    const size_t off_bT   = off_A + 25165824;         // 2,097,152
    const size_t off_Brow = off_A + 27262976;         // 2,097,152
    const size_t off_Crow = off_A + 29360128;         // 2,097,152
    const size_t off_dtdA = off_A + 58720256;         // 1,572,864
    const size_t off_y    = off_dtdA + 1572864;       // 50,331,648 (x_bf aliases head)
    const size_t off_sst  = off_y + 50331648;         // 25,165,824 (w_in_bf aliases head)
    const size_t off_P    = off_sst + 25165824;       // 6,144

    unsigned short* zx   = (unsigned short*)(ws + off_zx);
    unsigned short* xT   = (unsigned short*)(ws + off_xT);
    unsigned short* bT   = (unsigned short*)(ws + off_bT);
    unsigned short* Brow = (unsigned short*)(ws + off_Brow);
    unsigned short* Crow = (unsigned short*)(ws + off_Crow);
    float2* dtdA = (float2*)(ws + off_dtdA);
    float* yb    = (float*)(ws + off_y);
    unsigned short* sst  = (unsigned short*)(ws + off_sst);
    unsigned short* sstT = xT;                        // xT dead after ssd_local
    float* Pbuf = (float*)(ws + off_P);

    // transient aliases (dead regions at time of use)
    unsigned short* x_bf     = (unsigned short*)(ws + off_y);    // gemm1 only (before yb written)
    unsigned short* w_in_bf  = (unsigned short*)(ws + off_sst);  // gemm1 only (before sst written)
    unsigned short* w_out_bf = (unsigned short*)(ws + off_xT);   // written after sstT dead (step 7.5)

    static bool attr_set = false;
    if (!attr_set) {
        hipFuncSetAttribute((const void*)ssd_local_kernel,
                            hipFuncAttributeMaxDynamicSharedMemorySize, 70656);
        hipFuncSetAttribute((const void*)gemm_8phase,
                            hipFuncAttributeMaxDynamicSharedMemorySize, 131072);
        hipFuncSetAttribute((const void*)gemm_out,
                            hipFuncAttributeMaxDynamicSharedMemorySize, 65536);
        attr_set = true;
    }

    // 0. convert x, w_in (padded to 3584 rows) -> bf16
    convert_kernel<<<4416, 256, 0, stream>>>(x, w_in, x_bf, w_in_bf);
    // 1. in_proj (M=8192, N=3352 padded 3584, K=768) — 256x256 phase-split pipeline
    gemm_8phase<<<448, 512, 131072, stream>>>(x_bf, w_in_bf, zx, 3352, 768);
    // 2. fused conv + silu + layout (replaces conv_silu + transpose; cv eliminated)
    conv_fused_kernel<<<3584, 256, 0, stream>>>(zx, conv_w, conv_b, xT, bT, Brow, Crow);
    // 3. dt / log-dA (full f32)
    dt_kernel<<<8192, 64, 0, stream>>>(x, w_in, dt_bias, A_log, dtdA);
    // 4. SSD local
    ssd_local_kernel<<<1536, 256, 70656, stream>>>(Brow, Crow, dtdA, xT, bT, Dp, yb, sst, Pbuf);
    // 5. combine
    combine_kernel<<<3072, 256, 0, stream>>>(sst, sstT, Pbuf);
    // 6. SSD inter
    ssd_inter_kernel<<<1440, 256, 0, stream>>>(Crow, dtdA, sstT, yb);
    // 6.5 convert w_out -> bf16 (xT/sstT region dead now)
    convert_wout_kernel<<<576, 256, 0, stream>>>(w_out, w_out_bf);
    // 7. gated RMSNorm -> bf16 into zx cols [1536,3072)
    norm_kernel<<<8192, 256, 0, stream>>>(yb, zx, nw);
    // 8. out_proj + residual — 512-thread counted-vmcnt pipeline, 384 blocks co-resident
    gemm_out<<<384, 512, 65536, stream>>>(zx + 1536, w_out_bf, out, x, 3352);
}

// Round 3
// 405.708 us; speedup vs baseline: 1.1197x; 1.0145x over previous
//
#include <hip/hip_runtime.h>
#include <math.h>

// ---------- types ----------
typedef __bf16 bf16x8 __attribute__((ext_vector_type(8)));
typedef float  f32x4  __attribute__((ext_vector_type(4)));

#define QCHUNK 128
#define NCHUNK 16
#define SLD 136              // LDS row stride (bf16 elems) for 128-wide arrays

__device__ __forceinline__ float bf2f(unsigned short u) {
    union { unsigned int i; float f; } v; v.i = ((unsigned int)u) << 16; return v.f;
}
__device__ __forceinline__ unsigned short f2bf(float f) {
    union { float f; unsigned int i; } v; v.f = f;
    unsigned int x = v.i;
    unsigned int r = (x + 0x7FFFu + ((x >> 16) & 1u)) >> 16;
    return (unsigned short)r;
}
__device__ __forceinline__ uint4 pack8(float4 a, float4 b) {
    uint4 r;
    r.x = (unsigned)f2bf(a.x) | ((unsigned)f2bf(a.y) << 16);
    r.y = (unsigned)f2bf(a.z) | ((unsigned)f2bf(a.w) << 16);
    r.z = (unsigned)f2bf(b.x) | ((unsigned)f2bf(b.y) << 16);
    r.w = (unsigned)f2bf(b.z) | ((unsigned)f2bf(b.w) << 16);
    return r;
}
__device__ __forceinline__ void load_lds16(const void* g, void* l) {
    __builtin_amdgcn_global_load_lds((const __attribute__((address_space(1))) void*)g,
                                     (__attribute__((address_space(3))) void*)l,
                                     16, 0, 0);
}

// ---------- convert: x -> x_bf, w_in -> w_in_bf (padded 3584 rows, zero-filled) ----------
__global__ __launch_bounds__(256)
void convert_kernel(const float* __restrict__ x, const float* __restrict__ w_in,
                    unsigned short* __restrict__ x_bf, unsigned short* __restrict__ w_in_bf) {
    int idx = blockIdx.x * 256 + threadIdx.x;      // 8 elems each
    const int NX  = 8192 * 768 / 8;                // 786432
    const int NW1 = 3584 * 768 / 8;                // 344064 (padded to 14x256 tiles)
    const int NW1r = 3352 * 768 / 8;               // 321792 (real)
    if (idx < NX) {
        const float* s = x + (size_t)idx * 8;
        *(uint4*)(x_bf + (size_t)idx * 8) = pack8(*(const float4*)s, *(const float4*)(s + 4));
    } else if (idx < NX + NW1) {
        int j = idx - NX;
        uint4 v = make_uint4(0u, 0u, 0u, 0u);
        if (j < NW1r) {
            const float* s = w_in + (size_t)j * 8;
            v = pack8(*(const float4*)s, *(const float4*)(s + 4));
        }
        *(uint4*)(w_in_bf + (size_t)j * 8) = v;
    }
}

// ---------- convert w_out -> bf16 ----------
__global__ __launch_bounds__(256)
void convert_wout_kernel(const float* __restrict__ w_out, unsigned short* __restrict__ w_out_bf) {
    int idx = blockIdx.x * 256 + threadIdx.x;      // 147456 total
    const float* s = w_out + (size_t)idx * 8;
    *(uint4*)(w_out_bf + (size_t)idx * 8) = pack8(*(const float4*)s, *(const float4*)(s + 4));
}

// ---------- 256x256 pipelined GEMM: Out[m,n] = sum_k A[m,k]*Bw[n,k], bf16 out ----------
// 512 threads = 8 waves (2 wr x 4 wc); per-wave output 128x64; K-tile 64 (full 128B LDS row).
// LDS: A[2dbuf][256 rows][128B] @0 (64KB), B same @65536 (64KB) = 128 KiB.
// Swizzle (both-sides): 16B granule g of row r stores global slot g^(r&7); ds_read addr
// col ^= (r&7)<<4  -> every 16-lane quarter-wave covers all 8 bank granules 2x (floor).
// Pipeline: per tile stage next tile's 8 loads, gate s_waitcnt vmcnt(8) (never 0 mid-loop),
// 2 barriers/tile, kh0/kh1 {12 ds_read_b128 + 32 MFMA} clusters with setprio(1).
__global__ __launch_bounds__(512)
void gemm_8phase(const unsigned short* __restrict__ A,
                 const unsigned short* __restrict__ Bw,
                 unsigned short* __restrict__ Out,
                 int N_real, int K) {
    extern __shared__ __align__(16) char smem[];

    const int tid = threadIdx.x;
    const int bid = blockIdx.x;
    // XCD-chunked: 448 = 8 XCDs x 56; n-fastest within chunk (A-panel 1.6MB stays L2-resident)
    const int xcd = bid & 7, local = bid >> 3;
    const int mt = xcd * 4 + local / 14;       // 4 m-tiles per XCD
    const int nt = local % 14;
    const int m0 = mt * 256, n0 = nt * 256;

    const int wave = tid >> 6, lane = tid & 63;
    const int wr = wave >> 2, wc = wave & 3;
    const int lr = lane & 15, q = lane >> 4;

    const int gl   = (lr & 7) << 4;            // row-granule XOR bits (bits 4-6)
    const int arow = wr * 128 + lr;            // + m*16
    const int brow = wc * 64 + lr;             // + n*16
    const int colq = q << 4;                   // + kh*64, then ^ gl

    // staging: LDS linear (row=tid>>3 + i*64, slot=tid&7); global source slot pre-swizzled
    const int srow  = tid >> 3;                // 0..63
    const int sslot = (tid & 7) ^ (srow & 7);
    const unsigned short* ga = A  + (size_t)(m0 + srow) * K + sslot * 8;
    const unsigned short* gb = Bw + (size_t)(n0 + srow) * K + sslot * 8;
    char* sAd = smem +         (size_t)tid * 16;
    char* sBd = smem + 65536 + (size_t)tid * 16;
    const size_t gstep = (size_t)64 * K;

    const int NT = K >> 6;                     // 12
    f32x4 acc[8][4] = {};

    // prologue: tile0 -> dbuf0 (8 issues: 4 A + 4 B)
    #pragma unroll
    for (int i = 0; i < 4; ++i) {
        load_lds16(ga + (size_t)i * gstep, sAd + i * 8192);
        load_lds16(gb + (size_t)i * gstep, sBd + i * 8192);
    }

    for (int t = 0; t < NT; ++t) {
        const int d = t & 1;
        const bool more = (t + 1 < NT);
        if (more) {                            // stage tile t+1 -> other dbuf (safe: end
            const size_t kg = (size_t)(t + 1) * 64;   // barrier of t-1 ended its reads)
            const int ld = (d ^ 1) * 32768;
            #pragma unroll
            for (int i = 0; i < 4; ++i) {
                load_lds16(ga + kg + (size_t)i * gstep, sAd + ld + i * 8192);
                load_lds16(gb + kg + (size_t)i * gstep, sBd + ld + i * 8192);
            }
            asm volatile("s_waitcnt vmcnt(8)" ::: "memory");   // tile t's 8 landed
        } else {
            asm volatile("s_waitcnt vmcnt(0)" ::: "memory");
        }
        __builtin_amdgcn_s_barrier();

        const char* pa = smem +         d * 32768;
        const char* pb = smem + 65536 + d * 32768;
        #pragma unroll
        for (int kh = 0; kh < 2; ++kh) {
            const int col = ((kh << 6) | colq) ^ gl;
            bf16x8 af[8], bfr[4];
            #pragma unroll
            for (int m = 0; m < 8; ++m)
                af[m] = *(const bf16x8*)(pa + (arow + m * 16) * 128 + col);
            #pragma unroll
            for (int n = 0; n < 4; ++n)
                bfr[n] = *(const bf16x8*)(pb + (brow + n * 16) * 128 + col);

            __builtin_amdgcn_s_setprio(1);
            #pragma unroll
            for (int m = 0; m < 8; ++m)
                #pragma unroll
                for (int n = 0; n < 4; ++n)
                    acc[m][n] = __builtin_amdgcn_mfma_f32_16x16x32_bf16(af[m], bfr[n], acc[m][n], 0, 0, 0);
            __builtin_amdgcn_s_setprio(0);
        }
        __builtin_amdgcn_s_barrier();          // dbuf d free for iteration t+1's staging
    }

    // epilogue: C/D layout col=lane&15, row=(lane>>4)*4+reg
    #pragma unroll
    for (int m = 0; m < 8; ++m) {
        #pragma unroll
        for (int r = 0; r < 4; ++r) {
            int row = m0 + wr * 128 + m * 16 + q * 4 + r;
            #pragma unroll
            for (int n = 0; n < 4; ++n) {
                int col = n0 + wc * 64 + n * 16 + lr;
                if (col < N_real)
                    Out[(size_t)row * N_real + col] = f2bf(acc[m][n][r]);
            }
        }
    }
}

// ---------- out_proj GEMM: Out[m,n] = sum_k A[m,k]*Bw[n,k] + Resid, f32 out ----------
// M=8192, N=768, K=1536. BM=BN=128, 512 threads = 8 waves (2x4), per-wave 64x32.
// Same 128B-row + (row&7)<<4 XOR swizzle as gemm_8phase; per-tile vmcnt(4) gating.
// LDS: A[2dbuf][128][128B] @0 (32KB), B @32768 (32KB) = 64 KiB -> 2 blocks/CU.
__global__ __launch_bounds__(512)
void gemm_out(const unsigned short* __restrict__ A,
              const unsigned short* __restrict__ Bw,
              float* __restrict__ Out, const float* __restrict__ Resid,
              int lda) {
    extern __shared__ __align__(16) char smem[];
    const int K = 1536, Nn = 768;

    const int tid = threadIdx.x;
    const int bid = blockIdx.x;
    // XCD-chunked: 384 = 8 x 48; n-fastest (A panel 3.1MB/XCD ~L2-resident)
    const int xcd = bid & 7, local = bid >> 3;
    const int mt = xcd * 8 + local / 6;        // 0..63
    const int nt = local % 6;                  // 0..5
    const int m0 = mt * 128, n0 = nt * 128;

    const int wave = tid >> 6, lane = tid & 63;
    const int wr = wave >> 2, wc = wave & 3;
    const int lr = lane & 15, q = lane >> 4;

    const int gl   = (lr & 7) << 4;
    const int arow = wr * 64 + lr;             // + m*16
    const int brow = wc * 32 + lr;             // + n*16
    const int colq = q << 4;

    const int srow  = tid >> 3;                // 0..63
    const int sslot = (tid & 7) ^ (srow & 7);
    const unsigned short* ga = A  + (size_t)(m0 + srow) * lda + sslot * 8;
    const unsigned short* gb = Bw + (size_t)(n0 + srow) * K   + sslot * 8;
    char* sAd = smem +         (size_t)tid * 16;
    char* sBd = smem + 32768 + (size_t)tid * 16;
    const size_t gstep_a = (size_t)64 * lda;
    const size_t gstep_b = (size_t)64 * K;

    f32x4 acc[4][2] = {};

    // prologue: tile0 -> dbuf0 (4 issues: 2 A + 2 B)
    #pragma unroll
    for (int i = 0; i < 2; ++i) {
        load_lds16(ga + (size_t)i * gstep_a, sAd + i * 8192);
        load_lds16(gb + (size_t)i * gstep_b, sBd + i * 8192);
    }

    const int NT = K >> 6;   // 24
    for (int t = 0; t < NT; ++t) {
        const int d = t & 1;
        const bool more = (t + 1 < NT);
        if (more) {
            const size_t kg = (size_t)(t + 1) * 64;
            const int ld = (d ^ 1) * 16384;
            #pragma unroll
            for (int i = 0; i < 2; ++i) {
                load_lds16(ga + kg + (size_t)i * gstep_a, sAd + ld + i * 8192);
                load_lds16(gb + kg + (size_t)i * gstep_b, sBd + ld + i * 8192);
            }
            asm volatile("s_waitcnt vmcnt(4)" ::: "memory");
        } else {
            asm volatile("s_waitcnt vmcnt(0)" ::: "memory");
        }
        __builtin_amdgcn_s_barrier();

        const char* pa = smem +         d * 16384;
        const char* pb = smem + 32768 + d * 16384;
        #pragma unroll
        for (int kh = 0; kh < 2; ++kh) {
            const int col = ((kh << 6) | colq) ^ gl;
            bf16x8 af[4], bfr[2];
            #pragma unroll
            for (int m = 0; m < 4; ++m)
                af[m] = *(const bf16x8*)(pa + (arow + m * 16) * 128 + col);
            #pragma unroll
            for (int n = 0; n < 2; ++n)
                bfr[n] = *(const bf16x8*)(pb + (brow + n * 16) * 128 + col);

            __builtin_amdgcn_s_setprio(1);
            #pragma unroll
            for (int m = 0; m < 4; ++m)
                #pragma unroll
                for (int n = 0; n < 2; ++n)
                    acc[m][n] = __builtin_amdgcn_mfma_f32_16x16x32_bf16(af[m], bfr[n], acc[m][n], 0, 0, 0);
            __builtin_amdgcn_s_setprio(0);
        }
        __builtin_amdgcn_s_barrier();
    }

    // epilogue: f32 out + residual (N=768 = 6x128 exactly, no masking)
    #pragma unroll
    for (int m = 0; m < 4; ++m) {
        #pragma unroll
        for (int r = 0; r < 4; ++r) {
            int row = m0 + wr * 64 + m * 16 + q * 4 + r;
            #pragma unroll
            for (int n = 0; n < 2; ++n) {
                int col = n0 + wc * 32 + n * 16 + lr;
                Out[(size_t)row * Nn + col] = acc[m][n][r] + Resid[(size_t)row * Nn + col];
            }
        }
    }
}

// ---------- fused conv(4)+silu+layout: zx xBC cols -> xT (transposed), bT (transposed), Brow/Crow (row-major), all bf16 ----------
// grid: b(4) x t-tile(32) x ch-tile(28), 256 threads. Tile 64 t x 64 ch.
__global__ __launch_bounds__(256)
void conv_fused_kernel(const unsigned short* __restrict__ zx,
                       const float* __restrict__ cw, const float* __restrict__ cb,
                       unsigned short* __restrict__ xT, unsigned short* __restrict__ bT,
                       unsigned short* __restrict__ Brow, unsigned short* __restrict__ Crow) {
    __shared__ unsigned short outt[64][66];
    __shared__ float cwl[64][4];
    __shared__ float cbl[64];

    int blk = blockIdx.x;
    int cht = blk % 28;
    int tt  = (blk / 28) % 32;
    int b   = blk / (28 * 32);
    int ch0 = cht * 64, t0 = tt * 64;
    int tid = threadIdx.x;
    int tx = tid & 63, ty = tid >> 6;

    if (tid < 64) cbl[tid] = cb[ch0 + tid];
    cwl[tid >> 2][tid & 3] = cw[(ch0 + (tid >> 2)) * 4 + (tid & 3)];
    __syncthreads();

    const unsigned short* zp = zx + (size_t)(b * 2048) * 3352 + 1536 + ch0 + tx;
    float w0 = cwl[tx][0], w1 = cwl[tx][1], w2 = cwl[tx][2], w3 = cwl[tx][3];
    float bias = cbl[tx];
    int tg = t0 + ty * 16;                 // first output t for this thread
    float r0 = (tg >= 3) ? bf2f(zp[(size_t)(tg - 3) * 3352]) : 0.f;
    float r1 = (tg >= 2) ? bf2f(zp[(size_t)(tg - 2) * 3352]) : 0.f;
    float r2 = (tg >= 1) ? bf2f(zp[(size_t)(tg - 1) * 3352]) : 0.f;
    #pragma unroll
    for (int k = 0; k < 16; ++k) {
        float cur = bf2f(zp[(size_t)(tg + k) * 3352]);
        float a = bias + r0 * w0 + r1 * w1 + r2 * w2 + cur * w3;
        a = a / (1.f + expf(-a));          // silu
        outt[ty * 16 + k][tx] = f2bf(a);
        r0 = r1; r1 = r2; r2 = cur;
    }
    __syncthreads();

    if (ch0 < 1536) {
        // x region: transposed write xT[ch][t]
        unsigned short* dst = xT + ((size_t)(b * 1536 + ch0)) * 2048 + t0;
        #pragma unroll
        for (int k = 0; k < 16; ++k) {
            int chl = ty * 16 + k;
            dst[(size_t)chl * 2048 + tx] = outt[tx][chl];
        }
    } else if (ch0 < 1664) {
        // B region: transposed bT[n][t] + row-major Brow[t][n]
        int n0 = ch0 - 1536;
        unsigned short* dstT = bT + ((size_t)(b * 128 + n0)) * 2048 + t0;
        #pragma unroll
        for (int k = 0; k < 16; ++k) {
            int chl = ty * 16 + k;
            dstT[(size_t)chl * 2048 + tx] = outt[tx][chl];
        }
        unsigned short* dstR = Brow + ((size_t)(b * 2048 + t0)) * 128 + n0;
        int tl = tid >> 3, c8 = (tid & 7) << 3;
        #pragma unroll
        for (int it = 0; it < 2; ++it) {
            int t = tl + it * 32;
            unsigned short tmp[8];
            #pragma unroll
            for (int jj = 0; jj < 8; ++jj) tmp[jj] = outt[t][c8 + jj];
            *(uint4*)(dstR + (size_t)t * 128 + c8) = *(uint4*)tmp;
        }
    } else {
        // C region: row-major Crow[t][n]
        int n0 = ch0 - 1664;
        unsigned short* dstR = Crow + ((size_t)(b * 2048 + t0)) * 128 + n0;
        int tl = tid >> 3, c8 = (tid & 7) << 3;
        #pragma unroll
        for (int it = 0; it < 2; ++it) {
            int t = tl + it * 32;
            unsigned short tmp[8];
            #pragma unroll
            for (int jj = 0; jj < 8; ++jj) tmp[jj] = outt[t][c8 + jj];
            *(uint4*)(dstR + (size_t)t * 128 + c8) = *(uint4*)tmp;
        }
    }
}

// ---------- dt in full f32 -> interleaved (dt, dt*A) float2 ----------
__global__ __launch_bounds__(64)
void dt_kernel(const float* __restrict__ x, const float* __restrict__ w_in,
               const float* __restrict__ dt_bias, const float* __restrict__ A_log,
               float2* __restrict__ dtdA) {
    int row = blockIdx.x;
    int lane = threadIdx.x;
    float xv[12];
    #pragma unroll
    for (int i = 0; i < 12; ++i) xv[i] = x[(size_t)row * 768 + i * 64 + lane];
    for (int h = 0; h < 24; ++h) {
        const float* w = w_in + (size_t)(3328 + h) * 768;
        float acc = 0.f;
        #pragma unroll
        for (int i = 0; i < 12; ++i) acc += xv[i] * w[i * 64 + lane];
        #pragma unroll
        for (int m = 1; m < 64; m <<= 1) acc += __shfl_xor(acc, m);
        if (lane == 0) {
            float v = acc + dt_bias[h];
            float dt = (v > 20.f) ? v : log1pf(expf(v));
            float A = -expf(A_log[h]);
            dtdA[(size_t)row * 24 + h] = make_float2(dt, dt * A);   // (dt, log dA)
        }
    }
}

// ---------- SSD local kernel: per (b,h,chunk): G -> M -> Y, s_out ----------
__global__ __launch_bounds__(256)
void ssd_local_kernel(const unsigned short* __restrict__ Brow,
                      const unsigned short* __restrict__ Crow,
                      const float2* __restrict__ dtdA,
                      const unsigned short* __restrict__ xT,
                      const unsigned short* __restrict__ bT,
                      const float* __restrict__ Dh,
                      float* __restrict__ yb,
                      unsigned short* __restrict__ sst,
                      float* __restrict__ Pbuf) {
    extern __shared__ __align__(16) char smem[];
    __bf16* Bs  = (__bf16*)smem;                 // 128 x SLD; later Xt(0:17408)+Xtw(17408:34816)
    __bf16* Cs  = (__bf16*)(smem + 34816);       // 128 x SLD; later Ms
    float*  Lc  = (float*)(smem + 69632);        // 128
    float*  dtl = (float*)(smem + 70144);        // 128

    const int tid = threadIdx.x;
    const int c   = blockIdx.x & 15;
    const int bh  = blockIdx.x >> 4;
    const int b   = bh / 24, h = bh % 24;
    const int t0g = b * 2048 + c * QCHUNK;
    const int wave = tid >> 6, lane = tid & 63;
    const int lr = lane & 15, q = lane >> 4;

    for (int cc = tid; cc < 2048; cc += 256) {
        int r = cc >> 4, c8 = (cc & 15) << 3;
        *(uint4*)(Bs + r * SLD + c8) = *(const uint4*)(Brow + ((size_t)(t0g + r)) * 128 + c8);
        *(uint4*)(Cs + r * SLD + c8) = *(const uint4*)(Crow + ((size_t)(t0g + r)) * 128 + c8);
    }
    if (tid < 128) {
        float2 dd = dtdA[((size_t)t0g + tid) * 24 + h];
        dtl[tid] = dd.x;
        Lc[tid]  = dd.y;     // log dA
    }
    __syncthreads();
    for (int off = 1; off < 128; off <<= 1) {
        float v = 0.f;
        if (tid < 128 && tid >= off) v = Lc[tid - off];
        __syncthreads();
        if (tid < 128) Lc[tid] += v;
        __syncthreads();
    }

    // P1: G = Cs . Bs^T
    const int wm = (wave & 1) * 64, wn = (wave >> 1) * 64;
    f32x4 g[4][4] = {};
    #pragma unroll
    for (int k0 = 0; k0 < 128; k0 += 32) {
        bf16x8 af[4], bfr[4];
        #pragma unroll
        for (int t = 0; t < 4; ++t) {
            af[t]  = *(const bf16x8*)(Cs + (wm + t * 16 + lr) * SLD + k0 + q * 8);
            bfr[t] = *(const bf16x8*)(Bs + (wn + t * 16 + lr) * SLD + k0 + q * 8);
        }
        #pragma unroll
        for (int ti = 0; ti < 4; ++ti)
            #pragma unroll
            for (int tj = 0; tj < 4; ++tj)
                g[ti][tj] = __builtin_amdgcn_mfma_f32_16x16x32_bf16(af[ti], bfr[tj], g[ti][tj], 0, 0, 0);
    }
    __syncthreads();

    // P5: masked scale -> Ms[t][tau]
    __bf16* Ms = Cs;
    {
        float lt_[4], dt_[4];
        #pragma unroll
        for (int tj = 0; tj < 4; ++tj) {
            int tau = wn + tj * 16 + lr;
            lt_[tj] = Lc[tau];
            dt_[tj] = dtl[tau];
        }
        #pragma unroll
        for (int ti = 0; ti < 4; ++ti) {
            #pragma unroll
            for (int r = 0; r < 4; ++r) {
                int t = wm + ti * 16 + q * 4 + r;
                float Lt = Lc[t];
                #pragma unroll
                for (int tj = 0; tj < 4; ++tj) {
                    int tau = wn + tj * 16 + lr;
                    float mv = (tau <= t) ? g[ti][tj][r] * expf(Lt - lt_[tj]) * dt_[tj] : 0.f;
                    unsigned short u = f2bf(mv);
                    Ms[t * SLD + tau] = *(__bf16*)&u;
                }
            }
        }
    }

    // P3: stage Xt[p][t] and Xtw[p][t]
    __bf16* Xt  = Bs;
    __bf16* Xtw = (__bf16*)(smem + 17408);
    {
        float LQ = Lc[127];
        const unsigned short* xTb = xT + ((size_t)(b * 1536 + h * 64)) * 2048 + c * QCHUNK;
        for (int cc = tid; cc < 1024; cc += 256) {
            int p = cc >> 4, c8 = (cc & 15) << 3;
            uint4 v = *(const uint4*)(xTb + (size_t)p * 2048 + c8);
            *(uint4*)(Xt + p * SLD + c8) = v;
            unsigned short uu[8] = {(unsigned short)(v.x & 0xFFFF), (unsigned short)(v.x >> 16),
                                    (unsigned short)(v.y & 0xFFFF), (unsigned short)(v.y >> 16),
                                    (unsigned short)(v.z & 0xFFFF), (unsigned short)(v.z >> 16),
                                    (unsigned short)(v.w & 0xFFFF), (unsigned short)(v.w >> 16)};
            float w0[8];
            #pragma unroll
            for (int jj = 0; jj < 8; ++jj) {
                int tau = c8 + jj;
                w0[jj] = bf2f(uu[jj]) * expf(LQ - Lc[tau]) * dtl[tau];
            }
            *(uint4*)(Xtw + p * SLD + c8) = pack8(make_float4(w0[0], w0[1], w0[2], w0[3]),
                                                  make_float4(w0[4], w0[5], w0[6], w0[7]));
        }
    }
    __syncthreads();

    // P4: s_out[n][p] = bT . Xtw^T
    {
        f32x4 so[2][4] = {};
        const unsigned short* bTb = bT + ((size_t)(b * 128)) * 2048 + c * QCHUNK;
        #pragma unroll
        for (int k0 = 0; k0 < 128; k0 += 32) {
            bf16x8 af[2], bfr[4];
            #pragma unroll
            for (int ti = 0; ti < 2; ++ti) {
                int n = wave * 32 + ti * 16 + lr;
                af[ti] = *(const bf16x8*)(bTb + (size_t)n * 2048 + k0 + q * 8);
            }
            #pragma unroll
            for (int tj = 0; tj < 4; ++tj)
                bfr[tj] = *(const bf16x8*)(Xtw + (tj * 16 + lr) * SLD + k0 + q * 8);
            #pragma unroll
            for (int ti = 0; ti < 2; ++ti)
                #pragma unroll
                for (int tj = 0; tj < 4; ++tj)
                    so[ti][tj] = __builtin_amdgcn_mfma_f32_16x16x32_bf16(af[ti], bfr[tj], so[ti][tj], 0, 0, 0);
        }
        unsigned short* sb = sst + ((size_t)(bh * NCHUNK + c)) * 8192;
        #pragma unroll
        for (int ti = 0; ti < 2; ++ti) {
            #pragma unroll
            for (int r = 0; r < 4; ++r) {
                int n = wave * 32 + ti * 16 + q * 4 + r;
                #pragma unroll
                for (int tj = 0; tj < 4; ++tj) {
                    int p = tj * 16 + lr;
                    sb[n * 64 + p] = f2bf(so[ti][tj][r]);
                }
            }
        }
        if (tid == 0) Pbuf[bh * NCHUNK + c] = expf(Lc[127]);
    }

    // P6: Y[t][p] = Ms . Xt^T  (+ D skip)
    {
        f32x4 ya[2][4] = {};
        #pragma unroll
        for (int k0 = 0; k0 < 128; k0 += 32) {
            bf16x8 af[2], bfr[4];
            #pragma unroll
            for (int ti = 0; ti < 2; ++ti)
                af[ti] = *(const bf16x8*)(Ms + (wave * 32 + ti * 16 + lr) * SLD + k0 + q * 8);
            #pragma unroll
            for (int tj = 0; tj < 4; ++tj)
                bfr[tj] = *(const bf16x8*)(Xt + (tj * 16 + lr) * SLD + k0 + q * 8);
            #pragma unroll
            for (int ti = 0; ti < 2; ++ti)
                #pragma unroll
                for (int tj = 0; tj < 4; ++tj)
                    ya[ti][tj] = __builtin_amdgcn_mfma_f32_16x16x32_bf16(af[ti], bfr[tj], ya[ti][tj], 0, 0, 0);
        }
        float Dv = Dh[h];
        float* ybb = yb + (size_t)t0g * 1536 + h * 64;
        #pragma unroll
        for (int ti = 0; ti < 2; ++ti) {
            #pragma unroll
            for (int r = 0; r < 4; ++r) {
                int t = wave * 32 + ti * 16 + q * 4 + r;
                #pragma unroll
                for (int tj = 0; tj < 4; ++tj) {
                    int p = tj * 16 + lr;
                    __bf16 xb = Xt[p * SLD + t];
                    float xv = bf2f(*(unsigned short*)&xb);
                    ybb[(size_t)t * 1536 + p] = ya[ti][tj][r] + Dv * xv;
                }
            }
        }
    }
}

// ---------- combine ----------
__global__ __launch_bounds__(256)
void combine_kernel(const unsigned short* __restrict__ sst,
                    unsigned short* __restrict__ sstT,
                    const float* __restrict__ Pbuf) {
    int flat = blockIdx.x * 256 + threadIdx.x;
    int bh = flat >> 13;
    int pn = flat & 8191;
    int n = pn >> 6, p = pn & 63;
    const unsigned short* sb = sst + (size_t)bh * NCHUNK * 8192;
    unsigned short* tb = sstT + (size_t)bh * NCHUNK * 8192 + p * 128 + n;
    const float* Pb = Pbuf + bh * NCHUNK;
    float s = 0.f;
    #pragma unroll
    for (int c = 0; c < NCHUNK; ++c) {
        float tmp = bf2f(sb[(size_t)c * 8192 + pn]);
        tb[(size_t)c * 8192] = f2bf(s);
        s = Pb[c] * s + tmp;
    }
}

// ---------- SSD inter kernel ----------
__global__ __launch_bounds__(256)
void ssd_inter_kernel(const unsigned short* __restrict__ Crow,
                      const float2* __restrict__ dtdA,
                      const unsigned short* __restrict__ sstT,
                      float* __restrict__ yb) {
    __shared__ __align__(16) __bf16 Cs[128 * SLD];
    __shared__ __align__(16) __bf16 St[64 * SLD];
    __shared__ float Lc[128];

    const int tid = threadIdx.x;
    const int blk = blockIdx.x;
    const int bh = blk / 15;
    const int c  = blk % 15 + 1;
    const int b = bh / 24, h = bh % 24;
    const int t0g = b * 2048 + c * QCHUNK;
    const int wave = tid >> 6, lane = tid & 63;
    const int lr = lane & 15, q = lane >> 4;

    for (int cc = tid; cc < 2048; cc += 256) {
        int r = cc >> 4, c8 = (cc & 15) << 3;
        *(uint4*)(Cs + r * SLD + c8) = *(const uint4*)(Crow + ((size_t)(t0g + r)) * 128 + c8);
    }
    const unsigned short* stb = sstT + ((size_t)(bh * NCHUNK + c)) * 8192;
    for (int cc = tid; cc < 1024; cc += 256) {
        int p = cc >> 4, c8 = (cc & 15) << 3;
        *(uint4*)(St + p * SLD + c8) = *(const uint4*)(stb + p * 128 + c8);
    }
    if (tid < 128) Lc[tid] = dtdA[((size_t)t0g + tid) * 24 + h].y;
    __syncthreads();
    for (int off = 1; off < 128; off <<= 1) {
        float v = 0.f;
        if (tid < 128 && tid >= off) v = Lc[tid - off];
        __syncthreads();
        if (tid < 128) Lc[tid] += v;
        __syncthreads();
    }

    f32x4 ya[2][4] = {};
    #pragma unroll
    for (int k0 = 0; k0 < 128; k0 += 32) {
        bf16x8 af[2], bfr[4];
        #pragma unroll
        for (int ti = 0; ti < 2; ++ti)
            af[ti] = *(const bf16x8*)(Cs + (wave * 32 + ti * 16 + lr) * SLD + k0 + q * 8);
        #pragma unroll
        for (int tj = 0; tj < 4; ++tj)
            bfr[tj] = *(const bf16x8*)(St + (tj * 16 + lr) * SLD + k0 + q * 8);
        #pragma unroll
        for (int ti = 0; ti < 2; ++ti)
            #pragma unroll
            for (int tj = 0; tj < 4; ++tj)
                ya[ti][tj] = __builtin_amdgcn_mfma_f32_16x16x32_bf16(af[ti], bfr[tj], ya[ti][tj], 0, 0, 0);
    }
    float* ybb = yb + (size_t)t0g * 1536 + h * 64;
    #pragma unroll
    for (int ti = 0; ti < 2; ++ti) {
        #pragma unroll
        for (int r = 0; r < 4; ++r) {
            int t = wave * 32 + ti * 16 + q * 4 + r;
            float sc = expf(Lc[t]);
            #pragma unroll
            for (int tj = 0; tj < 4; ++tj) {
                int p = tj * 16 + lr;
                float* yp = ybb + (size_t)t * 1536 + p;
                *yp = *yp + sc * ya[ti][tj][r];
            }
        }
    }
}

// ---------- gated RMSNorm: writes bf16 into zx cols [1536,3072) ----------
__global__ __launch_bounds__(256)
void norm_kernel(const float* __restrict__ yb,
                 unsigned short* __restrict__ zx,
                 const float* __restrict__ nw) {
    int row = blockIdx.x;
    const float* yr = yb + (size_t)row * 1536;
    unsigned short* zr = zx + (size_t)row * 3352;
    int tid = threadIdx.x;
    float u[6];
    float ss = 0.f;
    #pragma unroll
    for (int i = 0; i < 6; ++i) {
        int c = tid + i * 256;
        float z = bf2f(zr[c]);
        float uu = yr[c] * (z / (1.f + expf(-z)));
        u[i] = uu;
        ss += uu * uu;
    }
    #pragma unroll
    for (int m = 1; m < 64; m <<= 1) ss += __shfl_xor(ss, m);
    __shared__ float red[4];
    if ((tid & 63) == 0) red[tid >> 6] = ss;
    __syncthreads();
    float tot = red[0] + red[1] + red[2] + red[3];
    float inv = rsqrtf(tot * (1.f / 1536.f) + 1e-5f);
    #pragma unroll
    for (int i = 0; i < 6; ++i) {
        int c = tid + i * 256;
        zr[1536 + c] = f2bf(u[i] * inv * nw[c]);
    }
}

// ---------- launch ----------
extern "C" void kernel_launch(void* const* d_in, const int* in_sizes, int n_in,
                              void* d_out, int out_size, void* d_ws, size_t ws_size,
                              hipStream_t stream) {
    const float* x       = (const float*)d_in[0];
    const float* w_in    = (const float*)d_in[1];
    const float* conv_w  = (const float*)d_in[2];
    const float* conv_b  = (const float*)d_in[3];
    const float* dt_bias = (const float*)d_in[4];
    const float* A_log   = (const float*)d_in[5];
    const float* Dp      = (const float*)d_in[6];
    const float* nw      = (const float*)d_in[7];
    const float* w_out   = (const float*)d_in[8];
    float* out = (float*)d_out;

    char* ws = (char*)d_ws;
    const size_t off_zx   = 0;                        // 8192*3352 bf16 = 54,919,168
    const size_t off_A    = off_zx + 54919168;        // region A (58,720,256 reserved)
    const size_t off_xT   = off_A;                    // 25,165,824 (sstT + w_out_bf alias later)
    const size_t off_bT   = off_A + 25165824;         // 2,097,152
    const size_t off_Brow = off_A + 27262976;         // 2,097,152
    const size_t off_Crow = off_A + 29360128;         // 2,097,152
    const size_t off_dtdA = off_A + 58720256;         // 1,572,864
    const size_t off_y    = off_dtdA + 1572864;       // 50,331,648 (x_bf aliases head)
    const size_t off_sst  = off_y + 50331648;         // 25,165,824 (w_in_bf aliases head)
    const size_t off_P    = off_sst + 25165824;       // 6,144

    unsigned short* zx   = (unsigned short*)(ws + off_zx);
    unsigned short* xT   = (unsigned short*)(ws + off_xT);
    unsigned short* bT   = (unsigned short*)(ws + off_bT);
    unsigned short* Brow = (unsigned short*)(ws + off_Brow);
    unsigned short* Crow = (unsigned short*)(ws + off_Crow);
    float2* dtdA = (float2*)(ws + off_dtdA);
    float* yb    = (float*)(ws + off_y);
    unsigned short* sst  = (unsigned short*)(ws + off_sst);
    unsigned short* sstT = xT;                        // xT dead after ssd_local
    float* Pbuf = (float*)(ws + off_P);

    // transient aliases (dead regions at time of use)
    unsigned short* x_bf     = (unsigned short*)(ws + off_y);    // gemm1 only (before yb written)
    unsigned short* w_in_bf  = (unsigned short*)(ws + off_sst);  // gemm1 only (before sst written)
    unsigned short* w_out_bf = (unsigned short*)(ws + off_xT);   // written after sstT dead (step 7.5)

    static bool attr_set = false;
    if (!attr_set) {
        hipFuncSetAttribute((const void*)ssd_local_kernel,
                            hipFuncAttributeMaxDynamicSharedMemorySize, 70656);
        hipFuncSetAttribute((const void*)gemm_8phase,
                            hipFuncAttributeMaxDynamicSharedMemorySize, 131072);
        hipFuncSetAttribute((const void*)gemm_out,
                            hipFuncAttributeMaxDynamicSharedMemorySize, 65536);
        attr_set = true;
    }

    // 0. convert x, w_in (padded to 3584 rows) -> bf16
    convert_kernel<<<4416, 256, 0, stream>>>(x, w_in, x_bf, w_in_bf);
    // 1. in_proj (M=8192, N=3352 padded 3584, K=768) — 256x256 swizzled pipeline
    gemm_8phase<<<448, 512, 131072, stream>>>(x_bf, w_in_bf, zx, 3352, 768);
    // 2. fused conv + silu + layout (replaces conv_silu + transpose; cv eliminated)
    conv_fused_kernel<<<3584, 256, 0, stream>>>(zx, conv_w, conv_b, xT, bT, Brow, Crow);
    // 3. dt / log-dA (full f32)
    dt_kernel<<<8192, 64, 0, stream>>>(x, w_in, dt_bias, A_log, dtdA);
    // 4. SSD local
    ssd_local_kernel<<<1536, 256, 70656, stream>>>(Brow, Crow, dtdA, xT, bT, Dp, yb, sst, Pbuf);
    // 5. combine
    combine_kernel<<<3072, 256, 0, stream>>>(sst, sstT, Pbuf);
    // 6. SSD inter
    ssd_inter_kernel<<<1440, 256, 0, stream>>>(Crow, dtdA, sstT, yb);
    // 6.5 convert w_out -> bf16 (xT/sstT region dead now)
    convert_wout_kernel<<<576, 256, 0, stream>>>(w_out, w_out_bf);
    // 7. gated RMSNorm -> bf16 into zx cols [1536,3072)
    norm_kernel<<<8192, 256, 0, stream>>>(yb, zx, nw);
    // 8. out_proj + residual — swizzled counted-vmcnt pipeline, 384 blocks co-resident
    gemm_out<<<384, 512, 65536, stream>>>(zx + 1536, w_out_bf, out, x, 3352);
}

// Round 5
// 405.143 us; speedup vs baseline: 1.1212x; 1.0014x over previous
//
#include <hip/hip_runtime.h>
#include <math.h>

// ---------- types ----------
typedef __bf16 bf16x8 __attribute__((ext_vector_type(8)));
typedef float  f32x4  __attribute__((ext_vector_type(4)));

#define QCHUNK 128
#define NCHUNK 16
#define SLD 136              // LDS row stride (bf16 elems) for 128-wide arrays

__device__ __forceinline__ float bf2f(unsigned short u) {
    union { unsigned int i; float f; } v; v.i = ((unsigned int)u) << 16; return v.f;
}
__device__ __forceinline__ unsigned short f2bf(float f) {
    union { float f; unsigned int i; } v; v.f = f;
    unsigned int x = v.i;
    unsigned int r = (x + 0x7FFFu + ((x >> 16) & 1u)) >> 16;
    return (unsigned short)r;
}
__device__ __forceinline__ uint4 pack8(float4 a, float4 b) {
    uint4 r;
    r.x = (unsigned)f2bf(a.x) | ((unsigned)f2bf(a.y) << 16);
    r.y = (unsigned)f2bf(a.z) | ((unsigned)f2bf(a.w) << 16);
    r.z = (unsigned)f2bf(b.x) | ((unsigned)f2bf(b.y) << 16);
    r.w = (unsigned)f2bf(b.z) | ((unsigned)f2bf(b.w) << 16);
    return r;
}
__device__ __forceinline__ void load_lds16(const void* g, void* l) {
    __builtin_amdgcn_global_load_lds((const __attribute__((address_space(1))) void*)g,
                                     (__attribute__((address_space(3))) void*)l,
                                     16, 0, 0);
}

// ---------- convert: x -> x_bf, w_in -> w_in_bf (padded 3584 rows, zero-filled) ----------
__global__ __launch_bounds__(256)
void convert_kernel(const float* __restrict__ x, const float* __restrict__ w_in,
                    unsigned short* __restrict__ x_bf, unsigned short* __restrict__ w_in_bf) {
    int idx = blockIdx.x * 256 + threadIdx.x;      // 8 elems each
    const int NX  = 8192 * 768 / 8;                // 786432
    const int NW1 = 3584 * 768 / 8;                // 344064 (padded to 14x256 tiles)
    const int NW1r = 3352 * 768 / 8;               // 321792 (real)
    if (idx < NX) {
        const float* s = x + (size_t)idx * 8;
        *(uint4*)(x_bf + (size_t)idx * 8) = pack8(*(const float4*)s, *(const float4*)(s + 4));
    } else if (idx < NX + NW1) {
        int j = idx - NX;
        uint4 v = make_uint4(0u, 0u, 0u, 0u);
        if (j < NW1r) {
            const float* s = w_in + (size_t)j * 8;
            v = pack8(*(const float4*)s, *(const float4*)(s + 4));
        }
        *(uint4*)(w_in_bf + (size_t)j * 8) = v;
    }
}

// ---------- convert w_out -> bf16 ----------
__global__ __launch_bounds__(256)
void convert_wout_kernel(const float* __restrict__ w_out, unsigned short* __restrict__ w_out_bf) {
    int idx = blockIdx.x * 256 + threadIdx.x;      // 147456 total
    const float* s = w_out + (size_t)idx * 8;
    *(uint4*)(w_out_bf + (size_t)idx * 8) = pack8(*(const float4*)s, *(const float4*)(s + 4));
}

// ---------- 256x256 8-phase GEMM (T2+T3+T4+T5): Out[m,n] = sum_k A[m,k]*Bw[n,k], bf16 out ----------
// 512 threads = 8 waves (2 wr x 4 wc); per-wave 128x64 out; BK=64 per K-tile, 4 phases/tile.
// LDS (region-contiguous): A[dbuf][kh][h][wblk][64r x 64B] @0 (2x32KB); B[dbuf][kh][256r x 64B]
// @65536 (2x32KB) = 128 KiB. Swizzle: 16B granule g' = q ^ ((row>>1)&3) on reads; inverse
// (tid&3)^((tid>>3)&3) pre-applied to global source (linear gload dest) -> 8 granules x 2 lanes.
// Phase = {ds_reads ; 2x global_load_lds (region freed LAST phase, tile t+2) ; barrier ;
// lgkmcnt(0)+schedbar ; setprio(1) ; 16 MFMA ; setprio(0) ; [ph4: vmcnt(6)+schedbar] ; barrier}.
__global__ __launch_bounds__(512)
void gemm_8phase(const unsigned short* __restrict__ A,
                 const unsigned short* __restrict__ Bw,
                 unsigned short* __restrict__ Out,
                 int N_real, int K) {
    extern __shared__ __align__(16) char smem[];

    const int tid = threadIdx.x;
    const int bid = blockIdx.x;
    // XCD-chunked: 448 = 8 XCDs x 56; n-fastest within chunk (A-panel 1.6MB stays L2-resident)
    const int xcd = bid & 7, local = bid >> 3;
    const int mt = xcd * 4 + local / 14;       // 4 m-tiles per XCD
    const int nt = local % 14;
    const int m0 = mt * 256, n0 = nt * 256;

    const int wave = tid >> 6, lane = tid & 63;
    const int wr = wave >> 2, wc = wave & 3;
    const int lr = lane & 15, q = lane >> 4;

    // read offsets: swz lane-constant (row>>1 ≡ lr>>1 mod 4 for all frag rows)
    const int swz = (q ^ ((lr >> 1) & 3)) << 4;
    const int ao  = wr * 4096 + lr * 64 + swz;     // + kh*16384 + h*8192 + j*1024
    const int bo  = wc * 4096 + lr * 64 + swz;     // + kh*16384 + n*1024

    // staging: linear LDS dest (tid*16); global slot inverse-swizzled
    const int w_    = tid >> 8;                // A wblk
    const int rib   = (tid >> 2) & 63;         // A row-in-block
    const int gslot = (tid & 3) ^ ((tid >> 3) & 3);
    const unsigned short* gA = A  + (size_t)(m0 + w_ * 128 + rib) * K + gslot * 8;
    const unsigned short* gB = Bw + (size_t)(n0 + (tid >> 2)) * K + gslot * 8;

    const int NT = K >> 6;                     // 12
    f32x4 acc[8][4] = {};

#define STAGE_A(u, kh, h)                                                              \
    load_lds16(gA + (size_t)(h) * 64 * K + (size_t)(u) * 64 + (kh) * 32,               \
               smem + ((u) & 1) * 32768 + (kh) * 16384 + (h) * 8192 + (size_t)tid * 16)
#define STAGE_B(u, kh, hb)                                                             \
    load_lds16(gB + (size_t)(hb) * 128 * K + (size_t)(u) * 64 + (kh) * 32,             \
               smem + 65536 + ((u) & 1) * 32768 + (kh) * 16384 + (hb) * 8192 + (size_t)tid * 16)
#define PH_READ_A(kh, h)                                           \
    {                                                              \
        const char* p_ = pa + (kh) * 16384 + (h) * 8192;           \
        af[0] = *(const bf16x8*)(p_ + ao);                         \
        af[1] = *(const bf16x8*)(p_ + ao + 1024);                  \
        af[2] = *(const bf16x8*)(p_ + ao + 2048);                  \
        af[3] = *(const bf16x8*)(p_ + ao + 3072);                  \
    }
#define PH_READ_B(kh)                                              \
    {                                                              \
        const char* p_ = pb + (kh) * 16384;                        \
        bfr[0] = *(const bf16x8*)(p_ + bo);                        \
        bfr[1] = *(const bf16x8*)(p_ + bo + 1024);                 \
        bfr[2] = *(const bf16x8*)(p_ + bo + 2048);                 \
        bfr[3] = *(const bf16x8*)(p_ + bo + 3072);                 \
    }
#define PH_MFMA(mb)                                                                     \
    __builtin_amdgcn_s_setprio(1);                                                      \
    _Pragma("unroll")                                                                   \
    for (int jj = 0; jj < 4; ++jj)                                                      \
        _Pragma("unroll")                                                               \
        for (int nn = 0; nn < 4; ++nn)                                                  \
            acc[(mb) + jj][nn] =                                                        \
                __builtin_amdgcn_mfma_f32_16x16x32_bf16(af[jj], bfr[nn],                \
                                                        acc[(mb) + jj][nn], 0, 0, 0);  \
    __builtin_amdgcn_s_setprio(0);
#define BAR()   __builtin_amdgcn_s_barrier()
#define LGKM0() do { asm volatile("s_waitcnt lgkmcnt(0)" ::: "memory");                \
                     __builtin_amdgcn_sched_barrier(0); } while (0)
#define VMW(n)  do { asm volatile("s_waitcnt vmcnt(" #n ")" ::: "memory");             \
                     __builtin_amdgcn_sched_barrier(0); } while (0)

    // prologue: tile0 all 8 chunks, tile1 first 6 (last 2 issued at tile0 ph1)
    STAGE_A(0, 0, 0); STAGE_B(0, 0, 0); STAGE_B(0, 0, 1); STAGE_A(0, 0, 1);
    STAGE_A(0, 1, 0); STAGE_B(0, 1, 0); STAGE_B(0, 1, 1); STAGE_A(0, 1, 1);
    STAGE_A(1, 0, 0); STAGE_B(1, 0, 0); STAGE_B(1, 0, 1); STAGE_A(1, 0, 1);
    STAGE_A(1, 1, 0); STAGE_B(1, 1, 0);
    VMW(6);                                    // tile0's 8 landed (6 = tile1's in flight)
    BAR();

    for (int t = 0; t < NT; ++t) {
        const int d = t & 1;
        const char* pa = smem +         d * 32768;
        const char* pb = smem + 65536 + d * 32768;
        bf16x8 af[4], bfr[4];

        // ph1: kh0, A-half0 (+ all B kh0)
        PH_READ_B(0); PH_READ_A(0, 0);
        if (t + 1 < NT) { STAGE_B(t + 1, 1, 1); STAGE_A(t + 1, 1, 1); }
        BAR(); LGKM0();
        PH_MFMA(0);
        BAR();

        // ph2: kh0, A-half1 (B kh0 regs persist)
        PH_READ_A(0, 1);
        if (t + 2 < NT) { STAGE_A(t + 2, 0, 0); STAGE_B(t + 2, 0, 0); }
        BAR(); LGKM0();
        PH_MFMA(4);
        BAR();

        // ph3: kh1, A-half0 (+ all B kh1)
        PH_READ_B(1); PH_READ_A(1, 0);
        if (t + 2 < NT) { STAGE_B(t + 2, 0, 1); STAGE_A(t + 2, 0, 1); }
        BAR(); LGKM0();
        PH_MFMA(0);
        BAR();

        // ph4: kh1, A-half1 ; gate next tile with counted vmcnt (never 0 mid-loop)
        PH_READ_A(1, 1);
        if (t + 2 < NT) { STAGE_A(t + 2, 1, 0); STAGE_B(t + 2, 1, 0); }
        BAR(); LGKM0();
        PH_MFMA(4);
        if (t + 2 < NT)      VMW(6);
        else if (t + 1 < NT) VMW(0);
        BAR();
    }

#undef STAGE_A
#undef STAGE_B
#undef PH_READ_A
#undef PH_READ_B
#undef PH_MFMA
#undef BAR
#undef LGKM0
#undef VMW

    // epilogue: C/D layout col=lane&15, row=(lane>>4)*4+reg
    #pragma unroll
    for (int m = 0; m < 8; ++m) {
        #pragma unroll
        for (int r = 0; r < 4; ++r) {
            int row = m0 + wr * 128 + m * 16 + q * 4 + r;
            #pragma unroll
            for (int n = 0; n < 4; ++n) {
                int col = n0 + wc * 64 + n * 16 + lr;
                if (col < N_real)
                    Out[(size_t)row * N_real + col] = f2bf(acc[m][n][r]);
            }
        }
    }
}

// ---------- out_proj GEMM: Out[m,n] = sum_k A[m,k]*Bw[n,k] + Resid, f32 out ----------
// M=8192, N=768, K=1536. BM=BN=128, 512 threads = 8 waves (2x4), per-wave 64x32.
// 128B-row + (row&7)<<4 XOR swizzle; per-tile vmcnt(4) gating.
// LDS: A[2dbuf][128][128B] @0 (32KB), B @32768 (32KB) = 64 KiB -> 2 blocks/CU.
__global__ __launch_bounds__(512)
void gemm_out(const unsigned short* __restrict__ A,
              const unsigned short* __restrict__ Bw,
              float* __restrict__ Out, const float* __restrict__ Resid,
              int lda) {
    extern __shared__ __align__(16) char smem[];
    const int K = 1536, Nn = 768;

    const int tid = threadIdx.x;
    const int bid = blockIdx.x;
    // XCD-chunked: 384 = 8 x 48; n-fastest (A panel 3.1MB/XCD ~L2-resident)
    const int xcd = bid & 7, local = bid >> 3;
    const int mt = xcd * 8 + local / 6;        // 0..63
    const int nt = local % 6;                  // 0..5
    const int m0 = mt * 128, n0 = nt * 128;

    const int wave = tid >> 6, lane = tid & 63;
    const int wr = wave >> 2, wc = wave & 3;
    const int lr = lane & 15, q = lane >> 4;

    const int gl   = (lr & 7) << 4;
    const int arow = wr * 64 + lr;             // + m*16
    const int brow = wc * 32 + lr;             // + n*16
    const int colq = q << 4;

    const int srow  = tid >> 3;                // 0..63
    const int sslot = (tid & 7) ^ (srow & 7);
    const unsigned short* ga = A  + (size_t)(m0 + srow) * lda + sslot * 8;
    const unsigned short* gb = Bw + (size_t)(n0 + srow) * K   + sslot * 8;
    char* sAd = smem +         (size_t)tid * 16;
    char* sBd = smem + 32768 + (size_t)tid * 16;
    const size_t gstep_a = (size_t)64 * lda;
    const size_t gstep_b = (size_t)64 * K;

    f32x4 acc[4][2] = {};

    // prologue: tile0 -> dbuf0 (4 issues: 2 A + 2 B)
    #pragma unroll
    for (int i = 0; i < 2; ++i) {
        load_lds16(ga + (size_t)i * gstep_a, sAd + i * 8192);
        load_lds16(gb + (size_t)i * gstep_b, sBd + i * 8192);
    }

    const int NT = K >> 6;   // 24
    for (int t = 0; t < NT; ++t) {
        const int d = t & 1;
        const bool more = (t + 1 < NT);
        if (more) {
            const size_t kg = (size_t)(t + 1) * 64;
            const int ld = (d ^ 1) * 16384;
            #pragma unroll
            for (int i = 0; i < 2; ++i) {
                load_lds16(ga + kg + (size_t)i * gstep_a, sAd + ld + i * 8192);
                load_lds16(gb + kg + (size_t)i * gstep_b, sBd + ld + i * 8192);
            }
            asm volatile("s_waitcnt vmcnt(4)" ::: "memory");
            __builtin_amdgcn_sched_barrier(0);
        } else {
            asm volatile("s_waitcnt vmcnt(0)" ::: "memory");
            __builtin_amdgcn_sched_barrier(0);
        }
        __builtin_amdgcn_s_barrier();

        const char* pa = smem +         d * 16384;
        const char* pb = smem + 32768 + d * 16384;
        #pragma unroll
        for (int kh = 0; kh < 2; ++kh) {
            const int col = ((kh << 6) | colq) ^ gl;
            bf16x8 af[4], bfr[2];
            #pragma unroll
            for (int m = 0; m < 4; ++m)
                af[m] = *(const bf16x8*)(pa + (arow + m * 16) * 128 + col);
            #pragma unroll
            for (int n = 0; n < 2; ++n)
                bfr[n] = *(const bf16x8*)(pb + (brow + n * 16) * 128 + col);

            __builtin_amdgcn_s_setprio(1);
            #pragma unroll
            for (int m = 0; m < 4; ++m)
                #pragma unroll
                for (int n = 0; n < 2; ++n)
                    acc[m][n] = __builtin_amdgcn_mfma_f32_16x16x32_bf16(af[m], bfr[n], acc[m][n], 0, 0, 0);
            __builtin_amdgcn_s_setprio(0);
        }
        __builtin_amdgcn_s_barrier();
    }

    // epilogue: f32 out + residual (N=768 = 6x128 exactly, no masking)
    #pragma unroll
    for (int m = 0; m < 4; ++m) {
        #pragma unroll
        for (int r = 0; r < 4; ++r) {
            int row = m0 + wr * 64 + m * 16 + q * 4 + r;
            #pragma unroll
            for (int n = 0; n < 2; ++n) {
                int col = n0 + wc * 32 + n * 16 + lr;
                Out[(size_t)row * Nn + col] = acc[m][n][r] + Resid[(size_t)row * Nn + col];
            }
        }
    }
}

// ---------- fused conv(4)+silu+layout: zx xBC cols -> xT (transposed), bT (transposed), Brow/Crow (row-major), all bf16 ----------
// grid: b(4) x t-tile(32) x ch-tile(28), 256 threads. Tile 64 t x 64 ch.
__global__ __launch_bounds__(256)
void conv_fused_kernel(const unsigned short* __restrict__ zx,
                       const float* __restrict__ cw, const float* __restrict__ cb,
                       unsigned short* __restrict__ xT, unsigned short* __restrict__ bT,
                       unsigned short* __restrict__ Brow, unsigned short* __restrict__ Crow) {
    __shared__ unsigned short outt[64][66];
    __shared__ float cwl[64][4];
    __shared__ float cbl[64];

    int blk = blockIdx.x;
    int cht = blk % 28;
    int tt  = (blk / 28) % 32;
    int b   = blk / (28 * 32);
    int ch0 = cht * 64, t0 = tt * 64;
    int tid = threadIdx.x;
    int tx = tid & 63, ty = tid >> 6;

    if (tid < 64) cbl[tid] = cb[ch0 + tid];
    cwl[tid >> 2][tid & 3] = cw[(ch0 + (tid >> 2)) * 4 + (tid & 3)];
    __syncthreads();

    const unsigned short* zp = zx + (size_t)(b * 2048) * 3352 + 1536 + ch0 + tx;
    float w0 = cwl[tx][0], w1 = cwl[tx][1], w2 = cwl[tx][2], w3 = cwl[tx][3];
    float bias = cbl[tx];
    int tg = t0 + ty * 16;                 // first output t for this thread
    float r0 = (tg >= 3) ? bf2f(zp[(size_t)(tg - 3) * 3352]) : 0.f;
    float r1 = (tg >= 2) ? bf2f(zp[(size_t)(tg - 2) * 3352]) : 0.f;
    float r2 = (tg >= 1) ? bf2f(zp[(size_t)(tg - 1) * 3352]) : 0.f;
    #pragma unroll
    for (int k = 0; k < 16; ++k) {
        float cur = bf2f(zp[(size_t)(tg + k) * 3352]);
        float a = bias + r0 * w0 + r1 * w1 + r2 * w2 + cur * w3;
        a = a / (1.f + expf(-a));          // silu
        outt[ty * 16 + k][tx] = f2bf(a);
        r0 = r1; r1 = r2; r2 = cur;
    }
    __syncthreads();

    if (ch0 < 1536) {
        // x region: transposed write xT[ch][t]
        unsigned short* dst = xT + ((size_t)(b * 1536 + ch0)) * 2048 + t0;
        #pragma unroll
        for (int k = 0; k < 16; ++k) {
            int chl = ty * 16 + k;
            dst[(size_t)chl * 2048 + tx] = outt[tx][chl];
        }
    } else if (ch0 < 1664) {
        // B region: transposed bT[n][t] + row-major Brow[t][n]
        int n0 = ch0 - 1536;
        unsigned short* dstT = bT + ((size_t)(b * 128 + n0)) * 2048 + t0;
        #pragma unroll
        for (int k = 0; k < 16; ++k) {
            int chl = ty * 16 + k;
            dstT[(size_t)chl * 2048 + tx] = outt[tx][chl];
        }
        unsigned short* dstR = Brow + ((size_t)(b * 2048 + t0)) * 128 + n0;
        int tl = tid >> 3, c8 = (tid & 7) << 3;
        #pragma unroll
        for (int it = 0; it < 2; ++it) {
            int t = tl + it * 32;
            unsigned short tmp[8];
            #pragma unroll
            for (int jj = 0; jj < 8; ++jj) tmp[jj] = outt[t][c8 + jj];
            *(uint4*)(dstR + (size_t)t * 128 + c8) = *(uint4*)tmp;
        }
    } else {
        // C region: row-major Crow[t][n]
        int n0 = ch0 - 1664;
        unsigned short* dstR = Crow + ((size_t)(b * 2048 + t0)) * 128 + n0;
        int tl = tid >> 3, c8 = (tid & 7) << 3;
        #pragma unroll
        for (int it = 0; it < 2; ++it) {
            int t = tl + it * 32;
            unsigned short tmp[8];
            #pragma unroll
            for (int jj = 0; jj < 8; ++jj) tmp[jj] = outt[t][c8 + jj];
            *(uint4*)(dstR + (size_t)t * 128 + c8) = *(uint4*)tmp;
        }
    }
}

// ---------- dt in full f32 -> interleaved (dt, dt*A) float2 ----------
__global__ __launch_bounds__(64)
void dt_kernel(const float* __restrict__ x, const float* __restrict__ w_in,
               const float* __restrict__ dt_bias, const float* __restrict__ A_log,
               float2* __restrict__ dtdA) {
    int row = blockIdx.x;
    int lane = threadIdx.x;
    float xv[12];
    #pragma unroll
    for (int i = 0; i < 12; ++i) xv[i] = x[(size_t)row * 768 + i * 64 + lane];
    for (int h = 0; h < 24; ++h) {
        const float* w = w_in + (size_t)(3328 + h) * 768;
        float acc = 0.f;
        #pragma unroll
        for (int i = 0; i < 12; ++i) acc += xv[i] * w[i * 64 + lane];
        #pragma unroll
        for (int m = 1; m < 64; m <<= 1) acc += __shfl_xor(acc, m);
        if (lane == 0) {
            float v = acc + dt_bias[h];
            float dt = (v > 20.f) ? v : log1pf(expf(v));
            float A = -expf(A_log[h]);
            dtdA[(size_t)row * 24 + h] = make_float2(dt, dt * A);   // (dt, log dA)
        }
    }
}

// ---------- SSD local kernel: per (b,h,chunk): G -> M -> Y, s_out ----------
__global__ __launch_bounds__(256)
void ssd_local_kernel(const unsigned short* __restrict__ Brow,
                      const unsigned short* __restrict__ Crow,
                      const float2* __restrict__ dtdA,
                      const unsigned short* __restrict__ xT,
                      const unsigned short* __restrict__ bT,
                      const float* __restrict__ Dh,
                      float* __restrict__ yb,
                      unsigned short* __restrict__ sst,
                      float* __restrict__ Pbuf) {
    extern __shared__ __align__(16) char smem[];
    __bf16* Bs  = (__bf16*)smem;                 // 128 x SLD; later Xt(0:17408)+Xtw(17408:34816)
    __bf16* Cs  = (__bf16*)(smem + 34816);       // 128 x SLD; later Ms
    float*  Lc  = (float*)(smem + 69632);        // 128
    float*  dtl = (float*)(smem + 70144);        // 128

    const int tid = threadIdx.x;
    const int c   = blockIdx.x & 15;
    const int bh  = blockIdx.x >> 4;
    const int b   = bh / 24, h = bh % 24;
    const int t0g = b * 2048 + c * QCHUNK;
    const int wave = tid >> 6, lane = tid & 63;
    const int lr = lane & 15, q = lane >> 4;

    for (int cc = tid; cc < 2048; cc += 256) {
        int r = cc >> 4, c8 = (cc & 15) << 3;
        *(uint4*)(Bs + r * SLD + c8) = *(const uint4*)(Brow + ((size_t)(t0g + r)) * 128 + c8);
        *(uint4*)(Cs + r * SLD + c8) = *(const uint4*)(Crow + ((size_t)(t0g + r)) * 128 + c8);
    }
    if (tid < 128) {
        float2 dd = dtdA[((size_t)t0g + tid) * 24 + h];
        dtl[tid] = dd.x;
        Lc[tid]  = dd.y;     // log dA
    }
    __syncthreads();
    for (int off = 1; off < 128; off <<= 1) {
        float v = 0.f;
        if (tid < 128 && tid >= off) v = Lc[tid - off];
        __syncthreads();
        if (tid < 128) Lc[tid] += v;
        __syncthreads();
    }

    // P1: G = Cs . Bs^T
    const int wm = (wave & 1) * 64, wn = (wave >> 1) * 64;
    f32x4 g[4][4] = {};
    #pragma unroll
    for (int k0 = 0; k0 < 128; k0 += 32) {
        bf16x8 af[4], bfr[4];
        #pragma unroll
        for (int t = 0; t < 4; ++t) {
            af[t]  = *(const bf16x8*)(Cs + (wm + t * 16 + lr) * SLD + k0 + q * 8);
            bfr[t] = *(const bf16x8*)(Bs + (wn + t * 16 + lr) * SLD + k0 + q * 8);
        }
        #pragma unroll
        for (int ti = 0; ti < 4; ++ti)
            #pragma unroll
            for (int tj = 0; tj < 4; ++tj)
                g[ti][tj] = __builtin_amdgcn_mfma_f32_16x16x32_bf16(af[ti], bfr[tj], g[ti][tj], 0, 0, 0);
    }
    __syncthreads();

    // P5: masked scale -> Ms[t][tau]
    __bf16* Ms = Cs;
    {
        float lt_[4], dt_[4];
        #pragma unroll
        for (int tj = 0; tj < 4; ++tj) {
            int tau = wn + tj * 16 + lr;
            lt_[tj] = Lc[tau];
            dt_[tj] = dtl[tau];
        }
        #pragma unroll
        for (int ti = 0; ti < 4; ++ti) {
            #pragma unroll
            for (int r = 0; r < 4; ++r) {
                int t = wm + ti * 16 + q * 4 + r;
                float Lt = Lc[t];
                #pragma unroll
                for (int tj = 0; tj < 4; ++tj) {
                    int tau = wn + tj * 16 + lr;
                    float mv = (tau <= t) ? g[ti][tj][r] * expf(Lt - lt_[tj]) * dt_[tj] : 0.f;
                    unsigned short u = f2bf(mv);
                    Ms[t * SLD + tau] = *(__bf16*)&u;
                }
            }
        }
    }

    // P3: stage Xt[p][t] and Xtw[p][t]
    __bf16* Xt  = Bs;
    __bf16* Xtw = (__bf16*)(smem + 17408);
    {
        float LQ = Lc[127];
        const unsigned short* xTb = xT + ((size_t)(b * 1536 + h * 64)) * 2048 + c * QCHUNK;
        for (int cc = tid; cc < 1024; cc += 256) {
            int p = cc >> 4, c8 = (cc & 15) << 3;
            uint4 v = *(const uint4*)(xTb + (size_t)p * 2048 + c8);
            *(uint4*)(Xt + p * SLD + c8) = v;
            unsigned short uu[8] = {(unsigned short)(v.x & 0xFFFF), (unsigned short)(v.x >> 16),
                                    (unsigned short)(v.y & 0xFFFF), (unsigned short)(v.y >> 16),
                                    (unsigned short)(v.z & 0xFFFF), (unsigned short)(v.z >> 16),
                                    (unsigned short)(v.w & 0xFFFF), (unsigned short)(v.w >> 16)};
            float w0[8];
            #pragma unroll
            for (int jj = 0; jj < 8; ++jj) {
                int tau = c8 + jj;
                w0[jj] = bf2f(uu[jj]) * expf(LQ - Lc[tau]) * dtl[tau];
            }
            *(uint4*)(Xtw + p * SLD + c8) = pack8(make_float4(w0[0], w0[1], w0[2], w0[3]),
                                                  make_float4(w0[4], w0[5], w0[6], w0[7]));
        }
    }
    __syncthreads();

    // P4: s_out[n][p] = bT . Xtw^T
    {
        f32x4 so[2][4] = {};
        const unsigned short* bTb = bT + ((size_t)(b * 128)) * 2048 + c * QCHUNK;
        #pragma unroll
        for (int k0 = 0; k0 < 128; k0 += 32) {
            bf16x8 af[2], bfr[4];
            #pragma unroll
            for (int ti = 0; ti < 2; ++ti) {
                int n = wave * 32 + ti * 16 + lr;
                af[ti] = *(const bf16x8*)(bTb + (size_t)n * 2048 + k0 + q * 8);
            }
            #pragma unroll
            for (int tj = 0; tj < 4; ++tj)
                bfr[tj] = *(const bf16x8*)(Xtw + (tj * 16 + lr) * SLD + k0 + q * 8);
            #pragma unroll
            for (int ti = 0; ti < 2; ++ti)
                #pragma unroll
                for (int tj = 0; tj < 4; ++tj)
                    so[ti][tj] = __builtin_amdgcn_mfma_f32_16x16x32_bf16(af[ti], bfr[tj], so[ti][tj], 0, 0, 0);
        }
        unsigned short* sb = sst + ((size_t)(bh * NCHUNK + c)) * 8192;
        #pragma unroll
        for (int ti = 0; ti < 2; ++ti) {
            #pragma unroll
            for (int r = 0; r < 4; ++r) {
                int n = wave * 32 + ti * 16 + q * 4 + r;
                #pragma unroll
                for (int tj = 0; tj < 4; ++tj) {
                    int p = tj * 16 + lr;
                    sb[n * 64 + p] = f2bf(so[ti][tj][r]);
                }
            }
        }
        if (tid == 0) Pbuf[bh * NCHUNK + c] = expf(Lc[127]);
    }

    // P6: Y[t][p] = Ms . Xt^T  (+ D skip)
    {
        f32x4 ya[2][4] = {};
        #pragma unroll
        for (int k0 = 0; k0 < 128; k0 += 32) {
            bf16x8 af[2], bfr[4];
            #pragma unroll
            for (int ti = 0; ti < 2; ++ti)
                af[ti] = *(const bf16x8*)(Ms + (wave * 32 + ti * 16 + lr) * SLD + k0 + q * 8);
            #pragma unroll
            for (int tj = 0; tj < 4; ++tj)
                bfr[tj] = *(const bf16x8*)(Xt + (tj * 16 + lr) * SLD + k0 + q * 8);
            #pragma unroll
            for (int ti = 0; ti < 2; ++ti)
                #pragma unroll
                for (int tj = 0; tj < 4; ++tj)
                    ya[ti][tj] = __builtin_amdgcn_mfma_f32_16x16x32_bf16(af[ti], bfr[tj], ya[ti][tj], 0, 0, 0);
        }
        float Dv = Dh[h];
        float* ybb = yb + (size_t)t0g * 1536 + h * 64;
        #pragma unroll
        for (int ti = 0; ti < 2; ++ti) {
            #pragma unroll
            for (int r = 0; r < 4; ++r) {
                int t = wave * 32 + ti * 16 + q * 4 + r;
                #pragma unroll
                for (int tj = 0; tj < 4; ++tj) {
                    int p = tj * 16 + lr;
                    __bf16 xb = Xt[p * SLD + t];
                    float xv = bf2f(*(unsigned short*)&xb);
                    ybb[(size_t)t * 1536 + p] = ya[ti][tj][r] + Dv * xv;
                }
            }
        }
    }
}

// ---------- combine ----------
__global__ __launch_bounds__(256)
void combine_kernel(const unsigned short* __restrict__ sst,
                    unsigned short* __restrict__ sstT,
                    const float* __restrict__ Pbuf) {
    int flat = blockIdx.x * 256 + threadIdx.x;
    int bh = flat >> 13;
    int pn = flat & 8191;
    int n = pn >> 6, p = pn & 63;
    const unsigned short* sb = sst + (size_t)bh * NCHUNK * 8192;
    unsigned short* tb = sstT + (size_t)bh * NCHUNK * 8192 + p * 128 + n;
    const float* Pb = Pbuf + bh * NCHUNK;
    float s = 0.f;
    #pragma unroll
    for (int c = 0; c < NCHUNK; ++c) {
        float tmp = bf2f(sb[(size_t)c * 8192 + pn]);
        tb[(size_t)c * 8192] = f2bf(s);
        s = Pb[c] * s + tmp;
    }
}

// ---------- SSD inter kernel ----------
__global__ __launch_bounds__(256)
void ssd_inter_kernel(const unsigned short* __restrict__ Crow,
                      const float2* __restrict__ dtdA,
                      const unsigned short* __restrict__ sstT,
                      float* __restrict__ yb) {
    __shared__ __align__(16) __bf16 Cs[128 * SLD];
    __shared__ __align__(16) __bf16 St[64 * SLD];
    __shared__ float Lc[128];

    const int tid = threadIdx.x;
    const int blk = blockIdx.x;
    const int bh = blk / 15;
    const int c  = blk % 15 + 1;
    const int b = bh / 24, h = bh % 24;
    const int t0g = b * 2048 + c * QCHUNK;
    const int wave = tid >> 6, lane = tid & 63;
    const int lr = lane & 15, q = lane >> 4;

    for (int cc = tid; cc < 2048; cc += 256) {
        int r = cc >> 4, c8 = (cc & 15) << 3;
        *(uint4*)(Cs + r * SLD + c8) = *(const uint4*)(Crow + ((size_t)(t0g + r)) * 128 + c8);
    }
    const unsigned short* stb = sstT + ((size_t)(bh * NCHUNK + c)) * 8192;
    for (int cc = tid; cc < 1024; cc += 256) {
        int p = cc >> 4, c8 = (cc & 15) << 3;
        *(uint4*)(St + p * SLD + c8) = *(const uint4*)(stb + p * 128 + c8);
    }
    if (tid < 128) Lc[tid] = dtdA[((size_t)t0g + tid) * 24 + h].y;
    __syncthreads();
    for (int off = 1; off < 128; off <<= 1) {
        float v = 0.f;
        if (tid < 128 && tid >= off) v = Lc[tid - off];
        __syncthreads();
        if (tid < 128) Lc[tid] += v;
        __syncthreads();
    }

    f32x4 ya[2][4] = {};
    #pragma unroll
    for (int k0 = 0; k0 < 128; k0 += 32) {
        bf16x8 af[2], bfr[4];
        #pragma unroll
        for (int ti = 0; ti < 2; ++ti)
            af[ti] = *(const bf16x8*)(Cs + (wave * 32 + ti * 16 + lr) * SLD + k0 + q * 8);
        #pragma unroll
        for (int tj = 0; tj < 4; ++tj)
            bfr[tj] = *(const bf16x8*)(St + (tj * 16 + lr) * SLD + k0 + q * 8);
        #pragma unroll
        for (int ti = 0; ti < 2; ++ti)
            #pragma unroll
            for (int tj = 0; tj < 4; ++tj)
                ya[ti][tj] = __builtin_amdgcn_mfma_f32_16x16x32_bf16(af[ti], bfr[tj], ya[ti][tj], 0, 0, 0);
    }
    float* ybb = yb + (size_t)t0g * 1536 + h * 64;
    #pragma unroll
    for (int ti = 0; ti < 2; ++ti) {
        #pragma unroll
        for (int r = 0; r < 4; ++r) {
            int t = wave * 32 + ti * 16 + q * 4 + r;
            float sc = expf(Lc[t]);
            #pragma unroll
            for (int tj = 0; tj < 4; ++tj) {
                int p = tj * 16 + lr;
                float* yp = ybb + (size_t)t * 1536 + p;
                *yp = *yp + sc * ya[ti][tj][r];
            }
        }
    }
}

// ---------- gated RMSNorm: writes bf16 into zx cols [1536,3072) ----------
__global__ __launch_bounds__(256)
void norm_kernel(const float* __restrict__ yb,
                 unsigned short* __restrict__ zx,
                 const float* __restrict__ nw) {
    int row = blockIdx.x;
    const float* yr = yb + (size_t)row * 1536;
    unsigned short* zr = zx + (size_t)row * 3352;
    int tid = threadIdx.x;
    float u[6];
    float ss = 0.f;
    #pragma unroll
    for (int i = 0; i < 6; ++i) {
        int c = tid + i * 256;
        float z = bf2f(zr[c]);
        float uu = yr[c] * (z / (1.f + expf(-z)));
        u[i] = uu;
        ss += uu * uu;
    }
    #pragma unroll
    for (int m = 1; m < 64; m <<= 1) ss += __shfl_xor(ss, m);
    __shared__ float red[4];
    if ((tid & 63) == 0) red[tid >> 6] = ss;
    __syncthreads();
    float tot = red[0] + red[1] + red[2] + red[3];
    float inv = rsqrtf(tot * (1.f / 1536.f) + 1e-5f);
    #pragma unroll
    for (int i = 0; i < 6; ++i) {
        int c = tid + i * 256;
        zr[1536 + c] = f2bf(u[i] * inv * nw[c]);
    }
}

// ---------- launch ----------
extern "C" void kernel_launch(void* const* d_in, const int* in_sizes, int n_in,
                              void* d_out, int out_size, void* d_ws, size_t ws_size,
                              hipStream_t stream) {
    const float* x       = (const float*)d_in[0];
    const float* w_in    = (const float*)d_in[1];
    const float* conv_w  = (const float*)d_in[2];
    const float* conv_b  = (const float*)d_in[3];
    const float* dt_bias = (const float*)d_in[4];
    const float* A_log   = (const float*)d_in[5];
    const float* Dp      = (const float*)d_in[6];
    const float* nw      = (const float*)d_in[7];
    const float* w_out   = (const float*)d_in[8];
    float* out = (float*)d_out;

    char* ws = (char*)d_ws;
    const size_t off_zx   = 0;                        // 8192*3352 bf16 = 54,919,168
    const size_t off_A    = off_zx + 54919168;        // region A (58,720,256 reserved)
    const size_t off_xT   = off_A;                    // 25,165,824 (sstT + w_out_bf alias later)
    const size_t off_bT   = off_A + 25165824;         // 2,097,152
    const size_t off_Brow = off_A + 27262976;         // 2,097,152
    const size_t off_Crow = off_A + 29360128;         // 2,097,152
    const size_t off_dtdA = off_A + 58720256;         // 1,572,864
    const size_t off_y    = off_dtdA + 1572864;       // 50,331,648 (x_bf aliases head)
    const size_t off_sst  = off_y + 50331648;         // 25,165,824 (w_in_bf aliases head)
    const size_t off_P    = off_sst + 25165824;       // 6,144

    unsigned short* zx   = (unsigned short*)(ws + off_zx);
    unsigned short* xT   = (unsigned short*)(ws + off_xT);
    unsigned short* bT   = (unsigned short*)(ws + off_bT);
    unsigned short* Brow = (unsigned short*)(ws + off_Brow);
    unsigned short* Crow = (unsigned short*)(ws + off_Crow);
    float2* dtdA = (float2*)(ws + off_dtdA);
    float* yb    = (float*)(ws + off_y);
    unsigned short* sst  = (unsigned short*)(ws + off_sst);
    unsigned short* sstT = xT;                        // xT dead after ssd_local
    float* Pbuf = (float*)(ws + off_P);

    // transient aliases (dead regions at time of use)
    unsigned short* x_bf     = (unsigned short*)(ws + off_y);    // gemm1 only (before yb written)
    unsigned short* w_in_bf  = (unsigned short*)(ws + off_sst);  // gemm1 only (before sst written)
    unsigned short* w_out_bf = (unsigned short*)(ws + off_xT);   // written after sstT dead (step 7.5)

    static bool attr_set = false;
    if (!attr_set) {
        hipFuncSetAttribute((const void*)ssd_local_kernel,
                            hipFuncAttributeMaxDynamicSharedMemorySize, 70656);
        hipFuncSetAttribute((const void*)gemm_8phase,
                            hipFuncAttributeMaxDynamicSharedMemorySize, 131072);
        hipFuncSetAttribute((const void*)gemm_out,
                            hipFuncAttributeMaxDynamicSharedMemorySize, 65536);
        attr_set = true;
    }

    // 0. convert x, w_in (padded to 3584 rows) -> bf16
    convert_kernel<<<4416, 256, 0, stream>>>(x, w_in, x_bf, w_in_bf);
    // 1. in_proj (M=8192, N=3352 padded 3584, K=768) — 256x256 8-phase pipeline
    gemm_8phase<<<448, 512, 131072, stream>>>(x_bf, w_in_bf, zx, 3352, 768);
    // 2. fused conv + silu + layout (replaces conv_silu + transpose; cv eliminated)
    conv_fused_kernel<<<3584, 256, 0, stream>>>(zx, conv_w, conv_b, xT, bT, Brow, Crow);
    // 3. dt / log-dA (full f32)
    dt_kernel<<<8192, 64, 0, stream>>>(x, w_in, dt_bias, A_log, dtdA);
    // 4. SSD local
    ssd_local_kernel<<<1536, 256, 70656, stream>>>(Brow, Crow, dtdA, xT, bT, Dp, yb, sst, Pbuf);
    // 5. combine
    combine_kernel<<<3072, 256, 0, stream>>>(sst, sstT, Pbuf);
    // 6. SSD inter
    ssd_inter_kernel<<<1440, 256, 0, stream>>>(Crow, dtdA, sstT, yb);
    // 6.5 convert w_out -> bf16 (xT/sstT region dead now)
    convert_wout_kernel<<<576, 256, 0, stream>>>(w_out, w_out_bf);
    // 7. gated RMSNorm -> bf16 into zx cols [1536,3072)
    norm_kernel<<<8192, 256, 0, stream>>>(yb, zx, nw);
    // 8. out_proj + residual — swizzled counted-vmcnt pipeline, 384 blocks co-resident
    gemm_out<<<384, 512, 65536, stream>>>(zx + 1536, w_out_bf, out, x, 3352);
}

// Round 6
// 359.551 us; speedup vs baseline: 1.2634x; 1.1268x over previous
//
#include <hip/hip_runtime.h>
#include <math.h>

// ---------- types ----------
typedef __bf16 bf16x8 __attribute__((ext_vector_type(8)));
typedef float  f32x4  __attribute__((ext_vector_type(4)));

#define QCHUNK 128
#define NCHUNK 16
#define SLD 136              // LDS row stride (bf16 elems) for 128-wide arrays

__device__ __forceinline__ float bf2f(unsigned short u) {
    union { unsigned int i; float f; } v; v.i = ((unsigned int)u) << 16; return v.f;
}
__device__ __forceinline__ unsigned short f2bf(float f) {
    union { float f; unsigned int i; } v; v.f = f;
    unsigned int x = v.i;
    unsigned int r = (x + 0x7FFFu + ((x >> 16) & 1u)) >> 16;
    return (unsigned short)r;
}
__device__ __forceinline__ uint4 pack8(float4 a, float4 b) {
    uint4 r;
    r.x = (unsigned)f2bf(a.x) | ((unsigned)f2bf(a.y) << 16);
    r.y = (unsigned)f2bf(a.z) | ((unsigned)f2bf(a.w) << 16);
    r.z = (unsigned)f2bf(b.x) | ((unsigned)f2bf(b.y) << 16);
    r.w = (unsigned)f2bf(b.z) | ((unsigned)f2bf(b.w) << 16);
    return r;
}
__device__ __forceinline__ void load_lds16(const void* g, void* l) {
    __builtin_amdgcn_global_load_lds((const __attribute__((address_space(1))) void*)g,
                                     (__attribute__((address_space(3))) void*)l,
                                     16, 0, 0);
}

// ---------- convert: x -> x_bf, w_in -> w_in_bf (padded 3584 rows, zero-filled) ----------
__global__ __launch_bounds__(256)
void convert_kernel(const float* __restrict__ x, const float* __restrict__ w_in,
                    unsigned short* __restrict__ x_bf, unsigned short* __restrict__ w_in_bf) {
    int idx = blockIdx.x * 256 + threadIdx.x;      // 8 elems each
    const int NX  = 8192 * 768 / 8;                // 786432
    const int NW1 = 3584 * 768 / 8;                // 344064 (padded to 14x256 tiles)
    const int NW1r = 3352 * 768 / 8;               // 321792 (real)
    if (idx < NX) {
        const float* s = x + (size_t)idx * 8;
        *(uint4*)(x_bf + (size_t)idx * 8) = pack8(*(const float4*)s, *(const float4*)(s + 4));
    } else if (idx < NX + NW1) {
        int j = idx - NX;
        uint4 v = make_uint4(0u, 0u, 0u, 0u);
        if (j < NW1r) {
            const float* s = w_in + (size_t)j * 8;
            v = pack8(*(const float4*)s, *(const float4*)(s + 4));
        }
        *(uint4*)(w_in_bf + (size_t)j * 8) = v;
    }
}

// ---------- convert w_out -> bf16 ----------
__global__ __launch_bounds__(256)
void convert_wout_kernel(const float* __restrict__ w_out, unsigned short* __restrict__ w_out_bf) {
    int idx = blockIdx.x * 256 + threadIdx.x;      // 147456 total
    const float* s = w_out + (size_t)idx * 8;
    *(uint4*)(w_out_bf + (size_t)idx * 8) = pack8(*(const float4*)s, *(const float4*)(s + 4));
}

// ---------- 256x256 pipelined GEMM: Out[m,n] = sum_k A[m,k]*Bw[n,k], bf16 out ----------
// (R3 form — best measured at 62.7 µs.) 512 threads = 8 waves (2 wr x 4 wc); per-wave 128x64;
// K-tile 64 (full 128B LDS row). LDS: A[2dbuf][256][128B] @0, B @65536 = 128 KiB.
// Swizzle both-sides: granule g of row r stores global slot g^(r&7); read col ^= (r&7)<<4.
// Per tile: stage next tile's 8 loads, gate vmcnt(8) (never 0 mid-loop), 2 barriers/tile.
__global__ __launch_bounds__(512)
void gemm_8phase(const unsigned short* __restrict__ A,
                 const unsigned short* __restrict__ Bw,
                 unsigned short* __restrict__ Out,
                 int N_real, int K) {
    extern __shared__ __align__(16) char smem[];

    const int tid = threadIdx.x;
    const int bid = blockIdx.x;
    // XCD-chunked: 448 = 8 XCDs x 56; n-fastest within chunk (A-panel 1.6MB stays L2-resident)
    const int xcd = bid & 7, local = bid >> 3;
    const int mt = xcd * 4 + local / 14;       // 4 m-tiles per XCD
    const int nt = local % 14;
    const int m0 = mt * 256, n0 = nt * 256;

    const int wave = tid >> 6, lane = tid & 63;
    const int wr = wave >> 2, wc = wave & 3;
    const int lr = lane & 15, q = lane >> 4;

    const int gl   = (lr & 7) << 4;            // row-granule XOR bits (bits 4-6)
    const int arow = wr * 128 + lr;            // + m*16
    const int brow = wc * 64 + lr;             // + n*16
    const int colq = q << 4;                   // + kh*64, then ^ gl

    // staging: LDS linear (row=tid>>3 + i*64, slot=tid&7); global source slot pre-swizzled
    const int srow  = tid >> 3;                // 0..63
    const int sslot = (tid & 7) ^ (srow & 7);
    const unsigned short* ga = A  + (size_t)(m0 + srow) * K + sslot * 8;
    const unsigned short* gb = Bw + (size_t)(n0 + srow) * K + sslot * 8;
    char* sAd = smem +         (size_t)tid * 16;
    char* sBd = smem + 65536 + (size_t)tid * 16;
    const size_t gstep = (size_t)64 * K;

    const int NT = K >> 6;                     // 12
    f32x4 acc[8][4] = {};

    // prologue: tile0 -> dbuf0 (8 issues: 4 A + 4 B)
    #pragma unroll
    for (int i = 0; i < 4; ++i) {
        load_lds16(ga + (size_t)i * gstep, sAd + i * 8192);
        load_lds16(gb + (size_t)i * gstep, sBd + i * 8192);
    }

    for (int t = 0; t < NT; ++t) {
        const int d = t & 1;
        const bool more = (t + 1 < NT);
        if (more) {                            // stage tile t+1 -> other dbuf
            const size_t kg = (size_t)(t + 1) * 64;
            const int ld = (d ^ 1) * 32768;
            #pragma unroll
            for (int i = 0; i < 4; ++i) {
                load_lds16(ga + kg + (size_t)i * gstep, sAd + ld + i * 8192);
                load_lds16(gb + kg + (size_t)i * gstep, sBd + ld + i * 8192);
            }
            asm volatile("s_waitcnt vmcnt(8)" ::: "memory");   // tile t's 8 landed
        } else {
            asm volatile("s_waitcnt vmcnt(0)" ::: "memory");
        }
        __builtin_amdgcn_s_barrier();

        const char* pa = smem +         d * 32768;
        const char* pb = smem + 65536 + d * 32768;
        #pragma unroll
        for (int kh = 0; kh < 2; ++kh) {
            const int col = ((kh << 6) | colq) ^ gl;
            bf16x8 af[8], bfr[4];
            #pragma unroll
            for (int m = 0; m < 8; ++m)
                af[m] = *(const bf16x8*)(pa + (arow + m * 16) * 128 + col);
            #pragma unroll
            for (int n = 0; n < 4; ++n)
                bfr[n] = *(const bf16x8*)(pb + (brow + n * 16) * 128 + col);

            __builtin_amdgcn_s_setprio(1);
            #pragma unroll
            for (int m = 0; m < 8; ++m)
                #pragma unroll
                for (int n = 0; n < 4; ++n)
                    acc[m][n] = __builtin_amdgcn_mfma_f32_16x16x32_bf16(af[m], bfr[n], acc[m][n], 0, 0, 0);
            __builtin_amdgcn_s_setprio(0);
        }
        __builtin_amdgcn_s_barrier();          // dbuf d free for iteration t+1's staging
    }

    // epilogue: C/D layout col=lane&15, row=(lane>>4)*4+reg
    #pragma unroll
    for (int m = 0; m < 8; ++m) {
        #pragma unroll
        for (int r = 0; r < 4; ++r) {
            int row = m0 + wr * 128 + m * 16 + q * 4 + r;
            #pragma unroll
            for (int n = 0; n < 4; ++n) {
                int col = n0 + wc * 64 + n * 16 + lr;
                if (col < N_real)
                    Out[(size_t)row * N_real + col] = f2bf(acc[m][n][r]);
            }
        }
    }
}

// ---------- out_proj GEMM: Out[m,n] = sum_k A[m,k]*Bw[n,k] + Resid, f32 out ----------
// M=8192, N=768, K=1536. BM=BN=128, 512 threads = 8 waves (2x4), per-wave 64x32.
// 128B-row + (row&7)<<4 XOR swizzle; per-tile vmcnt(4) gating.
// LDS: A[2dbuf][128][128B] @0 (32KB), B @32768 (32KB) = 64 KiB -> 2 blocks/CU.
__global__ __launch_bounds__(512)
void gemm_out(const unsigned short* __restrict__ A,
              const unsigned short* __restrict__ Bw,
              float* __restrict__ Out, const float* __restrict__ Resid,
              int lda) {
    extern __shared__ __align__(16) char smem[];
    const int K = 1536, Nn = 768;

    const int tid = threadIdx.x;
    const int bid = blockIdx.x;
    // XCD-chunked: 384 = 8 x 48; n-fastest (A panel 3.1MB/XCD ~L2-resident)
    const int xcd = bid & 7, local = bid >> 3;
    const int mt = xcd * 8 + local / 6;        // 0..63
    const int nt = local % 6;                  // 0..5
    const int m0 = mt * 128, n0 = nt * 128;

    const int wave = tid >> 6, lane = tid & 63;
    const int wr = wave >> 2, wc = wave & 3;
    const int lr = lane & 15, q = lane >> 4;

    const int gl   = (lr & 7) << 4;
    const int arow = wr * 64 + lr;             // + m*16
    const int brow = wc * 32 + lr;             // + n*16
    const int colq = q << 4;

    const int srow  = tid >> 3;                // 0..63
    const int sslot = (tid & 7) ^ (srow & 7);
    const unsigned short* ga = A  + (size_t)(m0 + srow) * lda + sslot * 8;
    const unsigned short* gb = Bw + (size_t)(n0 + srow) * K   + sslot * 8;
    char* sAd = smem +         (size_t)tid * 16;
    char* sBd = smem + 32768 + (size_t)tid * 16;
    const size_t gstep_a = (size_t)64 * lda;
    const size_t gstep_b = (size_t)64 * K;

    f32x4 acc[4][2] = {};

    // prologue: tile0 -> dbuf0 (4 issues: 2 A + 2 B)
    #pragma unroll
    for (int i = 0; i < 2; ++i) {
        load_lds16(ga + (size_t)i * gstep_a, sAd + i * 8192);
        load_lds16(gb + (size_t)i * gstep_b, sBd + i * 8192);
    }

    const int NT = K >> 6;   // 24
    for (int t = 0; t < NT; ++t) {
        const int d = t & 1;
        const bool more = (t + 1 < NT);
        if (more) {
            const size_t kg = (size_t)(t + 1) * 64;
            const int ld = (d ^ 1) * 16384;
            #pragma unroll
            for (int i = 0; i < 2; ++i) {
                load_lds16(ga + kg + (size_t)i * gstep_a, sAd + ld + i * 8192);
                load_lds16(gb + kg + (size_t)i * gstep_b, sBd + ld + i * 8192);
            }
            asm volatile("s_waitcnt vmcnt(4)" ::: "memory");
        } else {
            asm volatile("s_waitcnt vmcnt(0)" ::: "memory");
        }
        __builtin_amdgcn_s_barrier();

        const char* pa = smem +         d * 16384;
        const char* pb = smem + 32768 + d * 16384;
        #pragma unroll
        for (int kh = 0; kh < 2; ++kh) {
            const int col = ((kh << 6) | colq) ^ gl;
            bf16x8 af[4], bfr[2];
            #pragma unroll
            for (int m = 0; m < 4; ++m)
                af[m] = *(const bf16x8*)(pa + (arow + m * 16) * 128 + col);
            #pragma unroll
            for (int n = 0; n < 2; ++n)
                bfr[n] = *(const bf16x8*)(pb + (brow + n * 16) * 128 + col);

            __builtin_amdgcn_s_setprio(1);
            #pragma unroll
            for (int m = 0; m < 4; ++m)
                #pragma unroll
                for (int n = 0; n < 2; ++n)
                    acc[m][n] = __builtin_amdgcn_mfma_f32_16x16x32_bf16(af[m], bfr[n], acc[m][n], 0, 0, 0);
            __builtin_amdgcn_s_setprio(0);
        }
        __builtin_amdgcn_s_barrier();
    }

    // epilogue: f32 out + residual (N=768 = 6x128 exactly, no masking)
    #pragma unroll
    for (int m = 0; m < 4; ++m) {
        #pragma unroll
        for (int r = 0; r < 4; ++r) {
            int row = m0 + wr * 64 + m * 16 + q * 4 + r;
            #pragma unroll
            for (int n = 0; n < 2; ++n) {
                int col = n0 + wc * 32 + n * 16 + lr;
                Out[(size_t)row * Nn + col] = acc[m][n][r] + Resid[(size_t)row * Nn + col];
            }
        }
    }
}

// ---------- fused conv(4)+silu+layout: zx xBC cols -> xT (transposed), bT (transposed), Brow/Crow (row-major), all bf16 ----------
// grid: b(4) x t-tile(32) x ch-tile(28), 256 threads. Tile 64 t x 64 ch.
__global__ __launch_bounds__(256)
void conv_fused_kernel(const unsigned short* __restrict__ zx,
                       const float* __restrict__ cw, const float* __restrict__ cb,
                       unsigned short* __restrict__ xT, unsigned short* __restrict__ bT,
                       unsigned short* __restrict__ Brow, unsigned short* __restrict__ Crow) {
    __shared__ unsigned short outt[64][66];
    __shared__ float cwl[64][4];
    __shared__ float cbl[64];

    int blk = blockIdx.x;
    int cht = blk % 28;
    int tt  = (blk / 28) % 32;
    int b   = blk / (28 * 32);
    int ch0 = cht * 64, t0 = tt * 64;
    int tid = threadIdx.x;
    int tx = tid & 63, ty = tid >> 6;

    if (tid < 64) cbl[tid] = cb[ch0 + tid];
    cwl[tid >> 2][tid & 3] = cw[(ch0 + (tid >> 2)) * 4 + (tid & 3)];
    __syncthreads();

    const unsigned short* zp = zx + (size_t)(b * 2048) * 3352 + 1536 + ch0 + tx;
    float w0 = cwl[tx][0], w1 = cwl[tx][1], w2 = cwl[tx][2], w3 = cwl[tx][3];
    float bias = cbl[tx];
    int tg = t0 + ty * 16;                 // first output t for this thread
    float r0 = (tg >= 3) ? bf2f(zp[(size_t)(tg - 3) * 3352]) : 0.f;
    float r1 = (tg >= 2) ? bf2f(zp[(size_t)(tg - 2) * 3352]) : 0.f;
    float r2 = (tg >= 1) ? bf2f(zp[(size_t)(tg - 1) * 3352]) : 0.f;
    #pragma unroll
    for (int k = 0; k < 16; ++k) {
        float cur = bf2f(zp[(size_t)(tg + k) * 3352]);
        float a = bias + r0 * w0 + r1 * w1 + r2 * w2 + cur * w3;
        a = a / (1.f + expf(-a));          // silu
        outt[ty * 16 + k][tx] = f2bf(a);
        r0 = r1; r1 = r2; r2 = cur;
    }
    __syncthreads();

    if (ch0 < 1536) {
        // x region: transposed write xT[ch][t]
        unsigned short* dst = xT + ((size_t)(b * 1536 + ch0)) * 2048 + t0;
        #pragma unroll
        for (int k = 0; k < 16; ++k) {
            int chl = ty * 16 + k;
            dst[(size_t)chl * 2048 + tx] = outt[tx][chl];
        }
    } else if (ch0 < 1664) {
        // B region: transposed bT[n][t] + row-major Brow[t][n]
        int n0 = ch0 - 1536;
        unsigned short* dstT = bT + ((size_t)(b * 128 + n0)) * 2048 + t0;
        #pragma unroll
        for (int k = 0; k < 16; ++k) {
            int chl = ty * 16 + k;
            dstT[(size_t)chl * 2048 + tx] = outt[tx][chl];
        }
        unsigned short* dstR = Brow + ((size_t)(b * 2048 + t0)) * 128 + n0;
        int tl = tid >> 3, c8 = (tid & 7) << 3;
        #pragma unroll
        for (int it = 0; it < 2; ++it) {
            int t = tl + it * 32;
            unsigned short tmp[8];
            #pragma unroll
            for (int jj = 0; jj < 8; ++jj) tmp[jj] = outt[t][c8 + jj];
            *(uint4*)(dstR + (size_t)t * 128 + c8) = *(uint4*)tmp;
        }
    } else {
        // C region: row-major Crow[t][n]
        int n0 = ch0 - 1664;
        unsigned short* dstR = Crow + ((size_t)(b * 2048 + t0)) * 128 + n0;
        int tl = tid >> 3, c8 = (tid & 7) << 3;
        #pragma unroll
        for (int it = 0; it < 2; ++it) {
            int t = tl + it * 32;
            unsigned short tmp[8];
            #pragma unroll
            for (int jj = 0; jj < 8; ++jj) tmp[jj] = outt[t][c8 + jj];
            *(uint4*)(dstR + (size_t)t * 128 + c8) = *(uint4*)tmp;
        }
    }
}

// ---------- dt in full f32 -> interleaved (dt, dt*A) float2 ----------
__global__ __launch_bounds__(64)
void dt_kernel(const float* __restrict__ x, const float* __restrict__ w_in,
               const float* __restrict__ dt_bias, const float* __restrict__ A_log,
               float2* __restrict__ dtdA) {
    int row = blockIdx.x;
    int lane = threadIdx.x;
    float xv[12];
    #pragma unroll
    for (int i = 0; i < 12; ++i) xv[i] = x[(size_t)row * 768 + i * 64 + lane];
    for (int h = 0; h < 24; ++h) {
        const float* w = w_in + (size_t)(3328 + h) * 768;
        float acc = 0.f;
        #pragma unroll
        for (int i = 0; i < 12; ++i) acc += xv[i] * w[i * 64 + lane];
        #pragma unroll
        for (int m = 1; m < 64; m <<= 1) acc += __shfl_xor(acc, m);
        if (lane == 0) {
            float v = acc + dt_bias[h];
            float dt = (v > 20.f) ? v : log1pf(expf(v));
            float A = -expf(A_log[h]);
            dtdA[(size_t)row * 24 + h] = make_float2(dt, dt * A);   // (dt, log dA)
        }
    }
}

// ---------- SSD local kernel: per (b,h,chunk): G -> M -> Y, s_out ----------
__global__ __launch_bounds__(256)
void ssd_local_kernel(const unsigned short* __restrict__ Brow,
                      const unsigned short* __restrict__ Crow,
                      const float2* __restrict__ dtdA,
                      const unsigned short* __restrict__ xT,
                      const unsigned short* __restrict__ bT,
                      const float* __restrict__ Dh,
                      float* __restrict__ yb,
                      unsigned short* __restrict__ sst,
                      float* __restrict__ Pbuf) {
    extern __shared__ __align__(16) char smem[];
    __bf16* Bs  = (__bf16*)smem;                 // 128 x SLD; later Xt(0:17408)+Xtw(17408:34816)
    __bf16* Cs  = (__bf16*)(smem + 34816);       // 128 x SLD; later Ms
    float*  Lc  = (float*)(smem + 69632);        // 128
    float*  dtl = (float*)(smem + 70144);        // 128

    const int tid = threadIdx.x;
    const int c   = blockIdx.x & 15;
    const int bh  = blockIdx.x >> 4;
    const int b   = bh / 24, h = bh % 24;
    const int t0g = b * 2048 + c * QCHUNK;
    const int wave = tid >> 6, lane = tid & 63;
    const int lr = lane & 15, q = lane >> 4;

    for (int cc = tid; cc < 2048; cc += 256) {
        int r = cc >> 4, c8 = (cc & 15) << 3;
        *(uint4*)(Bs + r * SLD + c8) = *(const uint4*)(Brow + ((size_t)(t0g + r)) * 128 + c8);
        *(uint4*)(Cs + r * SLD + c8) = *(const uint4*)(Crow + ((size_t)(t0g + r)) * 128 + c8);
    }
    if (tid < 128) {
        float2 dd = dtdA[((size_t)t0g + tid) * 24 + h];
        dtl[tid] = dd.x;
        Lc[tid]  = dd.y;     // log dA
    }
    __syncthreads();
    for (int off = 1; off < 128; off <<= 1) {
        float v = 0.f;
        if (tid < 128 && tid >= off) v = Lc[tid - off];
        __syncthreads();
        if (tid < 128) Lc[tid] += v;
        __syncthreads();
    }

    // P1: G = Cs . Bs^T
    const int wm = (wave & 1) * 64, wn = (wave >> 1) * 64;
    f32x4 g[4][4] = {};
    #pragma unroll
    for (int k0 = 0; k0 < 128; k0 += 32) {
        bf16x8 af[4], bfr[4];
        #pragma unroll
        for (int t = 0; t < 4; ++t) {
            af[t]  = *(const bf16x8*)(Cs + (wm + t * 16 + lr) * SLD + k0 + q * 8);
            bfr[t] = *(const bf16x8*)(Bs + (wn + t * 16 + lr) * SLD + k0 + q * 8);
        }
        #pragma unroll
        for (int ti = 0; ti < 4; ++ti)
            #pragma unroll
            for (int tj = 0; tj < 4; ++tj)
                g[ti][tj] = __builtin_amdgcn_mfma_f32_16x16x32_bf16(af[ti], bfr[tj], g[ti][tj], 0, 0, 0);
    }
    __syncthreads();

    // P5: masked scale -> Ms[t][tau]
    __bf16* Ms = Cs;
    {
        float lt_[4], dt_[4];
        #pragma unroll
        for (int tj = 0; tj < 4; ++tj) {
            int tau = wn + tj * 16 + lr;
            lt_[tj] = Lc[tau];
            dt_[tj] = dtl[tau];
        }
        #pragma unroll
        for (int ti = 0; ti < 4; ++ti) {
            #pragma unroll
            for (int r = 0; r < 4; ++r) {
                int t = wm + ti * 16 + q * 4 + r;
                float Lt = Lc[t];
                #pragma unroll
                for (int tj = 0; tj < 4; ++tj) {
                    int tau = wn + tj * 16 + lr;
                    float mv = (tau <= t) ? g[ti][tj][r] * expf(Lt - lt_[tj]) * dt_[tj] : 0.f;
                    unsigned short u = f2bf(mv);
                    Ms[t * SLD + tau] = *(__bf16*)&u;
                }
            }
        }
    }

    // P3: stage Xt[p][t] and Xtw[p][t]
    __bf16* Xt  = Bs;
    __bf16* Xtw = (__bf16*)(smem + 17408);
    {
        float LQ = Lc[127];
        const unsigned short* xTb = xT + ((size_t)(b * 1536 + h * 64)) * 2048 + c * QCHUNK;
        for (int cc = tid; cc < 1024; cc += 256) {
            int p = cc >> 4, c8 = (cc & 15) << 3;
            uint4 v = *(const uint4*)(xTb + (size_t)p * 2048 + c8);
            *(uint4*)(Xt + p * SLD + c8) = v;
            unsigned short uu[8] = {(unsigned short)(v.x & 0xFFFF), (unsigned short)(v.x >> 16),
                                    (unsigned short)(v.y & 0xFFFF), (unsigned short)(v.y >> 16),
                                    (unsigned short)(v.z & 0xFFFF), (unsigned short)(v.z >> 16),
                                    (unsigned short)(v.w & 0xFFFF), (unsigned short)(v.w >> 16)};
            float w0[8];
            #pragma unroll
            for (int jj = 0; jj < 8; ++jj) {
                int tau = c8 + jj;
                w0[jj] = bf2f(uu[jj]) * expf(LQ - Lc[tau]) * dtl[tau];
            }
            *(uint4*)(Xtw + p * SLD + c8) = pack8(make_float4(w0[0], w0[1], w0[2], w0[3]),
                                                  make_float4(w0[4], w0[5], w0[6], w0[7]));
        }
    }
    __syncthreads();

    // P4: s_out[n][p] = bT . Xtw^T
    {
        f32x4 so[2][4] = {};
        const unsigned short* bTb = bT + ((size_t)(b * 128)) * 2048 + c * QCHUNK;
        #pragma unroll
        for (int k0 = 0; k0 < 128; k0 += 32) {
            bf16x8 af[2], bfr[4];
            #pragma unroll
            for (int ti = 0; ti < 2; ++ti) {
                int n = wave * 32 + ti * 16 + lr;
                af[ti] = *(const bf16x8*)(bTb + (size_t)n * 2048 + k0 + q * 8);
            }
            #pragma unroll
            for (int tj = 0; tj < 4; ++tj)
                bfr[tj] = *(const bf16x8*)(Xtw + (tj * 16 + lr) * SLD + k0 + q * 8);
            #pragma unroll
            for (int ti = 0; ti < 2; ++ti)
                #pragma unroll
                for (int tj = 0; tj < 4; ++tj)
                    so[ti][tj] = __builtin_amdgcn_mfma_f32_16x16x32_bf16(af[ti], bfr[tj], so[ti][tj], 0, 0, 0);
        }
        unsigned short* sb = sst + ((size_t)(bh * NCHUNK + c)) * 8192;
        #pragma unroll
        for (int ti = 0; ti < 2; ++ti) {
            #pragma unroll
            for (int r = 0; r < 4; ++r) {
                int n = wave * 32 + ti * 16 + q * 4 + r;
                #pragma unroll
                for (int tj = 0; tj < 4; ++tj) {
                    int p = tj * 16 + lr;
                    sb[n * 64 + p] = f2bf(so[ti][tj][r]);
                }
            }
        }
        if (tid == 0) Pbuf[bh * NCHUNK + c] = expf(Lc[127]);
    }

    // P6: Y[t][p] = Ms . Xt^T  (+ D skip)
    {
        f32x4 ya[2][4] = {};
        #pragma unroll
        for (int k0 = 0; k0 < 128; k0 += 32) {
            bf16x8 af[2], bfr[4];
            #pragma unroll
            for (int ti = 0; ti < 2; ++ti)
                af[ti] = *(const bf16x8*)(Ms + (wave * 32 + ti * 16 + lr) * SLD + k0 + q * 8);
            #pragma unroll
            for (int tj = 0; tj < 4; ++tj)
                bfr[tj] = *(const bf16x8*)(Xt + (tj * 16 + lr) * SLD + k0 + q * 8);
            #pragma unroll
            for (int ti = 0; ti < 2; ++ti)
                #pragma unroll
                for (int tj = 0; tj < 4; ++tj)
                    ya[ti][tj] = __builtin_amdgcn_mfma_f32_16x16x32_bf16(af[ti], bfr[tj], ya[ti][tj], 0, 0, 0);
        }
        float Dv = Dh[h];
        float* ybb = yb + (size_t)t0g * 1536 + h * 64;
        #pragma unroll
        for (int ti = 0; ti < 2; ++ti) {
            #pragma unroll
            for (int r = 0; r < 4; ++r) {
                int t = wave * 32 + ti * 16 + q * 4 + r;
                #pragma unroll
                for (int tj = 0; tj < 4; ++tj) {
                    int p = tj * 16 + lr;
                    __bf16 xb = Xt[p * SLD + t];
                    float xv = bf2f(*(unsigned short*)&xb);
                    ybb[(size_t)t * 1536 + p] = ya[ti][tj][r] + Dv * xv;
                }
            }
        }
    }
}

// ---------- combine: per-(bh, 32-p-slice) block; scan in registers, LDS transpose, ----------
// ---------- coalesced reads (64B segs) and fully-coalesced uint4 writes ----------
__global__ __launch_bounds__(256)
void combine_kernel(const unsigned short* __restrict__ sst,
                    unsigned short* __restrict__ sstT,
                    const float* __restrict__ Pbuf) {
    __shared__ unsigned short tl[32 * 130];        // [p-local 32][n 128], pad to 130
    const int blk = blockIdx.x;                    // 192 = 96 bh x 2 p-halves
    const int bh = blk >> 1;
    const int ph = (blk & 1) * 32;
    const int tid = threadIdx.x;
    const int pl = tid & 31;                       // p-local 0..31
    const int nb = tid >> 5;                       // 0..7
    const unsigned short* sb = sst + (size_t)bh * NCHUNK * 8192;
    unsigned short* tb = sstT + (size_t)bh * NCHUNK * 8192 + ph * 128;
    const float* Pb = Pbuf + bh * NCHUNK;

    float s[16];
    #pragma unroll
    for (int i = 0; i < 16; ++i) s[i] = 0.f;

    for (int c = 0; c < NCHUNK; ++c) {
        const float Pc = Pb[c];
        const unsigned short* sc = sb + (size_t)c * 8192;
        // scan step: read own pn values (64B-coalesced), stash OLD s transposed in LDS
        #pragma unroll
        for (int i = 0; i < 16; ++i) {
            int n = nb + 8 * i;                    // 0..127
            unsigned short v = sc[n * 64 + ph + pl];
            tl[pl * 130 + n] = f2bf(s[i]);
            s[i] = Pc * s[i] + bf2f(v);
        }
        __syncthreads();
        // emit transposed slab: 4096 elems = 512 uint4, 2 per thread, fully coalesced
        uint* tlw = (uint*)tl;
        uint4* tc4 = (uint4*)(tb + (size_t)c * 8192);
        #pragma unroll
        for (int k = 0; k < 2; ++k) {
            int j = tid + k * 256;                 // uint4 index 0..511
            int pp = j >> 4;                       // p-local
            int w0 = pp * 65 + (j & 15) * 4;       // word index in padded row
            tc4[j] = make_uint4(tlw[w0], tlw[w0 + 1], tlw[w0 + 2], tlw[w0 + 3]);
        }
        __syncthreads();
    }
}

// ---------- SSD inter kernel ----------
__global__ __launch_bounds__(256)
void ssd_inter_kernel(const unsigned short* __restrict__ Crow,
                      const float2* __restrict__ dtdA,
                      const unsigned short* __restrict__ sstT,
                      float* __restrict__ yb) {
    __shared__ __align__(16) __bf16 Cs[128 * SLD];
    __shared__ __align__(16) __bf16 St[64 * SLD];
    __shared__ float Lc[128];

    const int tid = threadIdx.x;
    const int blk = blockIdx.x;
    const int bh = blk / 15;
    const int c  = blk % 15 + 1;
    const int b = bh / 24, h = bh % 24;
    const int t0g = b * 2048 + c * QCHUNK;
    const int wave = tid >> 6, lane = tid & 63;
    const int lr = lane & 15, q = lane >> 4;

    for (int cc = tid; cc < 2048; cc += 256) {
        int r = cc >> 4, c8 = (cc & 15) << 3;
        *(uint4*)(Cs + r * SLD + c8) = *(const uint4*)(Crow + ((size_t)(t0g + r)) * 128 + c8);
    }
    const unsigned short* stb = sstT + ((size_t)(bh * NCHUNK + c)) * 8192;
    for (int cc = tid; cc < 1024; cc += 256) {
        int p = cc >> 4, c8 = (cc & 15) << 3;
        *(uint4*)(St + p * SLD + c8) = *(const uint4*)(stb + p * 128 + c8);
    }
    if (tid < 128) Lc[tid] = dtdA[((size_t)t0g + tid) * 24 + h].y;
    __syncthreads();
    for (int off = 1; off < 128; off <<= 1) {
        float v = 0.f;
        if (tid < 128 && tid >= off) v = Lc[tid - off];
        __syncthreads();
        if (tid < 128) Lc[tid] += v;
        __syncthreads();
    }

    f32x4 ya[2][4] = {};
    #pragma unroll
    for (int k0 = 0; k0 < 128; k0 += 32) {
        bf16x8 af[2], bfr[4];
        #pragma unroll
        for (int ti = 0; ti < 2; ++ti)
            af[ti] = *(const bf16x8*)(Cs + (wave * 32 + ti * 16 + lr) * SLD + k0 + q * 8);
        #pragma unroll
        for (int tj = 0; tj < 4; ++tj)
            bfr[tj] = *(const bf16x8*)(St + (tj * 16 + lr) * SLD + k0 + q * 8);
        #pragma unroll
        for (int ti = 0; ti < 2; ++ti)
            #pragma unroll
            for (int tj = 0; tj < 4; ++tj)
                ya[ti][tj] = __builtin_amdgcn_mfma_f32_16x16x32_bf16(af[ti], bfr[tj], ya[ti][tj], 0, 0, 0);
    }
    float* ybb = yb + (size_t)t0g * 1536 + h * 64;
    #pragma unroll
    for (int ti = 0; ti < 2; ++ti) {
        #pragma unroll
        for (int r = 0; r < 4; ++r) {
            int t = wave * 32 + ti * 16 + q * 4 + r;
            float sc = expf(Lc[t]);
            #pragma unroll
            for (int tj = 0; tj < 4; ++tj) {
                int p = tj * 16 + lr;
                float* yp = ybb + (size_t)t * 1536 + p;
                *yp = *yp + sc * ya[ti][tj][r];
            }
        }
    }
}

// ---------- gated RMSNorm: writes bf16 into zx cols [1536,3072) ----------
__global__ __launch_bounds__(256)
void norm_kernel(const float* __restrict__ yb,
                 unsigned short* __restrict__ zx,
                 const float* __restrict__ nw) {
    int row = blockIdx.x;
    const float* yr = yb + (size_t)row * 1536;
    unsigned short* zr = zx + (size_t)row * 3352;
    int tid = threadIdx.x;
    float u[6];
    float ss = 0.f;
    #pragma unroll
    for (int i = 0; i < 6; ++i) {
        int c = tid + i * 256;
        float z = bf2f(zr[c]);
        float uu = yr[c] * (z / (1.f + expf(-z)));
        u[i] = uu;
        ss += uu * uu;
    }
    #pragma unroll
    for (int m = 1; m < 64; m <<= 1) ss += __shfl_xor(ss, m);
    __shared__ float red[4];
    if ((tid & 63) == 0) red[tid >> 6] = ss;
    __syncthreads();
    float tot = red[0] + red[1] + red[2] + red[3];
    float inv = rsqrtf(tot * (1.f / 1536.f) + 1e-5f);
    #pragma unroll
    for (int i = 0; i < 6; ++i) {
        int c = tid + i * 256;
        zr[1536 + c] = f2bf(u[i] * inv * nw[c]);
    }
}

// ---------- launch ----------
extern "C" void kernel_launch(void* const* d_in, const int* in_sizes, int n_in,
                              void* d_out, int out_size, void* d_ws, size_t ws_size,
                              hipStream_t stream) {
    const float* x       = (const float*)d_in[0];
    const float* w_in    = (const float*)d_in[1];
    const float* conv_w  = (const float*)d_in[2];
    const float* conv_b  = (const float*)d_in[3];
    const float* dt_bias = (const float*)d_in[4];
    const float* A_log   = (const float*)d_in[5];
    const float* Dp      = (const float*)d_in[6];
    const float* nw      = (const float*)d_in[7];
    const float* w_out   = (const float*)d_in[8];
    float* out = (float*)d_out;

    char* ws = (char*)d_ws;
    const size_t off_zx   = 0;                        // 8192*3352 bf16 = 54,919,168
    const size_t off_A    = off_zx + 54919168;        // region A (58,720,256 reserved)
    const size_t off_xT   = off_A;                    // 25,165,824 (sstT + w_out_bf alias later)
    const size_t off_bT   = off_A + 25165824;         // 2,097,152
    const size_t off_Brow = off_A + 27262976;         // 2,097,152
    const size_t off_Crow = off_A + 29360128;         // 2,097,152
    const size_t off_dtdA = off_A + 58720256;         // 1,572,864
    const size_t off_y    = off_dtdA + 1572864;       // 50,331,648 (x_bf aliases head)
    const size_t off_sst  = off_y + 50331648;         // 25,165,824 (w_in_bf aliases head)
    const size_t off_P    = off_sst + 25165824;       // 6,144

    unsigned short* zx   = (unsigned short*)(ws + off_zx);
    unsigned short* xT   = (unsigned short*)(ws + off_xT);
    unsigned short* bT   = (unsigned short*)(ws + off_bT);
    unsigned short* Brow = (unsigned short*)(ws + off_Brow);
    unsigned short* Crow = (unsigned short*)(ws + off_Crow);
    float2* dtdA = (float2*)(ws + off_dtdA);
    float* yb    = (float*)(ws + off_y);
    unsigned short* sst  = (unsigned short*)(ws + off_sst);
    unsigned short* sstT = xT;                        // xT dead after ssd_local
    float* Pbuf = (float*)(ws + off_P);

    // transient aliases (dead regions at time of use)
    unsigned short* x_bf     = (unsigned short*)(ws + off_y);    // gemm1 only (before yb written)
    unsigned short* w_in_bf  = (unsigned short*)(ws + off_sst);  // gemm1 only (before sst written)
    unsigned short* w_out_bf = (unsigned short*)(ws + off_xT);   // written after sstT dead (step 7.5)

    static bool attr_set = false;
    if (!attr_set) {
        hipFuncSetAttribute((const void*)ssd_local_kernel,
                            hipFuncAttributeMaxDynamicSharedMemorySize, 70656);
        hipFuncSetAttribute((const void*)gemm_8phase,
                            hipFuncAttributeMaxDynamicSharedMemorySize, 131072);
        hipFuncSetAttribute((const void*)gemm_out,
                            hipFuncAttributeMaxDynamicSharedMemorySize, 65536);
        attr_set = true;
    }

    // 0. convert x, w_in (padded to 3584 rows) -> bf16
    convert_kernel<<<4416, 256, 0, stream>>>(x, w_in, x_bf, w_in_bf);
    // 1. in_proj (M=8192, N=3352 padded 3584, K=768) — 256x256 swizzled pipeline (R3 form)
    gemm_8phase<<<448, 512, 131072, stream>>>(x_bf, w_in_bf, zx, 3352, 768);
    // 2. fused conv + silu + layout
    conv_fused_kernel<<<3584, 256, 0, stream>>>(zx, conv_w, conv_b, xT, bT, Brow, Crow);
    // 3. dt / log-dA (full f32)
    dt_kernel<<<8192, 64, 0, stream>>>(x, w_in, dt_bias, A_log, dtdA);
    // 4. SSD local
    ssd_local_kernel<<<1536, 256, 70656, stream>>>(Brow, Crow, dtdA, xT, bT, Dp, yb, sst, Pbuf);
    // 5. combine — per-(bh,p-slice) blocks, LDS transpose, coalesced R/W
    combine_kernel<<<192, 256, 0, stream>>>(sst, sstT, Pbuf);
    // 6. SSD inter
    ssd_inter_kernel<<<1440, 256, 0, stream>>>(Crow, dtdA, sstT, yb);
    // 6.5 convert w_out -> bf16 (xT/sstT region dead now)
    convert_wout_kernel<<<576, 256, 0, stream>>>(w_out, w_out_bf);
    // 7. gated RMSNorm -> bf16 into zx cols [1536,3072)
    norm_kernel<<<8192, 256, 0, stream>>>(yb, zx, nw);
    // 8. out_proj + residual
    gemm_out<<<384, 512, 65536, stream>>>(zx + 1536, w_out_bf, out, x, 3352);
}

// Round 9
// 351.850 us; speedup vs baseline: 1.2911x; 1.0219x over previous
//
#include <hip/hip_runtime.h>
#include <math.h>

// ---------- types ----------
typedef __bf16 bf16x8 __attribute__((ext_vector_type(8)));
typedef float  f32x4  __attribute__((ext_vector_type(4)));

#define QCHUNK 128
#define NCHUNK 16
#define SLD 136              // LDS row stride (bf16 elems) for 128-wide arrays

__device__ __forceinline__ float bf2f(unsigned short u) {
    union { unsigned int i; float f; } v; v.i = ((unsigned int)u) << 16; return v.f;
}
__device__ __forceinline__ unsigned short f2bf(float f) {
    union { float f; unsigned int i; } v; v.f = f;
    unsigned int x = v.i;
    unsigned int r = (x + 0x7FFFu + ((x >> 16) & 1u)) >> 16;
    return (unsigned short)r;
}
__device__ __forceinline__ uint4 pack8(float4 a, float4 b) {
    uint4 r;
    r.x = (unsigned)f2bf(a.x) | ((unsigned)f2bf(a.y) << 16);
    r.y = (unsigned)f2bf(a.z) | ((unsigned)f2bf(a.w) << 16);
    r.z = (unsigned)f2bf(b.x) | ((unsigned)f2bf(b.y) << 16);
    r.w = (unsigned)f2bf(b.z) | ((unsigned)f2bf(b.w) << 16);
    return r;
}
__device__ __forceinline__ void load_lds16(const void* g, void* l) {
    __builtin_amdgcn_global_load_lds((const __attribute__((address_space(1))) void*)g,
                                     (__attribute__((address_space(3))) void*)l,
                                     16, 0, 0);
}

// ---------- convert: x -> x_bf, w_in -> w_in_bf (padded 3584 rows, zero-filled) ----------
__global__ __launch_bounds__(256)
void convert_kernel(const float* __restrict__ x, const float* __restrict__ w_in,
                    unsigned short* __restrict__ x_bf, unsigned short* __restrict__ w_in_bf) {
    int idx = blockIdx.x * 256 + threadIdx.x;      // 8 elems each
    const int NX  = 8192 * 768 / 8;                // 786432
    const int NW1 = 3584 * 768 / 8;                // 344064 (padded to 14x256 tiles)
    const int NW1r = 3352 * 768 / 8;               // 321792 (real)
    if (idx < NX) {
        const float* s = x + (size_t)idx * 8;
        *(uint4*)(x_bf + (size_t)idx * 8) = pack8(*(const float4*)s, *(const float4*)(s + 4));
    } else if (idx < NX + NW1) {
        int j = idx - NX;
        uint4 v = make_uint4(0u, 0u, 0u, 0u);
        if (j < NW1r) {
            const float* s = w_in + (size_t)j * 8;
            v = pack8(*(const float4*)s, *(const float4*)(s + 4));
        }
        *(uint4*)(w_in_bf + (size_t)j * 8) = v;
    }
}

// ---------- convert w_out -> bf16 ----------
__global__ __launch_bounds__(256)
void convert_wout_kernel(const float* __restrict__ w_out, unsigned short* __restrict__ w_out_bf) {
    int idx = blockIdx.x * 256 + threadIdx.x;      // 147456 total
    const float* s = w_out + (size_t)idx * 8;
    *(uint4*)(w_out_bf + (size_t)idx * 8) = pack8(*(const float4*)s, *(const float4*)(s + 4));
}

// ---------- 256x256 pipelined GEMM: Out[m,n] = sum_k A[m,k]*Bw[n,k], bf16 out ----------
// (R6-verified form, 62.9 µs.) 512 threads = 8 waves (2 wr x 4 wc); per-wave 128x64;
// K-tile 64 (full 128B LDS row). LDS: A[2dbuf][256][128B] @0, B @65536 = 128 KiB.
// Swizzle both-sides: granule g of row r stores global slot g^(r&7); read col ^= (r&7)<<4.
// Per tile: stage next tile's 8 loads, gate vmcnt(8) (never 0 mid-loop), 2 barriers/tile.
__global__ __launch_bounds__(512)
void gemm_8phase(const unsigned short* __restrict__ A,
                 const unsigned short* __restrict__ Bw,
                 unsigned short* __restrict__ Out,
                 int N_real, int K) {
    extern __shared__ __align__(16) char smem[];

    const int tid = threadIdx.x;
    const int bid = blockIdx.x;
    // XCD-chunked: 448 = 8 XCDs x 56; n-fastest within chunk (A-panel 1.6MB stays L2-resident)
    const int xcd = bid & 7, local = bid >> 3;
    const int mt = xcd * 4 + local / 14;       // 4 m-tiles per XCD
    const int nt = local % 14;
    const int m0 = mt * 256, n0 = nt * 256;

    const int wave = tid >> 6, lane = tid & 63;
    const int wr = wave >> 2, wc = wave & 3;
    const int lr = lane & 15, q = lane >> 4;

    const int gl   = (lr & 7) << 4;            // row-granule XOR bits (bits 4-6)
    const int arow = wr * 128 + lr;            // + m*16
    const int brow = wc * 64 + lr;             // + n*16
    const int colq = q << 4;                   // + kh*64, then ^ gl

    // staging: LDS linear (row=tid>>3 + i*64, slot=tid&7); global source slot pre-swizzled
    const int srow  = tid >> 3;                // 0..63
    const int sslot = (tid & 7) ^ (srow & 7);
    const unsigned short* ga = A  + (size_t)(m0 + srow) * K + sslot * 8;
    const unsigned short* gb = Bw + (size_t)(n0 + srow) * K + sslot * 8;
    char* sAd = smem +         (size_t)tid * 16;
    char* sBd = smem + 65536 + (size_t)tid * 16;
    const size_t gstep = (size_t)64 * K;

    const int NT = K >> 6;                     // 12
    f32x4 acc[8][4] = {};

    // prologue: tile0 -> dbuf0 (8 issues: 4 A + 4 B)
    #pragma unroll
    for (int i = 0; i < 4; ++i) {
        load_lds16(ga + (size_t)i * gstep, sAd + i * 8192);
        load_lds16(gb + (size_t)i * gstep, sBd + i * 8192);
    }

    for (int t = 0; t < NT; ++t) {
        const int d = t & 1;
        const bool more = (t + 1 < NT);
        if (more) {                            // stage tile t+1 -> other dbuf
            const size_t kg = (size_t)(t + 1) * 64;
            const int ld = (d ^ 1) * 32768;
            #pragma unroll
            for (int i = 0; i < 4; ++i) {
                load_lds16(ga + kg + (size_t)i * gstep, sAd + ld + i * 8192);
                load_lds16(gb + kg + (size_t)i * gstep, sBd + ld + i * 8192);
            }
            asm volatile("s_waitcnt vmcnt(8)" ::: "memory");   // tile t's 8 landed
        } else {
            asm volatile("s_waitcnt vmcnt(0)" ::: "memory");
        }
        __builtin_amdgcn_s_barrier();

        const char* pa = smem +         d * 32768;
        const char* pb = smem + 65536 + d * 32768;
        #pragma unroll
        for (int kh = 0; kh < 2; ++kh) {
            const int col = ((kh << 6) | colq) ^ gl;
            bf16x8 af[8], bfr[4];
            #pragma unroll
            for (int m = 0; m < 8; ++m)
                af[m] = *(const bf16x8*)(pa + (arow + m * 16) * 128 + col);
            #pragma unroll
            for (int n = 0; n < 4; ++n)
                bfr[n] = *(const bf16x8*)(pb + (brow + n * 16) * 128 + col);

            __builtin_amdgcn_s_setprio(1);
            #pragma unroll
            for (int m = 0; m < 8; ++m)
                #pragma unroll
                for (int n = 0; n < 4; ++n)
                    acc[m][n] = __builtin_amdgcn_mfma_f32_16x16x32_bf16(af[m], bfr[n], acc[m][n], 0, 0, 0);
            __builtin_amdgcn_s_setprio(0);
        }
        __builtin_amdgcn_s_barrier();          // dbuf d free for iteration t+1's staging
    }

    // epilogue: C/D layout col=lane&15, row=(lane>>4)*4+reg
    #pragma unroll
    for (int m = 0; m < 8; ++m) {
        #pragma unroll
        for (int r = 0; r < 4; ++r) {
            int row = m0 + wr * 128 + m * 16 + q * 4 + r;
            #pragma unroll
            for (int n = 0; n < 4; ++n) {
                int col = n0 + wc * 64 + n * 16 + lr;
                if (col < N_real)
                    Out[(size_t)row * N_real + col] = f2bf(acc[m][n][r]);
            }
        }
    }
}

// ---------- out_proj GEMM: Out[m,n] = sum_k A[m,k]*Bw[n,k] + Resid, f32 out ----------
// M=8192, N=768, K=1536. BM=BN=128, 512 threads = 8 waves (2x4), per-wave 64x32.
// 128B-row + (row&7)<<4 XOR swizzle; per-tile vmcnt(4) gating.
// LDS: A[2dbuf][128][128B] @0 (32KB), B @32768 (32KB) = 64 KiB -> 2 blocks/CU.
__global__ __launch_bounds__(512)
void gemm_out(const unsigned short* __restrict__ A,
              const unsigned short* __restrict__ Bw,
              float* __restrict__ Out, const float* __restrict__ Resid,
              int lda) {
    extern __shared__ __align__(16) char smem[];
    const int K = 1536, Nn = 768;

    const int tid = threadIdx.x;
    const int bid = blockIdx.x;
    // XCD-chunked: 384 = 8 x 48; n-fastest (A panel 3.1MB/XCD ~L2-resident)
    const int xcd = bid & 7, local = bid >> 3;
    const int mt = xcd * 8 + local / 6;        // 0..63
    const int nt = local % 6;                  // 0..5
    const int m0 = mt * 128, n0 = nt * 128;

    const int wave = tid >> 6, lane = tid & 63;
    const int wr = wave >> 2, wc = wave & 3;
    const int lr = lane & 15, q = lane >> 4;

    const int gl   = (lr & 7) << 4;
    const int arow = wr * 64 + lr;             // + m*16
    const int brow = wc * 32 + lr;             // + n*16
    const int colq = q << 4;

    const int srow  = tid >> 3;                // 0..63
    const int sslot = (tid & 7) ^ (srow & 7);
    const unsigned short* ga = A  + (size_t)(m0 + srow) * lda + sslot * 8;
    const unsigned short* gb = Bw + (size_t)(n0 + srow) * K   + sslot * 8;
    char* sAd = smem +         (size_t)tid * 16;
    char* sBd = smem + 32768 + (size_t)tid * 16;
    const size_t gstep_a = (size_t)64 * lda;
    const size_t gstep_b = (size_t)64 * K;

    f32x4 acc[4][2] = {};

    // prologue: tile0 -> dbuf0 (4 issues: 2 A + 2 B)
    #pragma unroll
    for (int i = 0; i < 2; ++i) {
        load_lds16(ga + (size_t)i * gstep_a, sAd + i * 8192);
        load_lds16(gb + (size_t)i * gstep_b, sBd + i * 8192);
    }

    const int NT = K >> 6;   // 24
    for (int t = 0; t < NT; ++t) {
        const int d = t & 1;
        const bool more = (t + 1 < NT);
        if (more) {
            const size_t kg = (size_t)(t + 1) * 64;
            const int ld = (d ^ 1) * 16384;
            #pragma unroll
            for (int i = 0; i < 2; ++i) {
                load_lds16(ga + kg + (size_t)i * gstep_a, sAd + ld + i * 8192);
                load_lds16(gb + kg + (size_t)i * gstep_b, sBd + ld + i * 8192);
            }
            asm volatile("s_waitcnt vmcnt(4)" ::: "memory");
        } else {
            asm volatile("s_waitcnt vmcnt(0)" ::: "memory");
        }
        __builtin_amdgcn_s_barrier();

        const char* pa = smem +         d * 16384;
        const char* pb = smem + 32768 + d * 16384;
        #pragma unroll
        for (int kh = 0; kh < 2; ++kh) {
            const int col = ((kh << 6) | colq) ^ gl;
            bf16x8 af[4], bfr[2];
            #pragma unroll
            for (int m = 0; m < 4; ++m)
                af[m] = *(const bf16x8*)(pa + (arow + m * 16) * 128 + col);
            #pragma unroll
            for (int n = 0; n < 2; ++n)
                bfr[n] = *(const bf16x8*)(pb + (brow + n * 16) * 128 + col);

            __builtin_amdgcn_s_setprio(1);
            #pragma unroll
            for (int m = 0; m < 4; ++m)
                #pragma unroll
                for (int n = 0; n < 2; ++n)
                    acc[m][n] = __builtin_amdgcn_mfma_f32_16x16x32_bf16(af[m], bfr[n], acc[m][n], 0, 0, 0);
            __builtin_amdgcn_s_setprio(0);
        }
        __builtin_amdgcn_s_barrier();
    }

    // epilogue: f32 out + residual (N=768 = 6x128 exactly, no masking)
    #pragma unroll
    for (int m = 0; m < 4; ++m) {
        #pragma unroll
        for (int r = 0; r < 4; ++r) {
            int row = m0 + wr * 64 + m * 16 + q * 4 + r;
            #pragma unroll
            for (int n = 0; n < 2; ++n) {
                int col = n0 + wc * 32 + n * 16 + lr;
                Out[(size_t)row * Nn + col] = acc[m][n][r] + Resid[(size_t)row * Nn + col];
            }
        }
    }
}

// ---------- fused conv(4)+silu+layout: zx xBC cols -> xT (transposed), bT (transposed), Brow/Crow (row-major), all bf16 ----------
// grid: b(4) x t-tile(32) x ch-tile(28), 256 threads. Tile 64 t x 64 ch.
__global__ __launch_bounds__(256)
void conv_fused_kernel(const unsigned short* __restrict__ zx,
                       const float* __restrict__ cw, const float* __restrict__ cb,
                       unsigned short* __restrict__ xT, unsigned short* __restrict__ bT,
                       unsigned short* __restrict__ Brow, unsigned short* __restrict__ Crow) {
    __shared__ unsigned short outt[64][66];
    __shared__ float cwl[64][4];
    __shared__ float cbl[64];

    int blk = blockIdx.x;
    int cht = blk % 28;
    int tt  = (blk / 28) % 32;
    int b   = blk / (28 * 32);
    int ch0 = cht * 64, t0 = tt * 64;
    int tid = threadIdx.x;
    int tx = tid & 63, ty = tid >> 6;

    if (tid < 64) cbl[tid] = cb[ch0 + tid];
    cwl[tid >> 2][tid & 3] = cw[(ch0 + (tid >> 2)) * 4 + (tid & 3)];
    __syncthreads();

    const unsigned short* zp = zx + (size_t)(b * 2048) * 3352 + 1536 + ch0 + tx;
    float w0 = cwl[tx][0], w1 = cwl[tx][1], w2 = cwl[tx][2], w3 = cwl[tx][3];
    float bias = cbl[tx];
    int tg = t0 + ty * 16;                 // first output t for this thread
    float r0 = (tg >= 3) ? bf2f(zp[(size_t)(tg - 3) * 3352]) : 0.f;
    float r1 = (tg >= 2) ? bf2f(zp[(size_t)(tg - 2) * 3352]) : 0.f;
    float r2 = (tg >= 1) ? bf2f(zp[(size_t)(tg - 1) * 3352]) : 0.f;
    #pragma unroll
    for (int k = 0; k < 16; ++k) {
        float cur = bf2f(zp[(size_t)(tg + k) * 3352]);
        float a = bias + r0 * w0 + r1 * w1 + r2 * w2 + cur * w3;
        a = a / (1.f + expf(-a));          // silu
        outt[ty * 16 + k][tx] = f2bf(a);
        r0 = r1; r1 = r2; r2 = cur;
    }
    __syncthreads();

    if (ch0 < 1536) {
        // x region: transposed write xT[ch][t]
        unsigned short* dst = xT + ((size_t)(b * 1536 + ch0)) * 2048 + t0;
        #pragma unroll
        for (int k = 0; k < 16; ++k) {
            int chl = ty * 16 + k;
            dst[(size_t)chl * 2048 + tx] = outt[tx][chl];
        }
    } else if (ch0 < 1664) {
        // B region: transposed bT[n][t] + row-major Brow[t][n]
        int n0 = ch0 - 1536;
        unsigned short* dstT = bT + ((size_t)(b * 128 + n0)) * 2048 + t0;
        #pragma unroll
        for (int k = 0; k < 16; ++k) {
            int chl = ty * 16 + k;
            dstT[(size_t)chl * 2048 + tx] = outt[tx][chl];
        }
        unsigned short* dstR = Brow + ((size_t)(b * 2048 + t0)) * 128 + n0;
        int tl = tid >> 3, c8 = (tid & 7) << 3;
        #pragma unroll
        for (int it = 0; it < 2; ++it) {
            int t = tl + it * 32;
            unsigned short tmp[8];
            #pragma unroll
            for (int jj = 0; jj < 8; ++jj) tmp[jj] = outt[t][c8 + jj];
            *(uint4*)(dstR + (size_t)t * 128 + c8) = *(uint4*)tmp;
        }
    } else {
        // C region: row-major Crow[t][n]
        int n0 = ch0 - 1664;
        unsigned short* dstR = Crow + ((size_t)(b * 2048 + t0)) * 128 + n0;
        int tl = tid >> 3, c8 = (tid & 7) << 3;
        #pragma unroll
        for (int it = 0; it < 2; ++it) {
            int t = tl + it * 32;
            unsigned short tmp[8];
            #pragma unroll
            for (int jj = 0; jj < 8; ++jj) tmp[jj] = outt[t][c8 + jj];
            *(uint4*)(dstR + (size_t)t * 128 + c8) = *(uint4*)tmp;
        }
    }
}

// ---------- dt in full f32 -> interleaved (dt, dt*A) float2 ----------
__global__ __launch_bounds__(64)
void dt_kernel(const float* __restrict__ x, const float* __restrict__ w_in,
               const float* __restrict__ dt_bias, const float* __restrict__ A_log,
               float2* __restrict__ dtdA) {
    int row = blockIdx.x;
    int lane = threadIdx.x;
    float xv[12];
    #pragma unroll
    for (int i = 0; i < 12; ++i) xv[i] = x[(size_t)row * 768 + i * 64 + lane];
    for (int h = 0; h < 24; ++h) {
        const float* w = w_in + (size_t)(3328 + h) * 768;
        float acc = 0.f;
        #pragma unroll
        for (int i = 0; i < 12; ++i) acc += xv[i] * w[i * 64 + lane];
        #pragma unroll
        for (int m = 1; m < 64; m <<= 1) acc += __shfl_xor(acc, m);
        if (lane == 0) {
            float v = acc + dt_bias[h];
            float dt = (v > 20.f) ? v : log1pf(expf(v));
            float A = -expf(A_log[h]);
            dtdA[(size_t)row * 24 + h] = make_float2(dt, dt * A);   // (dt, log dA)
        }
    }
}

// ---------- SSD local kernel: per (b,h,chunk): G -> M -> Y, s_out ----------
__global__ __launch_bounds__(256)
void ssd_local_kernel(const unsigned short* __restrict__ Brow,
                      const unsigned short* __restrict__ Crow,
                      const float2* __restrict__ dtdA,
                      const unsigned short* __restrict__ xT,
                      const unsigned short* __restrict__ bT,
                      const float* __restrict__ Dh,
                      unsigned short* __restrict__ yb,
                      unsigned short* __restrict__ sst,
                      float* __restrict__ Pbuf) {
    extern __shared__ __align__(16) char smem[];
    __bf16* Bs  = (__bf16*)smem;                 // 128 x SLD; later Xt(0:17408)+Xtw(17408:34816)
    __bf16* Cs  = (__bf16*)(smem + 34816);       // 128 x SLD; later Ms
    float*  Lc  = (float*)(smem + 69632);        // 128
    float*  dtl = (float*)(smem + 70144);        // 128

    const int tid = threadIdx.x;
    const int c   = blockIdx.x & 15;
    const int bh  = blockIdx.x >> 4;
    const int b   = bh / 24, h = bh % 24;
    const int t0g = b * 2048 + c * QCHUNK;
    const int wave = tid >> 6, lane = tid & 63;
    const int lr = lane & 15, q = lane >> 4;

    for (int cc = tid; cc < 2048; cc += 256) {
        int r = cc >> 4, c8 = (cc & 15) << 3;
        *(uint4*)(Bs + r * SLD + c8) = *(const uint4*)(Brow + ((size_t)(t0g + r)) * 128 + c8);
        *(uint4*)(Cs + r * SLD + c8) = *(const uint4*)(Crow + ((size_t)(t0g + r)) * 128 + c8);
    }
    if (tid < 128) {
        float2 dd = dtdA[((size_t)t0g + tid) * 24 + h];
        dtl[tid] = dd.x;
        Lc[tid]  = dd.y;     // log dA
    }
    __syncthreads();
    for (int off = 1; off < 128; off <<= 1) {
        float v = 0.f;
        if (tid < 128 && tid >= off) v = Lc[tid - off];
        __syncthreads();
        if (tid < 128) Lc[tid] += v;
        __syncthreads();
    }

    // P1: G = Cs . Bs^T
    const int wm = (wave & 1) * 64, wn = (wave >> 1) * 64;
    f32x4 g[4][4] = {};
    #pragma unroll
    for (int k0 = 0; k0 < 128; k0 += 32) {
        bf16x8 af[4], bfr[4];
        #pragma unroll
        for (int t = 0; t < 4; ++t) {
            af[t]  = *(const bf16x8*)(Cs + (wm + t * 16 + lr) * SLD + k0 + q * 8);
            bfr[t] = *(const bf16x8*)(Bs + (wn + t * 16 + lr) * SLD + k0 + q * 8);
        }
        #pragma unroll
        for (int ti = 0; ti < 4; ++ti)
            #pragma unroll
            for (int tj = 0; tj < 4; ++tj)
                g[ti][tj] = __builtin_amdgcn_mfma_f32_16x16x32_bf16(af[ti], bfr[tj], g[ti][tj], 0, 0, 0);
    }
    __syncthreads();

    // P5: masked scale -> Ms[t][tau]
    __bf16* Ms = Cs;
    {
        float lt_[4], dt_[4];
        #pragma unroll
        for (int tj = 0; tj < 4; ++tj) {
            int tau = wn + tj * 16 + lr;
            lt_[tj] = Lc[tau];
            dt_[tj] = dtl[tau];
        }
        #pragma unroll
        for (int ti = 0; ti < 4; ++ti) {
            #pragma unroll
            for (int r = 0; r < 4; ++r) {
                int t = wm + ti * 16 + q * 4 + r;
                float Lt = Lc[t];
                #pragma unroll
                for (int tj = 0; tj < 4; ++tj) {
                    int tau = wn + tj * 16 + lr;
                    float mv = (tau <= t) ? g[ti][tj][r] * expf(Lt - lt_[tj]) * dt_[tj] : 0.f;
                    unsigned short u = f2bf(mv);
                    Ms[t * SLD + tau] = *(__bf16*)&u;
                }
            }
        }
    }

    // P3: stage Xt[p][t] and Xtw[p][t]
    __bf16* Xt  = Bs;
    __bf16* Xtw = (__bf16*)(smem + 17408);
    {
        float LQ = Lc[127];
        const unsigned short* xTb = xT + ((size_t)(b * 1536 + h * 64)) * 2048 + c * QCHUNK;
        for (int cc = tid; cc < 1024; cc += 256) {
            int p = cc >> 4, c8 = (cc & 15) << 3;
            uint4 v = *(const uint4*)(xTb + (size_t)p * 2048 + c8);
            *(uint4*)(Xt + p * SLD + c8) = v;
            unsigned short uu[8] = {(unsigned short)(v.x & 0xFFFF), (unsigned short)(v.x >> 16),
                                    (unsigned short)(v.y & 0xFFFF), (unsigned short)(v.y >> 16),
                                    (unsigned short)(v.z & 0xFFFF), (unsigned short)(v.z >> 16),
                                    (unsigned short)(v.w & 0xFFFF), (unsigned short)(v.w >> 16)};
            float w0[8];
            #pragma unroll
            for (int jj = 0; jj < 8; ++jj) {
                int tau = c8 + jj;
                w0[jj] = bf2f(uu[jj]) * expf(LQ - Lc[tau]) * dtl[tau];
            }
            *(uint4*)(Xtw + p * SLD + c8) = pack8(make_float4(w0[0], w0[1], w0[2], w0[3]),
                                                  make_float4(w0[4], w0[5], w0[6], w0[7]));
        }
    }
    __syncthreads();

    // P4: s_out[n][p] = bT . Xtw^T
    {
        f32x4 so[2][4] = {};
        const unsigned short* bTb = bT + ((size_t)(b * 128)) * 2048 + c * QCHUNK;
        #pragma unroll
        for (int k0 = 0; k0 < 128; k0 += 32) {
            bf16x8 af[2], bfr[4];
            #pragma unroll
            for (int ti = 0; ti < 2; ++ti) {
                int n = wave * 32 + ti * 16 + lr;
                af[ti] = *(const bf16x8*)(bTb + (size_t)n * 2048 + k0 + q * 8);
            }
            #pragma unroll
            for (int tj = 0; tj < 4; ++tj)
                bfr[tj] = *(const bf16x8*)(Xtw + (tj * 16 + lr) * SLD + k0 + q * 8);
            #pragma unroll
            for (int ti = 0; ti < 2; ++ti)
                #pragma unroll
                for (int tj = 0; tj < 4; ++tj)
                    so[ti][tj] = __builtin_amdgcn_mfma_f32_16x16x32_bf16(af[ti], bfr[tj], so[ti][tj], 0, 0, 0);
        }
        unsigned short* sb = sst + ((size_t)(bh * NCHUNK + c)) * 8192;
        #pragma unroll
        for (int ti = 0; ti < 2; ++ti) {
            #pragma unroll
            for (int r = 0; r < 4; ++r) {
                int n = wave * 32 + ti * 16 + q * 4 + r;
                #pragma unroll
                for (int tj = 0; tj < 4; ++tj) {
                    int p = tj * 16 + lr;
                    sb[n * 64 + p] = f2bf(so[ti][tj][r]);
                }
            }
        }
        if (tid == 0) Pbuf[bh * NCHUNK + c] = expf(Lc[127]);
    }

    // P6: Y[t][p] = Ms . Xt^T  (+ D skip) -> bf16
    {
        f32x4 ya[2][4] = {};
        #pragma unroll
        for (int k0 = 0; k0 < 128; k0 += 32) {
            bf16x8 af[2], bfr[4];
            #pragma unroll
            for (int ti = 0; ti < 2; ++ti)
                af[ti] = *(const bf16x8*)(Ms + (wave * 32 + ti * 16 + lr) * SLD + k0 + q * 8);
            #pragma unroll
            for (int tj = 0; tj < 4; ++tj)
                bfr[tj] = *(const bf16x8*)(Xt + (tj * 16 + lr) * SLD + k0 + q * 8);
            #pragma unroll
            for (int ti = 0; ti < 2; ++ti)
                #pragma unroll
                for (int tj = 0; tj < 4; ++tj)
                    ya[ti][tj] = __builtin_amdgcn_mfma_f32_16x16x32_bf16(af[ti], bfr[tj], ya[ti][tj], 0, 0, 0);
        }
        float Dv = Dh[h];
        unsigned short* ybb = yb + (size_t)t0g * 1536 + h * 64;
        #pragma unroll
        for (int ti = 0; ti < 2; ++ti) {
            #pragma unroll
            for (int r = 0; r < 4; ++r) {
                int t = wave * 32 + ti * 16 + q * 4 + r;
                #pragma unroll
                for (int tj = 0; tj < 4; ++tj) {
                    int p = tj * 16 + lr;
                    __bf16 xb = Xt[p * SLD + t];
                    float xv = bf2f(*(unsigned short*)&xb);
                    ybb[(size_t)t * 1536 + p] = f2bf(ya[ti][tj][r] + Dv * xv);
                }
            }
        }
    }
}

// ---------- combine: per-(bh, 32-p-slice) block; scan in registers, LDS transpose, ----------
// ---------- coalesced reads (64B segs) and fully-coalesced uint4 writes ----------
__global__ __launch_bounds__(256)
void combine_kernel(const unsigned short* __restrict__ sst,
                    unsigned short* __restrict__ sstT,
                    const float* __restrict__ Pbuf) {
    __shared__ unsigned short tl[32 * 130];        // [p-local 32][n 128], pad to 130
    const int blk = blockIdx.x;                    // 192 = 96 bh x 2 p-halves
    const int bh = blk >> 1;
    const int ph = (blk & 1) * 32;
    const int tid = threadIdx.x;
    const int pl = tid & 31;                       // p-local 0..31
    const int nb = tid >> 5;                       // 0..7
    const unsigned short* sb = sst + (size_t)bh * NCHUNK * 8192;
    unsigned short* tb = sstT + (size_t)bh * NCHUNK * 8192 + ph * 128;
    const float* Pb = Pbuf + bh * NCHUNK;

    float s[16];
    #pragma unroll
    for (int i = 0; i < 16; ++i) s[i] = 0.f;

    for (int c = 0; c < NCHUNK; ++c) {
        const float Pc = Pb[c];
        const unsigned short* sc = sb + (size_t)c * 8192;
        // scan step: read own pn values (64B-coalesced), stash OLD s transposed in LDS
        #pragma unroll
        for (int i = 0; i < 16; ++i) {
            int n = nb + 8 * i;                    // 0..127
            unsigned short v = sc[n * 64 + ph + pl];
            tl[pl * 130 + n] = f2bf(s[i]);
            s[i] = Pc * s[i] + bf2f(v);
        }
        __syncthreads();
        // emit transposed slab: 4096 elems = 512 uint4, 2 per thread, fully coalesced
        uint* tlw = (uint*)tl;
        uint4* tc4 = (uint4*)(tb + (size_t)c * 8192);
        #pragma unroll
        for (int k = 0; k < 2; ++k) {
            int j = tid + k * 256;                 // uint4 index 0..511
            int pp = j >> 4;                       // p-local
            int w0 = pp * 65 + (j & 15) * 4;       // word index in padded row
            tc4[j] = make_uint4(tlw[w0], tlw[w0 + 1], tlw[w0 + 2], tlw[w0 + 3]);
        }
        __syncthreads();
    }
}

// ---------- SSD inter kernel (yb bf16 RMW) ----------
__global__ __launch_bounds__(256)
void ssd_inter_kernel(const unsigned short* __restrict__ Crow,
                      const float2* __restrict__ dtdA,
                      const unsigned short* __restrict__ sstT,
                      unsigned short* __restrict__ yb) {
    __shared__ __align__(16) __bf16 Cs[128 * SLD];
    __shared__ __align__(16) __bf16 St[64 * SLD];
    __shared__ float Lc[128];

    const int tid = threadIdx.x;
    const int blk = blockIdx.x;
    const int bh = blk / 15;
    const int c  = blk % 15 + 1;
    const int b = bh / 24, h = bh % 24;
    const int t0g = b * 2048 + c * QCHUNK;
    const int wave = tid >> 6, lane = tid & 63;
    const int lr = lane & 15, q = lane >> 4;

    for (int cc = tid; cc < 2048; cc += 256) {
        int r = cc >> 4, c8 = (cc & 15) << 3;
        *(uint4*)(Cs + r * SLD + c8) = *(const uint4*)(Crow + ((size_t)(t0g + r)) * 128 + c8);
    }
    const unsigned short* stb = sstT + ((size_t)(bh * NCHUNK + c)) * 8192;
    for (int cc = tid; cc < 1024; cc += 256) {
        int p = cc >> 4, c8 = (cc & 15) << 3;
        *(uint4*)(St + p * SLD + c8) = *(const uint4*)(stb + p * 128 + c8);
    }
    if (tid < 128) Lc[tid] = dtdA[((size_t)t0g + tid) * 24 + h].y;
    __syncthreads();
    for (int off = 1; off < 128; off <<= 1) {
        float v = 0.f;
        if (tid < 128 && tid >= off) v = Lc[tid - off];
        __syncthreads();
        if (tid < 128) Lc[tid] += v;
        __syncthreads();
    }

    f32x4 ya[2][4] = {};
    #pragma unroll
    for (int k0 = 0; k0 < 128; k0 += 32) {
        bf16x8 af[2], bfr[4];
        #pragma unroll
        for (int ti = 0; ti < 2; ++ti)
            af[ti] = *(const bf16x8*)(Cs + (wave * 32 + ti * 16 + lr) * SLD + k0 + q * 8);
        #pragma unroll
        for (int tj = 0; tj < 4; ++tj)
            bfr[tj] = *(const bf16x8*)(St + (tj * 16 + lr) * SLD + k0 + q * 8);
        #pragma unroll
        for (int ti = 0; ti < 2; ++ti)
            #pragma unroll
            for (int tj = 0; tj < 4; ++tj)
                ya[ti][tj] = __builtin_amdgcn_mfma_f32_16x16x32_bf16(af[ti], bfr[tj], ya[ti][tj], 0, 0, 0);
    }
    unsigned short* ybb = yb + (size_t)t0g * 1536 + h * 64;
    #pragma unroll
    for (int ti = 0; ti < 2; ++ti) {
        #pragma unroll
        for (int r = 0; r < 4; ++r) {
            int t = wave * 32 + ti * 16 + q * 4 + r;
            float sc = expf(Lc[t]);
            #pragma unroll
            for (int tj = 0; tj < 4; ++tj) {
                int p = tj * 16 + lr;
                unsigned short* yp = ybb + (size_t)t * 1536 + p;
                *yp = f2bf(bf2f(*yp) + sc * ya[ti][tj][r]);
            }
        }
    }
}

// ---------- gated RMSNorm: reads yb bf16, writes bf16 into zx cols [1536,3072) ----------
__global__ __launch_bounds__(256)
void norm_kernel(const unsigned short* __restrict__ yb,
                 unsigned short* __restrict__ zx,
                 const float* __restrict__ nw) {
    int row = blockIdx.x;
    const unsigned short* yr = yb + (size_t)row * 1536;
    unsigned short* zr = zx + (size_t)row * 3352;
    int tid = threadIdx.x;
    float u[6];
    float ss = 0.f;
    #pragma unroll
    for (int i = 0; i < 6; ++i) {
        int c = tid + i * 256;
        float z = bf2f(zr[c]);
        float uu = bf2f(yr[c]) * (z / (1.f + expf(-z)));
        u[i] = uu;
        ss += uu * uu;
    }
    #pragma unroll
    for (int m = 1; m < 64; m <<= 1) ss += __shfl_xor(ss, m);
    __shared__ float red[4];
    if ((tid & 63) == 0) red[tid >> 6] = ss;
    __syncthreads();
    float tot = red[0] + red[1] + red[2] + red[3];
    float inv = rsqrtf(tot * (1.f / 1536.f) + 1e-5f);
    #pragma unroll
    for (int i = 0; i < 6; ++i) {
        int c = tid + i * 256;
        zr[1536 + c] = f2bf(u[i] * inv * nw[c]);
    }
}

// ---------- launch ----------
extern "C" void kernel_launch(void* const* d_in, const int* in_sizes, int n_in,
                              void* d_out, int out_size, void* d_ws, size_t ws_size,
                              hipStream_t stream) {
    const float* x       = (const float*)d_in[0];
    const float* w_in    = (const float*)d_in[1];
    const float* conv_w  = (const float*)d_in[2];
    const float* conv_b  = (const float*)d_in[3];
    const float* dt_bias = (const float*)d_in[4];
    const float* A_log   = (const float*)d_in[5];
    const float* Dp      = (const float*)d_in[6];
    const float* nw      = (const float*)d_in[7];
    const float* w_out   = (const float*)d_in[8];
    float* out = (float*)d_out;

    char* ws = (char*)d_ws;
    const size_t off_zx   = 0;                        // 8192*3352 bf16 = 54,919,168
    const size_t off_A    = off_zx + 54919168;        // region A (58,720,256 reserved)
    const size_t off_xT   = off_A;                    // 25,165,824 (sstT + w_out_bf alias later)
    const size_t off_bT   = off_A + 25165824;         // 2,097,152
    const size_t off_Brow = off_A + 27262976;         // 2,097,152
    const size_t off_Crow = off_A + 29360128;         // 2,097,152
    const size_t off_dtdA = off_A + 58720256;         // 1,572,864
    const size_t off_y    = off_dtdA + 1572864;       // 50,331,648 reserved (yb bf16 uses 25MB; x_bf aliases head)
    const size_t off_sst  = off_y + 50331648;         // 25,165,824 (w_in_bf aliases head)
    const size_t off_P    = off_sst + 25165824;       // 6,144

    unsigned short* zx   = (unsigned short*)(ws + off_zx);
    unsigned short* xT   = (unsigned short*)(ws + off_xT);
    unsigned short* bT   = (unsigned short*)(ws + off_bT);
    unsigned short* Brow = (unsigned short*)(ws + off_Brow);
    unsigned short* Crow = (unsigned short*)(ws + off_Crow);
    float2* dtdA = (float2*)(ws + off_dtdA);
    unsigned short* yb   = (unsigned short*)(ws + off_y);
    unsigned short* sst  = (unsigned short*)(ws + off_sst);
    unsigned short* sstT = xT;                        // xT dead after ssd_local
    float* Pbuf = (float*)(ws + off_P);

    // transient aliases (dead regions at time of use)
    unsigned short* x_bf     = (unsigned short*)(ws + off_y);    // gemm1 only (before yb written)
    unsigned short* w_in_bf  = (unsigned short*)(ws + off_sst);  // gemm1 only (before sst written)
    unsigned short* w_out_bf = (unsigned short*)(ws + off_xT);   // written after sstT dead (step 6.5)

    static bool attr_set = false;
    if (!attr_set) {
        hipFuncSetAttribute((const void*)ssd_local_kernel,
                            hipFuncAttributeMaxDynamicSharedMemorySize, 70656);
        hipFuncSetAttribute((const void*)gemm_8phase,
                            hipFuncAttributeMaxDynamicSharedMemorySize, 131072);
        hipFuncSetAttribute((const void*)gemm_out,
                            hipFuncAttributeMaxDynamicSharedMemorySize, 65536);
        attr_set = true;
    }

    // 0. convert x, w_in (padded to 3584 rows) -> bf16
    convert_kernel<<<4416, 256, 0, stream>>>(x, w_in, x_bf, w_in_bf);
    // 1. in_proj (M=8192, N=3352 padded 3584, K=768) — R6-verified 256x256 BK=64 pipeline
    gemm_8phase<<<448, 512, 131072, stream>>>(x_bf, w_in_bf, zx, 3352, 768);
    // 2. fused conv + silu + layout
    conv_fused_kernel<<<3584, 256, 0, stream>>>(zx, conv_w, conv_b, xT, bT, Brow, Crow);
    // 3. dt / log-dA (full f32)
    dt_kernel<<<8192, 64, 0, stream>>>(x, w_in, dt_bias, A_log, dtdA);
    // 4. SSD local (yb bf16)
    ssd_local_kernel<<<1536, 256, 70656, stream>>>(Brow, Crow, dtdA, xT, bT, Dp, yb, sst, Pbuf);
    // 5. combine — per-(bh,p-slice) blocks, LDS transpose, coalesced R/W
    combine_kernel<<<192, 256, 0, stream>>>(sst, sstT, Pbuf);
    // 6. SSD inter (yb bf16 RMW)
    ssd_inter_kernel<<<1440, 256, 0, stream>>>(Crow, dtdA, sstT, yb);
    // 6.5 convert w_out -> bf16 (xT/sstT region dead now)
    convert_wout_kernel<<<576, 256, 0, stream>>>(w_out, w_out_bf);
    // 7. gated RMSNorm (yb bf16 in) -> bf16 into zx cols [1536,3072)
    norm_kernel<<<8192, 256, 0, stream>>>(yb, zx, nw);
    // 8. out_proj + residual
    gemm_out<<<384, 512, 65536, stream>>>(zx + 1536, w_out_bf, out, x, 3352);
}